// Round 12
// baseline (1597.893 us; speedup 1.0000x reference)
//
#include <hip/hip_runtime.h>

// EntityAttentionRNNMsgAgent — fused MI355X implementation.
// r12 = r11 + k3 caches 2/12 col-tiles of w_hh per wave in LDS (66KB, loaded
// once before the 64-step loop) — cuts the per-step per-CU L2 w_hh stream by
// 16.7%. Everything else byte-identical to r11 (1584.9us verified).
// Stages:
//  K0:  transpose all weights to f16 [N][K] (gate branch: hi/lo split pair)
//  K0w: gate-tail collapse: Weff = Wout@Wg2, Wveff (256x8), beff — f32, 1 block
//  K1b2: merged main+msg branch attention, 2 items/block, 512 thr (2048 blocks)
//  K1g: gate branch, algebraically reduced: split-2 f16 + f32 P.v2 -> og/gate
//  K2:  gated_msg, global attention, fc2, gru-input GEMM (gi); reads gate flag
//  K3:  64-step GRU, row-partitioned (32 blocks x 16 rows), h in LDS,
//       w_hh tiles c<2 LDS-cached, c>=2 streamed from L2
//  K4:  q = hs @ fc3 + b, masked

#define DEV __device__ __forceinline__

typedef _Float16 f16x8 __attribute__((ext_vector_type(8)));
typedef float    f32x4 __attribute__((ext_vector_type(4)));

DEV f32x4 mfma16(f16x8 a, f16x8 b, f32x4 c){
  return __builtin_amdgcn_mfma_f32_16x16x32_f16(a, b, c, 0, 0, 0);
}

// A/B fragment pair for optional split-precision (MODE=1: value = hi + lo)
template<int MODE> struct AB {
  f16x8 hi, lo;
  DEV void mf(const AB& b, f32x4& c) const {
    if constexpr (MODE){
      c = mfma16(lo, b.hi, c);
      c = mfma16(hi, b.lo, c);
    }
    c = mfma16(hi, b.hi, c);
  }
};

template<int MODE> DEV AB<MODE> ldW(const _Float16* p, int losz){
  AB<MODE> r; r.hi = *(const f16x8*)p;
  if constexpr (MODE) r.lo = *(const f16x8*)(p + losz);
  return r;
}
template<int MODE> DEV AB<MODE> ldL(const _Float16* ph, const _Float16* pl){
  AB<MODE> r; r.hi = *(const f16x8*)ph;
  if constexpr (MODE) r.lo = *(const f16x8*)pl;
  return r;
}
template<int MODE> DEV AB<MODE> ldF(const float* p){
  AB<MODE> r;
  f32x4 v0 = *(const f32x4*)p, v1 = *(const f32x4*)(p + 4);
#pragma unroll
  for (int i = 0; i < 4; ++i){
    float a = v0[i], b = v1[i];
    _Float16 ah = (_Float16)a, bh = (_Float16)b;
    r.hi[i] = ah; r.hi[i+4] = bh;
    if constexpr (MODE){
      r.lo[i]   = (_Float16)(a - (float)ah);
      r.lo[i+4] = (_Float16)(b - (float)bh);
    }
  }
  return r;
}
template<int MODE> DEV void stL(_Float16* ph, _Float16* pl, int idx, float v){
  _Float16 h = (_Float16)v;
  ph[idx] = h;
  if constexpr (MODE) pl[idx] = (_Float16)(v - (float)h);
}

// ---------------------------------------------------------------- K0: weights
struct WJobs {
  const float* src[15];
  unsigned off[15];
  int K[15], N[15], mode[15];
};

__global__ __launch_bounds__(256) void k0_conv(WJobs jb, char* ws){
  const int job = blockIdx.y;
  const int K = jb.K[job], N = jb.N[job];
  const int total = K * N;
  _Float16* dh = (_Float16*)(ws + jb.off[job]);
  const float* src = jb.src[job];
  const int m = jb.mode[job];
  for (int idx = blockIdx.x*256 + threadIdx.x; idx < total; idx += gridDim.x*256){
    int n = idx / K, k = idx - n*K;
    float v = src[(size_t)k*N + n];
    _Float16 h = (_Float16)v;
    dh[idx] = h;
    if (m) dh[total + idx] = (_Float16)(v - (float)h);
  }
}

// ------------------------------------------------- K0w: gate-tail precompute
__global__ __launch_bounds__(256) void k0w_gate(
    const float* __restrict__ Wout, const float* __restrict__ Wg2,
    const float* __restrict__ bo,   const float* __restrict__ Win,
    _Float16* __restrict__ wveff, float* __restrict__ beff)
{
  __shared__ float weff_s[256*2];
  const int tid = threadIdx.x;
  {
    float a0 = 0.f, a1 = 0.f;
    const float* wr = Wout + (size_t)tid*256;
    for (int f = 0; f < 256; ++f){ float x = wr[f]; a0 += x*Wg2[2*f]; a1 += x*Wg2[2*f+1]; }
    weff_s[tid*2] = a0; weff_s[tid*2+1] = a1;
  }
  if (tid < 2){
    float s = 0.f;
    for (int f = 0; f < 256; ++f) s += bo[f]*Wg2[2*f + tid];
    beff[tid] = s;
  }
  __syncthreads();
  {
    const int j = tid;
    for (int n = 0; n < 16; ++n){
      float v = 0.f;
      if (n < 8){
        int h = n >> 1, c = n & 1;
        const float* wr = Win + (size_t)j*768 + 512 + h*64;
        const float* we = weff_s + (h*64)*2 + c;
        for (int d = 0; d < 64; ++d) v += wr[d]*we[2*d];
      }
      _Float16 hi = (_Float16)v;
      wveff[n*256 + j] = hi;
      wveff[16*256 + n*256 + j] = (_Float16)(v - (float)hi);
    }
  }
}

// ------------------------------------------- K1b2: branch attention, 2 items
// 2048 blocks x 512 threads (8 waves); br = blockIdx.x>>10 selects {main,msg};
// pair p = blockIdx.x&1023 -> items 2p, 2p+1. Weight fragments are loaded once
// per wave and applied to both items; tile-space split across 8 waves.
// wi = w&3 (tile role), ih = w>>2 (half: item or c-subset, phase-dependent).
__global__ __launch_bounds__(512) void k1_branch2(
    const float* __restrict__ ent, const float* __restrict__ om, const float* __restrict__ em,
    const _Float16* __restrict__ W1a, const float* __restrict__ b1a,
    const _Float16* __restrict__ WINa,
    const _Float16* __restrict__ WOUTa, const float* __restrict__ boa,
    float* __restrict__ x2outa,
    const _Float16* __restrict__ W1b, const float* __restrict__ b1b,
    const _Float16* __restrict__ WINb,
    const _Float16* __restrict__ WOUTb, const float* __restrict__ bob,
    float* __restrict__ x2outb)
{
  const int br = blockIdx.x >> 10;
  const int p  = blockIdx.x & 1023;
  const int bb2[2] = { 2*p, 2*p + 1 };
  const _Float16* W1   = br ? W1b   : W1a;
  const float*    b1   = br ? b1b   : b1a;
  const _Float16* WIN  = br ? WINb  : WINa;
  const _Float16* WOUT = br ? WOUTb : WOUTa;
  const float*    bo   = br ? bob   : boa;
  float*          x2out= br ? x2outb: x2outa;

  const int tid = threadIdx.x;
  const int w = tid >> 6, lg = (tid >> 4) & 3, li = tid & 15;
  const int wi = w & 3, ih = w >> 2;

  extern __shared__ char smem[];
  _Float16* x1  = (_Float16*)smem;               // [2][64*264]  67584 B
  _Float16* Ks  = (_Float16*)(smem + 67584);     // [2][64*72]   18432 B
  _Float16* Vs  = (_Float16*)(smem + 86016);     // [2][64*72]T  18432 B
  _Float16* Qs  = (_Float16*)(smem + 104448);    // [2][16*72]    4608 B
  float*    lgs = (float*)(smem + 109056);       // [2][16*72]    9216 B
  _Float16* Ps  = (_Float16*)(smem + 118272);    // [2][16*72]    4608 B
  float*    outp= (float*)(smem + 122880);       // [2][16*264]  33792 B
  // total 156672 B

  // ---- phase 1: x1 = relu(ent @ W1 + b1); wave -> item ih, col-group wi
  {
    const int b = bb2[ih];
    _Float16* x1p = x1 + ih*16896;
    f32x4 acc[4][4];
#pragma unroll
    for (int r = 0; r < 4; ++r)
#pragma unroll
      for (int c = 0; c < 4; ++c) acc[r][c] = 0.f;
#pragma unroll
    for (int kk = 0; kk < 3; ++kk){
      AB<0> a[4];
#pragma unroll
      for (int r = 0; r < 4; ++r)
        a[r] = ldF<0>(ent + ((size_t)b*64 + 16*r + li)*96 + kk*32 + lg*8);
#pragma unroll
      for (int c = 0; c < 4; ++c){
        f16x8 B = *(const f16x8*)(W1 + (size_t)(64*wi + 16*c + li)*96 + kk*32 + lg*8);
#pragma unroll
        for (int r = 0; r < 4; ++r) acc[r][c] = mfma16(a[r].hi, B, acc[r][c]);
      }
    }
#pragma unroll
    for (int c = 0; c < 4; ++c){
      int col = 64*wi + 16*c + li;
      float bias = b1[col];
#pragma unroll
      for (int r = 0; r < 4; ++r)
#pragma unroll
        for (int j = 0; j < 4; ++j){
          float v = fmaxf(acc[r][c][j] + bias, 0.f);
          x1p[(16*r + 4*lg + j)*264 + col] = (_Float16)v;
        }
    }
  }
  __syncthreads();

  // ---- phase 2: per-head attention
  for (int h = 0; h < 4; ++h){
    { // K_h: wave -> keys 16*wi, c-tiles {2ih, 2ih+1}, both items
      f32x4 acc[2][2];
#pragma unroll
      for (int it = 0; it < 2; ++it)
#pragma unroll
        for (int c = 0; c < 2; ++c) acc[it][c] = 0.f;
      for (int kk = 0; kk < 8; ++kk){
        int ao = (16*wi + li)*264 + kk*32 + lg*8;
        f16x8 A0 = *(const f16x8*)(x1 + ao);
        f16x8 A1 = *(const f16x8*)(x1 + 16896 + ao);
#pragma unroll
        for (int cc = 0; cc < 2; ++cc){
          int c = 2*ih + cc;
          f16x8 B = *(const f16x8*)(WIN + (size_t)(256 + 64*h + 16*c + li)*256 + kk*32 + lg*8);
          acc[0][cc] = mfma16(A0, B, acc[0][cc]);
          acc[1][cc] = mfma16(A1, B, acc[1][cc]);
        }
      }
#pragma unroll
      for (int it = 0; it < 2; ++it)
#pragma unroll
        for (int cc = 0; cc < 2; ++cc){
          int c = 2*ih + cc;
#pragma unroll
          for (int j = 0; j < 4; ++j)
            Ks[it*4608 + (16*wi + 4*lg + j)*72 + 16*c + li] = (_Float16)acc[it][cc][j];
        }
    }
    { // V_h (stored transposed): same split
      f32x4 acc[2][2];
#pragma unroll
      for (int it = 0; it < 2; ++it)
#pragma unroll
        for (int c = 0; c < 2; ++c) acc[it][c] = 0.f;
      for (int kk = 0; kk < 8; ++kk){
        int ao = (16*wi + li)*264 + kk*32 + lg*8;
        f16x8 A0 = *(const f16x8*)(x1 + ao);
        f16x8 A1 = *(const f16x8*)(x1 + 16896 + ao);
#pragma unroll
        for (int cc = 0; cc < 2; ++cc){
          int c = 2*ih + cc;
          f16x8 B = *(const f16x8*)(WIN + (size_t)(512 + 64*h + 16*c + li)*256 + kk*32 + lg*8);
          acc[0][cc] = mfma16(A0, B, acc[0][cc]);
          acc[1][cc] = mfma16(A1, B, acc[1][cc]);
        }
      }
#pragma unroll
      for (int it = 0; it < 2; ++it)
#pragma unroll
        for (int cc = 0; cc < 2; ++cc){
          int c = 2*ih + cc;
#pragma unroll
          for (int j = 0; j < 4; ++j)
            Vs[it*4608 + (16*c + li)*72 + 16*wi + 4*lg + j] = (_Float16)acc[it][cc][j];
        }
    }
    { // Q_h: rows 0..15, wave -> dim tile wi, item ih
      f32x4 acc = 0.f;
      for (int kk = 0; kk < 8; ++kk){
        f16x8 A = *(const f16x8*)(x1 + ih*16896 + li*264 + kk*32 + lg*8);
        f16x8 B = *(const f16x8*)(WIN + (size_t)(64*h + 16*wi + li)*256 + kk*32 + lg*8);
        acc = mfma16(A, B, acc);
      }
#pragma unroll
      for (int j = 0; j < 4; ++j)
        Qs[ih*1152 + (4*lg + j)*72 + 16*wi + li] = (_Float16)acc[j];
    }
    __syncthreads();
    { // logits = Q K^T / 8, masked; wave -> keys 16*wi, item ih
      const int b = bb2[ih];
      f32x4 acc = 0.f;
#pragma unroll
      for (int kk = 0; kk < 2; ++kk){
        f16x8 A = *(const f16x8*)(Qs + ih*1152 + li*72 + kk*32 + lg*8);
        f16x8 B = *(const f16x8*)(Ks + ih*4608 + (16*wi + li)*72 + kk*32 + lg*8);
        acc = mfma16(A, B, acc);
      }
#pragma unroll
      for (int j = 0; j < 4; ++j){
        int q = 4*lg + j, key = 16*wi + li;
        float v = acc[j] * 0.125f;
        float m = om[((size_t)b*64 + q)*64 + key];
        if (m > 0.f) v = -1e9f;
        lgs[ih*1152 + q*72 + key] = v;
      }
    }
    __syncthreads();
    { // softmax: 512 threads cover 2 items x 16 q x 16 lanes
      const int it = tid >> 8, q = (tid >> 4) & 15, i16 = tid & 15;
      const int b = bb2[it];
      float pv[4], mx = -3e38f;
#pragma unroll
      for (int u = 0; u < 4; ++u){ pv[u] = lgs[it*1152 + q*72 + i16 + 16*u]; mx = fmaxf(mx, pv[u]); }
#pragma unroll
      for (int d = 1; d < 16; d <<= 1) mx = fmaxf(mx, __shfl_xor(mx, d, 16));
      float s = 0.f;
#pragma unroll
      for (int u = 0; u < 4; ++u){ pv[u] = expf(pv[u] - mx); s += pv[u]; }
#pragma unroll
      for (int d = 1; d < 16; d <<= 1) s += __shfl_xor(s, d, 16);
#pragma unroll
      for (int u = 0; u < 4; ++u){
        int key = i16 + 16*u;
        float m = om[((size_t)b*64 + q)*64 + key];
        Ps[it*1152 + q*72 + key] = (_Float16)((pv[u]/s)*(1.f - m));
      }
    }
    __syncthreads();
    { // out_h = P @ V_h; wave -> dim tile wi, item ih
      f32x4 acc = 0.f;
#pragma unroll
      for (int kk = 0; kk < 2; ++kk){
        f16x8 A = *(const f16x8*)(Ps + ih*1152 + li*72 + kk*32 + lg*8);
        f16x8 B = *(const f16x8*)(Vs + ih*4608 + (16*wi + li)*72 + kk*32 + lg*8);
        acc = mfma16(A, B, acc);
      }
#pragma unroll
      for (int j = 0; j < 4; ++j)
        outp[ih*4224 + (4*lg + j)*264 + 64*h + 16*wi + li] = acc[j];
    }
    __syncthreads();
  }

  // ---- phase 3: out-proj; wave -> col-group wi, c-tiles {2ih,2ih+1}, 2 items
  {
    f32x4 acc[2][2];
#pragma unroll
    for (int it = 0; it < 2; ++it)
#pragma unroll
      for (int c = 0; c < 2; ++c) acc[it][c] = 0.f;
    for (int kk = 0; kk < 8; ++kk){
      AB<0> a0 = ldF<0>(outp + li*264 + kk*32 + lg*8);
      AB<0> a1 = ldF<0>(outp + 4224 + li*264 + kk*32 + lg*8);
#pragma unroll
      for (int cc = 0; cc < 2; ++cc){
        int c = 2*ih + cc;
        f16x8 B = *(const f16x8*)(WOUT + (size_t)(64*wi + 16*c + li)*256 + kk*32 + lg*8);
        acc[0][cc] = mfma16(a0.hi, B, acc[0][cc]);
        acc[1][cc] = mfma16(a1.hi, B, acc[1][cc]);
      }
    }
#pragma unroll
    for (int it = 0; it < 2; ++it){
      const int b = bb2[it];
#pragma unroll
      for (int cc = 0; cc < 2; ++cc){
        int col = 64*wi + 16*(2*ih + cc) + li;
        float bias = bo[col];
#pragma unroll
        for (int j = 0; j < 4; ++j){
          int q = 4*lg + j;
          float v = (acc[it][cc][j] + bias) * (1.f - em[(size_t)b*64 + q]);
          x2out[((size_t)b*16 + q)*256 + col] = v;
        }
      }
    }
  }
}

// --------------------------------------------- K1g: reduced gate branch
// 512 threads = 8 waves, one block per batch item.
__global__ __launch_bounds__(512) void k1_gate(
    const float* __restrict__ ent, const float* __restrict__ om, const float* __restrict__ em,
    const _Float16* __restrict__ W1, const float* __restrict__ b1,
    const _Float16* __restrict__ WIN,
    const _Float16* __restrict__ WVEFF,
    const float* __restrict__ beff, const float* __restrict__ gb2,
    float* __restrict__ og, float* __restrict__ gate)
{
  constexpr int W1SZ = 96*256, WINSZ = 256*768, WVSZ = 16*256;
  const int b = blockIdx.x;
  const int tid = threadIdx.x;
  const int w = tid >> 6, lg = (tid >> 4) & 3, li = tid & 15;

  extern __shared__ char smem[];
  char* sp = smem;
  _Float16* x1h = (_Float16*)sp; sp += 64*264*2;
  _Float16* x1l = (_Float16*)sp; sp += 64*264*2;
  _Float16* Kh  = (_Float16*)sp; sp += 64*72*2;
  _Float16* Kl  = (_Float16*)sp; sp += 64*72*2;
  _Float16* Qh  = (_Float16*)sp; sp += 16*264*2;
  _Float16* Ql  = (_Float16*)sp; sp += 16*264*2;
  float*    lgs = (float*)sp;    sp += 16*72*4;
  float*    Ps  = (float*)sp;    sp += 16*66*4;
  float*    v2s = (float*)sp;    sp += 64*18*4;
  float*  ogacc = (float*)sp;    sp += 32*4;

  // ---- phase 1: x1 = relu(ent @ W1 + b1); wave w -> m-tile w>>1, 8 n-tiles
  {
    const int mt = w >> 1;
    f32x4 acc[8];
#pragma unroll
    for (int c = 0; c < 8; ++c) acc[c] = 0.f;
#pragma unroll
    for (int kk = 0; kk < 3; ++kk){
      AB<1> a = ldF<1>(ent + ((size_t)b*64 + mt*16 + li)*96 + kk*32 + lg*8);
#pragma unroll
      for (int c = 0; c < 8; ++c){
        int nt = (w & 1)*8 + c;
        AB<1> bb = ldW<1>(W1 + (size_t)(nt*16 + li)*96 + kk*32 + lg*8, W1SZ);
        a.mf(bb, acc[c]);
      }
    }
#pragma unroll
    for (int c = 0; c < 8; ++c){
      int col = ((w & 1)*8 + c)*16 + li;
      float bias = b1[col];
#pragma unroll
      for (int j = 0; j < 4; ++j){
        float v = fmaxf(acc[c][j] + bias, 0.f);
        stL<1>(x1h, x1l, (mt*16 + 4*lg + j)*264 + col, v);
      }
    }
  }
  if (tid < 32) ogacc[tid] = 0.f;
  __syncthreads();

  // ---- phase 2: Qfull = x1[0:16] @ Wq (16 n-tiles), v2 = x1 @ Wveff (4 m-tiles)
  {
#pragma unroll
    for (int s = 0; s < 2; ++s){
      int nt = w + s*8;
      f32x4 acc = 0.f;
      for (int kk = 0; kk < 8; ++kk){
        int ao = li*264 + kk*32 + lg*8;
        AB<1> a = ldL<1>(x1h + ao, x1l + ao);
        AB<1> bb = ldW<1>(WIN + (size_t)(nt*16 + li)*256 + kk*32 + lg*8, WINSZ);
        a.mf(bb, acc);
      }
#pragma unroll
      for (int j = 0; j < 4; ++j)
        stL<1>(Qh, Ql, (4*lg + j)*264 + nt*16 + li, acc[j]);
    }
    if (w < 4){   // v2 m-tile w
      f32x4 acc = 0.f;
      for (int kk = 0; kk < 8; ++kk){
        int ao = (w*16 + li)*264 + kk*32 + lg*8;
        AB<1> a = ldL<1>(x1h + ao, x1l + ao);
        AB<1> bb = ldW<1>(WVEFF + (size_t)li*256 + kk*32 + lg*8, WVSZ);
        a.mf(bb, acc);
      }
#pragma unroll
      for (int j = 0; j < 4; ++j)
        v2s[(w*16 + 4*lg + j)*18 + li] = acc[j];
    }
  }
  __syncthreads();

  // ---- head loop
  for (int h = 0; h < 4; ++h){
    { // K_h: wave w -> m-tile w>>1, 2 n-tiles
      const int mt = w >> 1;
      f32x4 acc[2];
      acc[0] = 0.f; acc[1] = 0.f;
      for (int kk = 0; kk < 8; ++kk){
        int ao = (mt*16 + li)*264 + kk*32 + lg*8;
        AB<1> a = ldL<1>(x1h + ao, x1l + ao);
#pragma unroll
        for (int c = 0; c < 2; ++c){
          int nt = (w & 1)*2 + c;
          AB<1> bb = ldW<1>(WIN + (size_t)(256 + h*64 + nt*16 + li)*256 + kk*32 + lg*8, WINSZ);
          a.mf(bb, acc[c]);
        }
      }
#pragma unroll
      for (int c = 0; c < 2; ++c){
        int colb = ((w & 1)*2 + c)*16 + li;
#pragma unroll
        for (int j = 0; j < 4; ++j)
          stL<1>(Kh, Kl, (mt*16 + 4*lg + j)*72 + colb, acc[c][j]);
      }
    }
    __syncthreads();
    if (w < 4){ // logits: keys 16w..16w+15
      f32x4 acc = 0.f;
#pragma unroll
      for (int kk = 0; kk < 2; ++kk){
        int ao = li*264 + h*64 + kk*32 + lg*8;
        AB<1> a = ldL<1>(Qh + ao, Ql + ao);
        int bo_ = (16*w + li)*72 + kk*32 + lg*8;
        AB<1> bb = ldL<1>(Kh + bo_, Kl + bo_);
        a.mf(bb, acc);
      }
#pragma unroll
      for (int j = 0; j < 4; ++j){
        int q = 4*lg + j, key = 16*w + li;
        float v = acc[j] * 0.125f;
        float m = om[((size_t)b*64 + q)*64 + key];
        if (m > 0.f) v = -1e9f;
        lgs[q*72 + key] = v;
      }
    }
    __syncthreads();
    if (tid < 256){ // softmax
      int q = tid >> 4, i16 = tid & 15;
      float pv[4], mx = -3e38f;
#pragma unroll
      for (int u = 0; u < 4; ++u){ pv[u] = lgs[q*72 + i16 + 16*u]; mx = fmaxf(mx, pv[u]); }
#pragma unroll
      for (int d = 1; d < 16; d <<= 1) mx = fmaxf(mx, __shfl_xor(mx, d, 16));
      float s = 0.f;
#pragma unroll
      for (int u = 0; u < 4; ++u){ pv[u] = expf(pv[u] - mx); s += pv[u]; }
#pragma unroll
      for (int d = 1; d < 16; d <<= 1) s += __shfl_xor(s, d, 16);
#pragma unroll
      for (int u = 0; u < 4; ++u){
        int key = i16 + 16*u;
        float m = om[((size_t)b*64 + q)*64 + key];
        Ps[q*66 + key] = (pv[u]/s)*(1.f - m);
      }
    }
    __syncthreads();
    if (tid < 256){ // og += P_h . v2_h  (f32)
      int q = tid >> 4, l16 = tid & 15;
      float a0 = 0.f, a1 = 0.f;
#pragma unroll
      for (int u = 0; u < 4; ++u){
        int k = l16 + 16*u;
        float p = Ps[q*66 + k];
        a0 += p * v2s[k*18 + h*2];
        a1 += p * v2s[k*18 + h*2 + 1];
      }
#pragma unroll
      for (int d = 1; d < 16; d <<= 1){ a0 += __shfl_xor(a0, d, 16); a1 += __shfl_xor(a1, d, 16); }
      if (l16 == 0){ ogacc[q*2] += a0; ogacc[q*2 + 1] += a1; }
    }
    __syncthreads();
  }
  // epilogue: og + gate
  if (tid < 16){
    int q = tid;
    float am = em[(size_t)b*64 + q];
    float g0 = (1.f - am)*(ogacc[2*q]     + beff[0]) + gb2[0];
    float g1 = (1.f - am)*(ogacc[2*q + 1] + beff[1]) + gb2[1];
    og[((size_t)b*16 + q)*2]     = g0;
    og[((size_t)b*16 + q)*2 + 1] = g1;
    gate[(size_t)b*16 + q] = (g1 > g0) ? 1.f : 0.f;
  }
}

// ----------------------------------------- K2: gate, global attention, fc2, gi
__global__ __launch_bounds__(256) void k2_global(
    const float* __restrict__ em,
    const float* __restrict__ x2, const float* __restrict__ x2m,
    const float* __restrict__ gate,
    const _Float16* __restrict__ GMIN, const _Float16* __restrict__ GMOUT, const float* __restrict__ gob,
    const _Float16* __restrict__ FC2T, const float* __restrict__ fc2b,
    const _Float16* __restrict__ GIHT, const float* __restrict__ gib,
    float* __restrict__ gi)
{
  const int b = blockIdx.x;
  const int tid = threadIdx.x;
  const int w = tid >> 6, lg = (tid >> 4) & 3, li = tid & 15;

  __shared__ float gate_s[16];
  __shared__ __align__(16) _Float16 gm_s[16*264];
  __shared__ __align__(16) _Float16 Q2[16*72];
  __shared__ __align__(16) _Float16 K2s[16*72];
  __shared__ __align__(16) _Float16 Vt2[64*40];
  __shared__ float lg2[16*24];
  __shared__ __align__(16) _Float16 P2[16*40];
  __shared__ __align__(16) float outp[16*264];
  __shared__ __align__(16) _Float16 cat_s[16*520];
  __shared__ __align__(16) _Float16 x3_s[16*264];

  if (tid < 16) gate_s[tid] = gate[(size_t)b*16 + tid];
  __syncthreads();
  for (int idx = tid; idx < 4096; idx += 256){
    int q = idx >> 8, d = idx & 255;
    gm_s[q*264 + d]  = (_Float16)(x2m[((size_t)b*16 + q)*256 + d] * gate_s[q]);
    cat_s[q*520 + d] = (_Float16)(x2[((size_t)b*16 + q)*256 + d]);
  }
  for (int idx = tid; idx < 64*40; idx += 256) Vt2[idx] = (_Float16)0.f;
  for (int idx = tid; idx < 16*40; idx += 256) P2[idx] = (_Float16)0.f;
  __syncthreads();
  for (int h = 0; h < 4; ++h){
    {
      f32x4 aq = 0.f, ak = 0.f, av = 0.f;
      for (int kk = 0; kk < 8; ++kk){
        f16x8 A  = *(const f16x8*)(gm_s + li*264 + kk*32 + lg*8);
        f16x8 Bq = *(const f16x8*)(GMIN + (size_t)(      64*h + 16*w + li)*256 + kk*32 + lg*8);
        f16x8 Bk = *(const f16x8*)(GMIN + (size_t)(256 + 64*h + 16*w + li)*256 + kk*32 + lg*8);
        f16x8 Bv = *(const f16x8*)(GMIN + (size_t)(512 + 64*h + 16*w + li)*256 + kk*32 + lg*8);
        aq = mfma16(A, Bq, aq); ak = mfma16(A, Bk, ak); av = mfma16(A, Bv, av);
      }
#pragma unroll
      for (int j = 0; j < 4; ++j){
        int rw = 4*lg + j, dim = 16*w + li;
        Q2[rw*72 + dim]  = (_Float16)aq[j];
        K2s[rw*72 + dim] = (_Float16)ak[j];
        Vt2[dim*40 + rw] = (_Float16)av[j];
      }
    }
    __syncthreads();
    if (w == 0){
      f32x4 acc = 0.f;
#pragma unroll
      for (int kk = 0; kk < 2; ++kk){
        f16x8 A = *(const f16x8*)(Q2  + li*72 + kk*32 + lg*8);
        f16x8 B = *(const f16x8*)(K2s + li*72 + kk*32 + lg*8);
        acc = mfma16(A, B, acc);
      }
      float amk = em[(size_t)b*64 + li];
#pragma unroll
      for (int j = 0; j < 4; ++j){
        int q = 4*lg + j;
        float amq = em[(size_t)b*64 + q];
        float m = 1.f - (1.f - amq)*(1.f - amk);
        float v = acc[j]*0.125f;
        if (m > 0.f) v = -1e9f;
        lg2[q*24 + li] = v;
      }
    }
    __syncthreads();
    {
      int q = tid >> 4, key = tid & 15;
      float v = lg2[q*24 + key];
      float mx = v;
#pragma unroll
      for (int d = 1; d < 16; d <<= 1) mx = fmaxf(mx, __shfl_xor(mx, d, 16));
      float pe = expf(v - mx);
      float s = pe;
#pragma unroll
      for (int d = 1; d < 16; d <<= 1) s += __shfl_xor(s, d, 16);
      float amq = em[(size_t)b*64 + q], amk = em[(size_t)b*64 + key];
      float m = 1.f - (1.f - amq)*(1.f - amk);
      P2[q*40 + key] = (_Float16)((pe/s)*(1.f - m));
    }
    __syncthreads();
    {
      f32x4 acc = 0.f;
      f16x8 A = *(const f16x8*)(P2 + li*40 + lg*8);
      f16x8 B = *(const f16x8*)(Vt2 + (16*w + li)*40 + lg*8);
      acc = mfma16(A, B, acc);
#pragma unroll
      for (int j = 0; j < 4; ++j)
        outp[(4*lg + j)*264 + 64*h + 16*w + li] = acc[j];
    }
    __syncthreads();
  }
  {
    f32x4 acc[4];
#pragma unroll
    for (int c = 0; c < 4; ++c) acc[c] = 0.f;
    for (int kk = 0; kk < 8; ++kk){
      const float* ap = outp + li*264 + kk*32 + lg*8;
      f32x4 v0 = *(const f32x4*)ap, v1 = *(const f32x4*)(ap + 4);
      f16x8 A;
#pragma unroll
      for (int e = 0; e < 4; ++e){ A[e] = (_Float16)v0[e]; A[e+4] = (_Float16)v1[e]; }
#pragma unroll
      for (int c = 0; c < 4; ++c){
        f16x8 B = *(const f16x8*)(GMOUT + (size_t)(64*w + 16*c + li)*256 + kk*32 + lg*8);
        acc[c] = mfma16(A, B, acc[c]);
      }
    }
#pragma unroll
    for (int c = 0; c < 4; ++c){
      int col = 64*w + 16*c + li;
      float bias = gob[col];
#pragma unroll
      for (int j = 0; j < 4; ++j){
        int q = 4*lg + j;
        float v = (acc[c][j] + bias)*(1.f - em[(size_t)b*64 + q]);
        cat_s[q*520 + 256 + col] = (_Float16)v;
      }
    }
  }
  __syncthreads();
  {
    f32x4 acc[4];
#pragma unroll
    for (int c = 0; c < 4; ++c) acc[c] = 0.f;
    for (int kk = 0; kk < 16; ++kk){
      f16x8 A = *(const f16x8*)(cat_s + li*520 + kk*32 + lg*8);
#pragma unroll
      for (int c = 0; c < 4; ++c){
        f16x8 B = *(const f16x8*)(FC2T + (size_t)(64*w + 16*c + li)*512 + kk*32 + lg*8);
        acc[c] = mfma16(A, B, acc[c]);
      }
    }
#pragma unroll
    for (int c = 0; c < 4; ++c){
      int col = 64*w + 16*c + li;
      float bias = fc2b[col];
#pragma unroll
      for (int j = 0; j < 4; ++j)
        x3_s[(4*lg + j)*264 + col] = (_Float16)fmaxf(acc[c][j] + bias, 0.f);
    }
  }
  __syncthreads();
  {
    const int r0 = (b >> 6)*16, t = b & 63;
    f32x4 acc[12];
#pragma unroll
    for (int cc = 0; cc < 12; ++cc) acc[cc] = 0.f;
    for (int kk = 0; kk < 8; ++kk){
      f16x8 A = *(const f16x8*)(x3_s + li*264 + kk*32 + lg*8);
#pragma unroll
      for (int cc = 0; cc < 12; ++cc){
        int col = (w*12 + cc)*16 + li;
        f16x8 B = *(const f16x8*)(GIHT + (size_t)col*256 + kk*32 + lg*8);
        acc[cc] = mfma16(A, B, acc[cc]);
      }
    }
#pragma unroll
    for (int cc = 0; cc < 12; ++cc){
      int col = (w*12 + cc)*16 + li;
      float bias = gib[col];
#pragma unroll
      for (int j = 0; j < 4; ++j){
        int q = 4*lg + j;
        gi[((size_t)((r0 + q)*64 + t))*768 + col] = acc[cc][j] + bias;
      }
    }
  }
}

// ------------------------------------------------------------------ K3: GRU
// Row-partitioned: 32 blocks x 16 rows, 256 threads, h resident in LDS.
// r12: w_hh col-tiles c<2 of each wave cached in LDS (loaded once), c>=2
// streamed from L2 each step. Cache layout matches hf16's 264-padding
// (2-way bank conflict, free).
__global__ __launch_bounds__(256) void k3_gru(
    const _Float16* __restrict__ WHH, const float* __restrict__ bhh,
    const float* __restrict__ gi, const float* __restrict__ h0,
    float* __restrict__ hs)
{
  const int rb = blockIdx.x;
  const int row0 = rb * 16;
  const int tid = threadIdx.x;
  const int w = tid >> 6, lg = (tid >> 4) & 3, li = tid & 15;

  extern __shared__ char smem3[];
  _Float16* hf16 = (_Float16*)smem3;                     //  8448 B
  float* hf32 = (float*)(smem3 + 8448);                  // 16640 B
  float* gh   = (float*)(smem3 + 25088);                 // 49664 B
  float* bhs  = (float*)(smem3 + 74752);                 //  3072 B
  _Float16* wc = (_Float16*)(smem3 + 77824);             // 8 tiles x 16 x 264 f16 = 67584 B
  // total 145408 B

  for (int idx = tid; idx < 768; idx += 256) bhs[idx] = bhh[idx];
  for (int idx = tid; idx < 4096; idx += 256){
    int r = idx >> 8, d = idx & 255;
    float v = h0[(size_t)(row0 + r)*256 + d];
    hf32[r*260 + d] = v;
    hf16[r*264 + d] = (_Float16)v;
  }
  // stage w_hh cache: tiles (wv, c<2) -> wc[(wv*2+c)*16 + col][264]
  for (int idx = tid; idx < 4096; idx += 256){   // 4096 chunks of f16x8
    int tile = idx >> 9;            // 0..7 = wv*2 + c
    int rem  = idx & 511;           // col*32 + kc
    int col  = rem >> 5, kc = rem & 31;
    int gcol = (tile >> 1)*192 + (tile & 1)*16 + col;
    *(f16x8*)(wc + (size_t)(tile*16 + col)*264 + kc*8) =
        *(const f16x8*)(WHH + (size_t)gcol*256 + kc*8);
  }
  __syncthreads();

  const int er = tid >> 4;
  const int d0 = (tid & 15) * 16;

  for (int t = 0; t < 64; ++t){
    const float* gp = gi + ((size_t)(row0 + er)*64 + t)*768 + d0;
    f32x4 gr[4], gz[4], gn[4];
#pragma unroll
    for (int v = 0; v < 4; ++v){
      gr[v] = *(const f32x4*)(gp + v*4);
      gz[v] = *(const f32x4*)(gp + 256 + v*4);
      gn[v] = *(const f32x4*)(gp + 512 + v*4);
    }
    f16x8 a[8];
#pragma unroll
    for (int kk = 0; kk < 8; ++kk)
      a[kk] = *(const f16x8*)(hf16 + li*264 + kk*32 + lg*8);
    f32x4 acc[12];
#pragma unroll
    for (int c = 0; c < 12; ++c) acc[c] = 0.f;
#pragma unroll
    for (int c = 0; c < 12; ++c){
      if (c < 2){
        const _Float16* bp = wc + (size_t)((w*2 + c)*16 + li)*264 + lg*8;
#pragma unroll
        for (int kk = 0; kk < 8; ++kk)
          acc[c] = mfma16(a[kk], *(const f16x8*)(bp + kk*32), acc[c]);
      } else {
        const _Float16* bp = WHH + (size_t)(w*192 + c*16 + li)*256 + lg*8;
#pragma unroll
        for (int kk = 0; kk < 8; ++kk)
          acc[c] = mfma16(a[kk], *(const f16x8*)(bp + kk*32), acc[c]);
      }
    }
#pragma unroll
    for (int c = 0; c < 12; ++c){
      int col = w*192 + c*16 + li;
#pragma unroll
      for (int j = 0; j < 4; ++j)
        gh[(4*lg + j)*776 + col] = acc[c][j];
    }
    __syncthreads();
    {
      float* hp32 = hf32 + er*260 + d0;
      float* hsp  = hs + ((size_t)(rb*64 + t)*16 + er)*256 + d0;
      f16x8 hv8[2];
#pragma unroll
      for (int v = 0; v < 4; ++v){
        f32x4 xr = *(const f32x4*)(gh + er*776 +       d0 + v*4);
        f32x4 xz = *(const f32x4*)(gh + er*776 + 256 + d0 + v*4);
        f32x4 xn = *(const f32x4*)(gh + er*776 + 512 + d0 + v*4);
        f32x4 hold = *(const f32x4*)(hp32 + v*4);
        f32x4 hout;
#pragma unroll
        for (int e = 0; e < 4; ++e){
          int d = d0 + v*4 + e;
          float rr_ = 1.f/(1.f + expf(-(gr[v][e] + xr[e] + bhs[d])));
          float zz  = 1.f/(1.f + expf(-(gz[v][e] + xz[e] + bhs[256 + d])));
          float nn  = tanhf(gn[v][e] + rr_*(xn[e] + bhs[512 + d]));
          float hv = (1.f - zz)*nn + zz*hold[e];
          hout[e] = hv;
          int sl = v*4 + e;
          hv8[sl >> 3][sl & 7] = (_Float16)hv;
        }
        *(f32x4*)(hp32 + v*4) = hout;
        *(f32x4*)(hsp + v*4)  = hout;
      }
      *(f16x8*)(hf16 + er*264 + d0)     = hv8[0];
      *(f16x8*)(hf16 + er*264 + d0 + 8) = hv8[1];
    }
    __syncthreads();
  }
}

// ------------------------------------------------------------------ K4: q out
__global__ __launch_bounds__(256) void k4_q(
    const _Float16* __restrict__ FC3T, const float* __restrict__ fc3b,
    const float* __restrict__ em, const float* __restrict__ hs, float* __restrict__ qo)
{
  const int tid = threadIdx.x;
  const int w = tid >> 6, lg = (tid >> 4) & 3, li = tid & 15;
  const int rb = blockIdx.x*64 + 16*w;
  f32x4 acc[2];
#pragma unroll
  for (int c = 0; c < 2; ++c) acc[c] = 0.f;
  for (int kk = 0; kk < 8; ++kk){
    const float* ap = hs + (size_t)(rb + li)*256 + kk*32 + lg*8;
    f32x4 v0 = *(const f32x4*)ap, v1 = *(const f32x4*)(ap + 4);
    f16x8 A;
#pragma unroll
    for (int e = 0; e < 4; ++e){ A[e] = (_Float16)v0[e]; A[e+4] = (_Float16)v1[e]; }
#pragma unroll
    for (int c = 0; c < 2; ++c){
      f16x8 B = *(const f16x8*)(FC3T + (size_t)(16*c + li)*256 + kk*32 + lg*8);
      acc[c] = mfma16(A, B, acc[c]);
    }
  }
#pragma unroll
  for (int c = 0; c < 2; ++c){
    int col = 16*c + li;
    float bias = fc3b[col];
#pragma unroll
    for (int j = 0; j < 4; ++j){
      int row = rb + 4*lg + j;
      float am = em[(size_t)(row >> 4)*64 + (row & 15)];
      qo[(size_t)row*32 + col] = (acc[c][j] + bias)*(1.f - am);
    }
  }
}

// --------------------------------------------------------------------- launch
extern "C" void kernel_launch(void* const* d_in, const int* in_sizes, int n_in,
                              void* d_out, int out_size, void* d_ws, size_t ws_size,
                              hipStream_t stream)
{
  // ws layout (bytes) — r3 layout
  constexpr size_t OFF_FC1T   = 0;
  constexpr size_t OFF_MSG1T  = 49152;
  constexpr size_t OFF_AINT   = 98304;
  constexpr size_t OFF_LINT   = 491520;
  constexpr size_t OFF_AOUTT  = 884736;
  constexpr size_t OFF_LOUTT  = 1015808;
  constexpr size_t OFF_GMINT  = 1146880;
  constexpr size_t OFF_GMOUTT = 1540096;
  constexpr size_t OFF_FC2T   = 1671168;
  constexpr size_t OFF_GIHT   = 1933312;
  constexpr size_t OFF_GHHT   = 2326528;
  constexpr size_t OFF_FC3T   = 2719744;
  constexpr size_t OFF_G1T    = 2736128;   // f16 hi+lo pair
  constexpr size_t OFF_GINT   = 2834432;   // pair
  constexpr size_t OFF_WVEFF  = 3620864;   // pair
  constexpr size_t OFF_BEFF   = 3637248;
  constexpr size_t OFF_GATE   = 3637504;   // 131072
  constexpr size_t OFF_X2     = 3768576;   // 33554432
  constexpr size_t OFF_X2M    = 37323008;  // 33554432
  constexpr size_t OFF_GI     = 70877440;  // 100663296
  constexpr size_t NEED       = 171540736;
  if (ws_size < NEED) return;

  char* ws = (char*)d_ws;
  const float* ent = (const float*)d_in[0];
  const float* om  = (const float*)d_in[1];
  const float* em  = (const float*)d_in[2];

  WJobs jb{};
  int nj = 0;
  auto addj = [&](int src_idx, size_t off, int K, int N, int m){
    jb.src[nj] = (const float*)d_in[src_idx]; jb.off[nj] = (unsigned)off;
    jb.K[nj] = K; jb.N[nj] = N; jb.mode[nj] = m; ++nj;
  };
  addj(4,  OFF_FC1T,   96, 256, 0);
  addj(17, OFF_MSG1T,  96, 256, 0);
  addj(6,  OFF_AINT,  256, 768, 0);
  addj(19, OFF_LINT,  256, 768, 0);
  addj(7,  OFF_AOUTT, 256, 256, 0);
  addj(20, OFF_LOUTT, 256, 256, 0);
  addj(22, OFF_GMINT, 256, 768, 0);
  addj(23, OFF_GMOUTT,256, 256, 0);
  addj(9,  OFF_FC2T,  512, 256, 0);
  addj(11, OFF_GIHT,  256, 768, 0);
  addj(12, OFF_GHHT,  256, 768, 0);
  addj(15, OFF_FC3T,  256,  32, 0);
  addj(28, OFF_G1T,    96, 256, 1);
  addj(25, OFF_GINT,  256, 768, 1);
  k0_conv<<<dim3(96, nj), 256, 0, stream>>>(jb, ws);

  // gate-tail precompute: Weff/Wveff/beff
  k0w_gate<<<1, 256, 0, stream>>>(
      (const float*)d_in[26], (const float*)d_in[30],
      (const float*)d_in[27], (const float*)d_in[25],
      (_Float16*)(ws + OFF_WVEFF), (float*)(ws + OFF_BEFF));

  constexpr int SMB = 156672, SMG = 116480, SM3 = 145408;
  (void)hipFuncSetAttribute(reinterpret_cast<const void*>(&k1_branch2),
                            hipFuncAttributeMaxDynamicSharedMemorySize, SMB);
  (void)hipFuncSetAttribute(reinterpret_cast<const void*>(&k1_gate),
                            hipFuncAttributeMaxDynamicSharedMemorySize, SMG);
  (void)hipFuncSetAttribute(reinterpret_cast<const void*>(&k3_gru),
                            hipFuncAttributeMaxDynamicSharedMemorySize, SM3);

  float* qout = (float*)d_out;
  float* hsout = qout + 1048576;
  float* gout = qout + 9437184;

  // merged main+msg branches: 2048 blocks, 2 items each, 512 threads
  k1_branch2<<<2048, 512, SMB, stream>>>(ent, om, em,
      (const _Float16*)(ws + OFF_FC1T),  (const float*)d_in[5],
      (const _Float16*)(ws + OFF_AINT),
      (const _Float16*)(ws + OFF_AOUTT), (const float*)d_in[8],
      (float*)(ws + OFF_X2),
      (const _Float16*)(ws + OFF_MSG1T), (const float*)d_in[18],
      (const _Float16*)(ws + OFF_LINT),
      (const _Float16*)(ws + OFF_LOUTT), (const float*)d_in[21],
      (float*)(ws + OFF_X2M));
  k1_gate<<<2048, 512, SMG, stream>>>(ent, om, em,
      (const _Float16*)(ws + OFF_G1T),   (const float*)d_in[29],
      (const _Float16*)(ws + OFF_GINT),
      (const _Float16*)(ws + OFF_WVEFF),
      (const float*)(ws + OFF_BEFF), (const float*)d_in[31],
      gout, (float*)(ws + OFF_GATE));

  k2_global<<<2048, 256, 0, stream>>>(em,
      (const float*)(ws + OFF_X2), (const float*)(ws + OFF_X2M),
      (const float*)(ws + OFF_GATE),
      (const _Float16*)(ws + OFF_GMINT), (const _Float16*)(ws + OFF_GMOUTT), (const float*)d_in[24],
      (const _Float16*)(ws + OFF_FC2T), (const float*)d_in[10],
      (const _Float16*)(ws + OFF_GIHT), (const float*)d_in[13],
      (float*)(ws + OFF_GI));

  k3_gru<<<32, 256, SM3, stream>>>(
      (const _Float16*)(ws + OFF_GHHT), (const float*)d_in[14],
      (const float*)(ws + OFF_GI), (const float*)d_in[3], hsout);

  k4_q<<<512, 256, 0, stream>>>(
      (const _Float16*)(ws + OFF_FC3T), (const float*)d_in[16],
      em, hsout, qout);
}

// Round 13
// 1575.741 us; speedup vs baseline: 1.0141x; 1.0141x over previous
//
#include <hip/hip_runtime.h>

// EntityAttentionRNNMsgAgent — fused MI355X implementation.
// r13 = r11 + {k1_branch2, k1_gate} fused into ONE 4096-block dispatch
// (roles by blockIdx; both 512 thr, 1 block/CU) — removes the serial
// drain-tail between the two independent kernels. k3 reverted to r11's
// plain version (r12's LDS w_hh cache was neutral/negative).
// Stages:
//  K0:  transpose all weights to f16 [N][K] (gate branch: hi/lo split pair)
//  K0w: gate-tail collapse: Weff = Wout@Wg2, Wveff (256x8), beff — f32, 1 block
//  K1:  fused: blocks 0..2047 branch2 (2 items, B-shared), 2048..4095 gate
//  K2:  gated_msg, global attention, fc2, gru-input GEMM (gi); reads gate flag
//  K3:  64-step GRU, row-partitioned (32 blocks x 16 rows), h resident in LDS
//  K4:  q = hs @ fc3 + b, masked

#define DEV __device__ __forceinline__

typedef _Float16 f16x8 __attribute__((ext_vector_type(8)));
typedef float    f32x4 __attribute__((ext_vector_type(4)));

DEV f32x4 mfma16(f16x8 a, f16x8 b, f32x4 c){
  return __builtin_amdgcn_mfma_f32_16x16x32_f16(a, b, c, 0, 0, 0);
}

// A/B fragment pair for optional split-precision (MODE=1: value = hi + lo)
template<int MODE> struct AB {
  f16x8 hi, lo;
  DEV void mf(const AB& b, f32x4& c) const {
    if constexpr (MODE){
      c = mfma16(lo, b.hi, c);
      c = mfma16(hi, b.lo, c);
    }
    c = mfma16(hi, b.hi, c);
  }
};

template<int MODE> DEV AB<MODE> ldW(const _Float16* p, int losz){
  AB<MODE> r; r.hi = *(const f16x8*)p;
  if constexpr (MODE) r.lo = *(const f16x8*)(p + losz);
  return r;
}
template<int MODE> DEV AB<MODE> ldL(const _Float16* ph, const _Float16* pl){
  AB<MODE> r; r.hi = *(const f16x8*)ph;
  if constexpr (MODE) r.lo = *(const f16x8*)pl;
  return r;
}
template<int MODE> DEV AB<MODE> ldF(const float* p){
  AB<MODE> r;
  f32x4 v0 = *(const f32x4*)p, v1 = *(const f32x4*)(p + 4);
#pragma unroll
  for (int i = 0; i < 4; ++i){
    float a = v0[i], b = v1[i];
    _Float16 ah = (_Float16)a, bh = (_Float16)b;
    r.hi[i] = ah; r.hi[i+4] = bh;
    if constexpr (MODE){
      r.lo[i]   = (_Float16)(a - (float)ah);
      r.lo[i+4] = (_Float16)(b - (float)bh);
    }
  }
  return r;
}
template<int MODE> DEV void stL(_Float16* ph, _Float16* pl, int idx, float v){
  _Float16 h = (_Float16)v;
  ph[idx] = h;
  if constexpr (MODE) pl[idx] = (_Float16)(v - (float)h);
}

// ---------------------------------------------------------------- K0: weights
struct WJobs {
  const float* src[15];
  unsigned off[15];
  int K[15], N[15], mode[15];
};

__global__ __launch_bounds__(256) void k0_conv(WJobs jb, char* ws){
  const int job = blockIdx.y;
  const int K = jb.K[job], N = jb.N[job];
  const int total = K * N;
  _Float16* dh = (_Float16*)(ws + jb.off[job]);
  const float* src = jb.src[job];
  const int m = jb.mode[job];
  for (int idx = blockIdx.x*256 + threadIdx.x; idx < total; idx += gridDim.x*256){
    int n = idx / K, k = idx - n*K;
    float v = src[(size_t)k*N + n];
    _Float16 h = (_Float16)v;
    dh[idx] = h;
    if (m) dh[total + idx] = (_Float16)(v - (float)h);
  }
}

// ------------------------------------------------- K0w: gate-tail precompute
__global__ __launch_bounds__(256) void k0w_gate(
    const float* __restrict__ Wout, const float* __restrict__ Wg2,
    const float* __restrict__ bo,   const float* __restrict__ Win,
    _Float16* __restrict__ wveff, float* __restrict__ beff)
{
  __shared__ float weff_s[256*2];
  const int tid = threadIdx.x;
  {
    float a0 = 0.f, a1 = 0.f;
    const float* wr = Wout + (size_t)tid*256;
    for (int f = 0; f < 256; ++f){ float x = wr[f]; a0 += x*Wg2[2*f]; a1 += x*Wg2[2*f+1]; }
    weff_s[tid*2] = a0; weff_s[tid*2+1] = a1;
  }
  if (tid < 2){
    float s = 0.f;
    for (int f = 0; f < 256; ++f) s += bo[f]*Wg2[2*f + tid];
    beff[tid] = s;
  }
  __syncthreads();
  {
    const int j = tid;
    for (int n = 0; n < 16; ++n){
      float v = 0.f;
      if (n < 8){
        int h = n >> 1, c = n & 1;
        const float* wr = Win + (size_t)j*768 + 512 + h*64;
        const float* we = weff_s + (h*64)*2 + c;
        for (int d = 0; d < 64; ++d) v += wr[d]*we[2*d];
      }
      _Float16 hi = (_Float16)v;
      wveff[n*256 + j] = hi;
      wveff[16*256 + n*256 + j] = (_Float16)(v - (float)hi);
    }
  }
}

// -------------------------------------------- K1 fused: branch2 + gate roles
// 4096 blocks x 512 threads. Blocks 0..2047: branch2 (br = bid>>10, pair
// p = bid&1023 -> items 2p,2p+1). Blocks 2048..4095: gate (item = bid-2048).
__global__ __launch_bounds__(512) void k1_all(
    const float* __restrict__ ent, const float* __restrict__ om, const float* __restrict__ em,
    // branch2 weights
    const _Float16* __restrict__ W1a, const float* __restrict__ b1a,
    const _Float16* __restrict__ WINa,
    const _Float16* __restrict__ WOUTa, const float* __restrict__ boa,
    float* __restrict__ x2outa,
    const _Float16* __restrict__ W1b, const float* __restrict__ b1b,
    const _Float16* __restrict__ WINb,
    const _Float16* __restrict__ WOUTb, const float* __restrict__ bob,
    float* __restrict__ x2outb,
    // gate weights
    const _Float16* __restrict__ W1g, const float* __restrict__ b1g,
    const _Float16* __restrict__ WINg,
    const _Float16* __restrict__ WVEFF,
    const float* __restrict__ beff, const float* __restrict__ gb2,
    float* __restrict__ og, float* __restrict__ gate)
{
  const int tid = threadIdx.x;
  const int w = tid >> 6, lg = (tid >> 4) & 3, li = tid & 15;
  extern __shared__ char smem[];

  if (blockIdx.x < 2048){
    // ============================ branch2 role ============================
    const int br = blockIdx.x >> 10;
    const int p  = blockIdx.x & 1023;
    const int bb2[2] = { 2*p, 2*p + 1 };
    const _Float16* W1   = br ? W1b   : W1a;
    const float*    b1   = br ? b1b   : b1a;
    const _Float16* WIN  = br ? WINb  : WINa;
    const _Float16* WOUT = br ? WOUTb : WOUTa;
    const float*    bo   = br ? bob   : boa;
    float*          x2out= br ? x2outb: x2outa;

    const int wi = w & 3, ih = w >> 2;

    _Float16* x1  = (_Float16*)smem;               // [2][64*264]  67584 B
    _Float16* Ks  = (_Float16*)(smem + 67584);     // [2][64*72]   18432 B
    _Float16* Vs  = (_Float16*)(smem + 86016);     // [2][64*72]T  18432 B
    _Float16* Qs  = (_Float16*)(smem + 104448);    // [2][16*72]    4608 B
    float*    lgs = (float*)(smem + 109056);       // [2][16*72]    9216 B
    _Float16* Ps  = (_Float16*)(smem + 118272);    // [2][16*72]    4608 B
    float*    outp= (float*)(smem + 122880);       // [2][16*264]  33792 B

    // ---- phase 1: x1 = relu(ent @ W1 + b1); wave -> item ih, col-group wi
    {
      const int b = bb2[ih];
      _Float16* x1p = x1 + ih*16896;
      f32x4 acc[4][4];
#pragma unroll
      for (int r = 0; r < 4; ++r)
#pragma unroll
        for (int c = 0; c < 4; ++c) acc[r][c] = 0.f;
#pragma unroll
      for (int kk = 0; kk < 3; ++kk){
        AB<0> a[4];
#pragma unroll
        for (int r = 0; r < 4; ++r)
          a[r] = ldF<0>(ent + ((size_t)b*64 + 16*r + li)*96 + kk*32 + lg*8);
#pragma unroll
        for (int c = 0; c < 4; ++c){
          f16x8 B = *(const f16x8*)(W1 + (size_t)(64*wi + 16*c + li)*96 + kk*32 + lg*8);
#pragma unroll
          for (int r = 0; r < 4; ++r) acc[r][c] = mfma16(a[r].hi, B, acc[r][c]);
        }
      }
#pragma unroll
      for (int c = 0; c < 4; ++c){
        int col = 64*wi + 16*c + li;
        float bias = b1[col];
#pragma unroll
        for (int r = 0; r < 4; ++r)
#pragma unroll
          for (int j = 0; j < 4; ++j){
            float v = fmaxf(acc[r][c][j] + bias, 0.f);
            x1p[(16*r + 4*lg + j)*264 + col] = (_Float16)v;
          }
      }
    }
    __syncthreads();

    // ---- phase 2: per-head attention
    for (int h = 0; h < 4; ++h){
      { // K_h
        f32x4 acc[2][2];
#pragma unroll
        for (int it = 0; it < 2; ++it)
#pragma unroll
          for (int c = 0; c < 2; ++c) acc[it][c] = 0.f;
        for (int kk = 0; kk < 8; ++kk){
          int ao = (16*wi + li)*264 + kk*32 + lg*8;
          f16x8 A0 = *(const f16x8*)(x1 + ao);
          f16x8 A1 = *(const f16x8*)(x1 + 16896 + ao);
#pragma unroll
          for (int cc = 0; cc < 2; ++cc){
            int c = 2*ih + cc;
            f16x8 B = *(const f16x8*)(WIN + (size_t)(256 + 64*h + 16*c + li)*256 + kk*32 + lg*8);
            acc[0][cc] = mfma16(A0, B, acc[0][cc]);
            acc[1][cc] = mfma16(A1, B, acc[1][cc]);
          }
        }
#pragma unroll
        for (int it = 0; it < 2; ++it)
#pragma unroll
          for (int cc = 0; cc < 2; ++cc){
            int c = 2*ih + cc;
#pragma unroll
            for (int j = 0; j < 4; ++j)
              Ks[it*4608 + (16*wi + 4*lg + j)*72 + 16*c + li] = (_Float16)acc[it][cc][j];
          }
      }
      { // V_h (stored transposed)
        f32x4 acc[2][2];
#pragma unroll
        for (int it = 0; it < 2; ++it)
#pragma unroll
          for (int c = 0; c < 2; ++c) acc[it][c] = 0.f;
        for (int kk = 0; kk < 8; ++kk){
          int ao = (16*wi + li)*264 + kk*32 + lg*8;
          f16x8 A0 = *(const f16x8*)(x1 + ao);
          f16x8 A1 = *(const f16x8*)(x1 + 16896 + ao);
#pragma unroll
          for (int cc = 0; cc < 2; ++cc){
            int c = 2*ih + cc;
            f16x8 B = *(const f16x8*)(WIN + (size_t)(512 + 64*h + 16*c + li)*256 + kk*32 + lg*8);
            acc[0][cc] = mfma16(A0, B, acc[0][cc]);
            acc[1][cc] = mfma16(A1, B, acc[1][cc]);
          }
        }
#pragma unroll
        for (int it = 0; it < 2; ++it)
#pragma unroll
          for (int cc = 0; cc < 2; ++cc){
            int c = 2*ih + cc;
#pragma unroll
            for (int j = 0; j < 4; ++j)
              Vs[it*4608 + (16*c + li)*72 + 16*wi + 4*lg + j] = (_Float16)acc[it][cc][j];
          }
      }
      { // Q_h
        f32x4 acc = 0.f;
        for (int kk = 0; kk < 8; ++kk){
          f16x8 A = *(const f16x8*)(x1 + ih*16896 + li*264 + kk*32 + lg*8);
          f16x8 B = *(const f16x8*)(WIN + (size_t)(64*h + 16*wi + li)*256 + kk*32 + lg*8);
          acc = mfma16(A, B, acc);
        }
#pragma unroll
        for (int j = 0; j < 4; ++j)
          Qs[ih*1152 + (4*lg + j)*72 + 16*wi + li] = (_Float16)acc[j];
      }
      __syncthreads();
      { // logits
        const int b = bb2[ih];
        f32x4 acc = 0.f;
#pragma unroll
        for (int kk = 0; kk < 2; ++kk){
          f16x8 A = *(const f16x8*)(Qs + ih*1152 + li*72 + kk*32 + lg*8);
          f16x8 B = *(const f16x8*)(Ks + ih*4608 + (16*wi + li)*72 + kk*32 + lg*8);
          acc = mfma16(A, B, acc);
        }
#pragma unroll
        for (int j = 0; j < 4; ++j){
          int q = 4*lg + j, key = 16*wi + li;
          float v = acc[j] * 0.125f;
          float m = om[((size_t)b*64 + q)*64 + key];
          if (m > 0.f) v = -1e9f;
          lgs[ih*1152 + q*72 + key] = v;
        }
      }
      __syncthreads();
      { // softmax
        const int it = tid >> 8, q = (tid >> 4) & 15, i16 = tid & 15;
        const int b = bb2[it];
        float pv[4], mx = -3e38f;
#pragma unroll
        for (int u = 0; u < 4; ++u){ pv[u] = lgs[it*1152 + q*72 + i16 + 16*u]; mx = fmaxf(mx, pv[u]); }
#pragma unroll
        for (int d = 1; d < 16; d <<= 1) mx = fmaxf(mx, __shfl_xor(mx, d, 16));
        float s = 0.f;
#pragma unroll
        for (int u = 0; u < 4; ++u){ pv[u] = expf(pv[u] - mx); s += pv[u]; }
#pragma unroll
        for (int d = 1; d < 16; d <<= 1) s += __shfl_xor(s, d, 16);
#pragma unroll
        for (int u = 0; u < 4; ++u){
          int key = i16 + 16*u;
          float m = om[((size_t)b*64 + q)*64 + key];
          Ps[it*1152 + q*72 + key] = (_Float16)((pv[u]/s)*(1.f - m));
        }
      }
      __syncthreads();
      { // out_h = P @ V_h
        f32x4 acc = 0.f;
#pragma unroll
        for (int kk = 0; kk < 2; ++kk){
          f16x8 A = *(const f16x8*)(Ps + ih*1152 + li*72 + kk*32 + lg*8);
          f16x8 B = *(const f16x8*)(Vs + ih*4608 + (16*wi + li)*72 + kk*32 + lg*8);
          acc = mfma16(A, B, acc);
        }
#pragma unroll
        for (int j = 0; j < 4; ++j)
          outp[ih*4224 + (4*lg + j)*264 + 64*h + 16*wi + li] = acc[j];
      }
      __syncthreads();
    }

    // ---- phase 3: out-proj
    {
      f32x4 acc[2][2];
#pragma unroll
      for (int it = 0; it < 2; ++it)
#pragma unroll
        for (int c = 0; c < 2; ++c) acc[it][c] = 0.f;
      for (int kk = 0; kk < 8; ++kk){
        AB<0> a0 = ldF<0>(outp + li*264 + kk*32 + lg*8);
        AB<0> a1 = ldF<0>(outp + 4224 + li*264 + kk*32 + lg*8);
#pragma unroll
        for (int cc = 0; cc < 2; ++cc){
          int c = 2*ih + cc;
          f16x8 B = *(const f16x8*)(WOUT + (size_t)(64*wi + 16*c + li)*256 + kk*32 + lg*8);
          acc[0][cc] = mfma16(a0.hi, B, acc[0][cc]);
          acc[1][cc] = mfma16(a1.hi, B, acc[1][cc]);
        }
      }
#pragma unroll
      for (int it = 0; it < 2; ++it){
        const int b = bb2[it];
#pragma unroll
        for (int cc = 0; cc < 2; ++cc){
          int col = 64*wi + 16*(2*ih + cc) + li;
          float bias = bo[col];
#pragma unroll
          for (int j = 0; j < 4; ++j){
            int q = 4*lg + j;
            float v = (acc[it][cc][j] + bias) * (1.f - em[(size_t)b*64 + q]);
            x2out[((size_t)b*16 + q)*256 + col] = v;
          }
        }
      }
    }
    return;
  }

  // ============================== gate role ==============================
  {
    constexpr int W1SZ = 96*256, WINSZ = 256*768, WVSZ = 16*256;
    const int b = blockIdx.x - 2048;

    char* sp = smem;
    _Float16* x1h = (_Float16*)sp; sp += 64*264*2;
    _Float16* x1l = (_Float16*)sp; sp += 64*264*2;
    _Float16* Kh  = (_Float16*)sp; sp += 64*72*2;
    _Float16* Kl  = (_Float16*)sp; sp += 64*72*2;
    _Float16* Qh  = (_Float16*)sp; sp += 16*264*2;
    _Float16* Ql  = (_Float16*)sp; sp += 16*264*2;
    float*    lgs = (float*)sp;    sp += 16*72*4;
    float*    Ps  = (float*)sp;    sp += 16*66*4;
    float*    v2s = (float*)sp;    sp += 64*18*4;
    float*  ogacc = (float*)sp;    sp += 32*4;

    // ---- phase 1: x1 = relu(ent @ W1 + b1)
    {
      const int mt = w >> 1;
      f32x4 acc[8];
#pragma unroll
      for (int c = 0; c < 8; ++c) acc[c] = 0.f;
#pragma unroll
      for (int kk = 0; kk < 3; ++kk){
        AB<1> a = ldF<1>(ent + ((size_t)b*64 + mt*16 + li)*96 + kk*32 + lg*8);
#pragma unroll
        for (int c = 0; c < 8; ++c){
          int nt = (w & 1)*8 + c;
          AB<1> bb = ldW<1>(W1g + (size_t)(nt*16 + li)*96 + kk*32 + lg*8, W1SZ);
          a.mf(bb, acc[c]);
        }
      }
#pragma unroll
      for (int c = 0; c < 8; ++c){
        int col = ((w & 1)*8 + c)*16 + li;
        float bias = b1g[col];
#pragma unroll
        for (int j = 0; j < 4; ++j){
          float v = fmaxf(acc[c][j] + bias, 0.f);
          stL<1>(x1h, x1l, (mt*16 + 4*lg + j)*264 + col, v);
        }
      }
    }
    if (tid < 32) ogacc[tid] = 0.f;
    __syncthreads();

    // ---- phase 2: Qfull, v2
    {
#pragma unroll
      for (int s = 0; s < 2; ++s){
        int nt = w + s*8;
        f32x4 acc = 0.f;
        for (int kk = 0; kk < 8; ++kk){
          int ao = li*264 + kk*32 + lg*8;
          AB<1> a = ldL<1>(x1h + ao, x1l + ao);
          AB<1> bb = ldW<1>(WINg + (size_t)(nt*16 + li)*256 + kk*32 + lg*8, WINSZ);
          a.mf(bb, acc);
        }
#pragma unroll
        for (int j = 0; j < 4; ++j)
          stL<1>(Qh, Ql, (4*lg + j)*264 + nt*16 + li, acc[j]);
      }
      if (w < 4){
        f32x4 acc = 0.f;
        for (int kk = 0; kk < 8; ++kk){
          int ao = (w*16 + li)*264 + kk*32 + lg*8;
          AB<1> a = ldL<1>(x1h + ao, x1l + ao);
          AB<1> bb = ldW<1>(WVEFF + (size_t)li*256 + kk*32 + lg*8, WVSZ);
          a.mf(bb, acc);
        }
#pragma unroll
        for (int j = 0; j < 4; ++j)
          v2s[(w*16 + 4*lg + j)*18 + li] = acc[j];
      }
    }
    __syncthreads();

    // ---- head loop
    for (int h = 0; h < 4; ++h){
      {
        const int mt = w >> 1;
        f32x4 acc[2];
        acc[0] = 0.f; acc[1] = 0.f;
        for (int kk = 0; kk < 8; ++kk){
          int ao = (mt*16 + li)*264 + kk*32 + lg*8;
          AB<1> a = ldL<1>(x1h + ao, x1l + ao);
#pragma unroll
          for (int c = 0; c < 2; ++c){
            int nt = (w & 1)*2 + c;
            AB<1> bb = ldW<1>(WINg + (size_t)(256 + h*64 + nt*16 + li)*256 + kk*32 + lg*8, WINSZ);
            a.mf(bb, acc[c]);
          }
        }
#pragma unroll
        for (int c = 0; c < 2; ++c){
          int colb = ((w & 1)*2 + c)*16 + li;
#pragma unroll
          for (int j = 0; j < 4; ++j)
            stL<1>(Kh, Kl, (mt*16 + 4*lg + j)*72 + colb, acc[c][j]);
        }
      }
      __syncthreads();
      if (w < 4){
        f32x4 acc = 0.f;
#pragma unroll
        for (int kk = 0; kk < 2; ++kk){
          int ao = li*264 + h*64 + kk*32 + lg*8;
          AB<1> a = ldL<1>(Qh + ao, Ql + ao);
          int bo_ = (16*w + li)*72 + kk*32 + lg*8;
          AB<1> bb = ldL<1>(Kh + bo_, Kl + bo_);
          a.mf(bb, acc);
        }
#pragma unroll
        for (int j = 0; j < 4; ++j){
          int q = 4*lg + j, key = 16*w + li;
          float v = acc[j] * 0.125f;
          float m = om[((size_t)b*64 + q)*64 + key];
          if (m > 0.f) v = -1e9f;
          lgs[q*72 + key] = v;
        }
      }
      __syncthreads();
      if (tid < 256){
        int q = tid >> 4, i16 = tid & 15;
        float pv[4], mx = -3e38f;
#pragma unroll
        for (int u = 0; u < 4; ++u){ pv[u] = lgs[q*72 + i16 + 16*u]; mx = fmaxf(mx, pv[u]); }
#pragma unroll
        for (int d = 1; d < 16; d <<= 1) mx = fmaxf(mx, __shfl_xor(mx, d, 16));
        float s = 0.f;
#pragma unroll
        for (int u = 0; u < 4; ++u){ pv[u] = expf(pv[u] - mx); s += pv[u]; }
#pragma unroll
        for (int d = 1; d < 16; d <<= 1) s += __shfl_xor(s, d, 16);
#pragma unroll
        for (int u = 0; u < 4; ++u){
          int key = i16 + 16*u;
          float m = om[((size_t)b*64 + q)*64 + key];
          Ps[q*66 + key] = (pv[u]/s)*(1.f - m);
        }
      }
      __syncthreads();
      if (tid < 256){
        int q = tid >> 4, l16 = tid & 15;
        float a0 = 0.f, a1 = 0.f;
#pragma unroll
        for (int u = 0; u < 4; ++u){
          int k = l16 + 16*u;
          float p2 = Ps[q*66 + k];
          a0 += p2 * v2s[k*18 + h*2];
          a1 += p2 * v2s[k*18 + h*2 + 1];
        }
#pragma unroll
        for (int d = 1; d < 16; d <<= 1){ a0 += __shfl_xor(a0, d, 16); a1 += __shfl_xor(a1, d, 16); }
        if (l16 == 0){ ogacc[q*2] += a0; ogacc[q*2 + 1] += a1; }
      }
      __syncthreads();
    }
    if (tid < 16){
      int q = tid;
      float am = em[(size_t)b*64 + q];
      float g0 = (1.f - am)*(ogacc[2*q]     + beff[0]) + gb2[0];
      float g1 = (1.f - am)*(ogacc[2*q + 1] + beff[1]) + gb2[1];
      og[((size_t)b*16 + q)*2]     = g0;
      og[((size_t)b*16 + q)*2 + 1] = g1;
      gate[(size_t)b*16 + q] = (g1 > g0) ? 1.f : 0.f;
    }
  }
}

// ----------------------------------------- K2: gate, global attention, fc2, gi
__global__ __launch_bounds__(256) void k2_global(
    const float* __restrict__ em,
    const float* __restrict__ x2, const float* __restrict__ x2m,
    const float* __restrict__ gate,
    const _Float16* __restrict__ GMIN, const _Float16* __restrict__ GMOUT, const float* __restrict__ gob,
    const _Float16* __restrict__ FC2T, const float* __restrict__ fc2b,
    const _Float16* __restrict__ GIHT, const float* __restrict__ gib,
    float* __restrict__ gi)
{
  const int b = blockIdx.x;
  const int tid = threadIdx.x;
  const int w = tid >> 6, lg = (tid >> 4) & 3, li = tid & 15;

  __shared__ float gate_s[16];
  __shared__ __align__(16) _Float16 gm_s[16*264];
  __shared__ __align__(16) _Float16 Q2[16*72];
  __shared__ __align__(16) _Float16 K2s[16*72];
  __shared__ __align__(16) _Float16 Vt2[64*40];
  __shared__ float lg2[16*24];
  __shared__ __align__(16) _Float16 P2[16*40];
  __shared__ __align__(16) float outp[16*264];
  __shared__ __align__(16) _Float16 cat_s[16*520];
  __shared__ __align__(16) _Float16 x3_s[16*264];

  if (tid < 16) gate_s[tid] = gate[(size_t)b*16 + tid];
  __syncthreads();
  for (int idx = tid; idx < 4096; idx += 256){
    int q = idx >> 8, d = idx & 255;
    gm_s[q*264 + d]  = (_Float16)(x2m[((size_t)b*16 + q)*256 + d] * gate_s[q]);
    cat_s[q*520 + d] = (_Float16)(x2[((size_t)b*16 + q)*256 + d]);
  }
  for (int idx = tid; idx < 64*40; idx += 256) Vt2[idx] = (_Float16)0.f;
  for (int idx = tid; idx < 16*40; idx += 256) P2[idx] = (_Float16)0.f;
  __syncthreads();
  for (int h = 0; h < 4; ++h){
    {
      f32x4 aq = 0.f, ak = 0.f, av = 0.f;
      for (int kk = 0; kk < 8; ++kk){
        f16x8 A  = *(const f16x8*)(gm_s + li*264 + kk*32 + lg*8);
        f16x8 Bq = *(const f16x8*)(GMIN + (size_t)(      64*h + 16*w + li)*256 + kk*32 + lg*8);
        f16x8 Bk = *(const f16x8*)(GMIN + (size_t)(256 + 64*h + 16*w + li)*256 + kk*32 + lg*8);
        f16x8 Bv = *(const f16x8*)(GMIN + (size_t)(512 + 64*h + 16*w + li)*256 + kk*32 + lg*8);
        aq = mfma16(A, Bq, aq); ak = mfma16(A, Bk, ak); av = mfma16(A, Bv, av);
      }
#pragma unroll
      for (int j = 0; j < 4; ++j){
        int rw = 4*lg + j, dim = 16*w + li;
        Q2[rw*72 + dim]  = (_Float16)aq[j];
        K2s[rw*72 + dim] = (_Float16)ak[j];
        Vt2[dim*40 + rw] = (_Float16)av[j];
      }
    }
    __syncthreads();
    if (w == 0){
      f32x4 acc = 0.f;
#pragma unroll
      for (int kk = 0; kk < 2; ++kk){
        f16x8 A = *(const f16x8*)(Q2  + li*72 + kk*32 + lg*8);
        f16x8 B = *(const f16x8*)(K2s + li*72 + kk*32 + lg*8);
        acc = mfma16(A, B, acc);
      }
      float amk = em[(size_t)b*64 + li];
#pragma unroll
      for (int j = 0; j < 4; ++j){
        int q = 4*lg + j;
        float amq = em[(size_t)b*64 + q];
        float m = 1.f - (1.f - amq)*(1.f - amk);
        float v = acc[j]*0.125f;
        if (m > 0.f) v = -1e9f;
        lg2[q*24 + li] = v;
      }
    }
    __syncthreads();
    {
      int q = tid >> 4, key = tid & 15;
      float v = lg2[q*24 + key];
      float mx = v;
#pragma unroll
      for (int d = 1; d < 16; d <<= 1) mx = fmaxf(mx, __shfl_xor(mx, d, 16));
      float pe = expf(v - mx);
      float s = pe;
#pragma unroll
      for (int d = 1; d < 16; d <<= 1) s += __shfl_xor(s, d, 16);
      float amq = em[(size_t)b*64 + q], amk = em[(size_t)b*64 + key];
      float m = 1.f - (1.f - amq)*(1.f - amk);
      P2[q*40 + key] = (_Float16)((pe/s)*(1.f - m));
    }
    __syncthreads();
    {
      f32x4 acc = 0.f;
      f16x8 A = *(const f16x8*)(P2 + li*40 + lg*8);
      f16x8 B = *(const f16x8*)(Vt2 + (16*w + li)*40 + lg*8);
      acc = mfma16(A, B, acc);
#pragma unroll
      for (int j = 0; j < 4; ++j)
        outp[(4*lg + j)*264 + 64*h + 16*w + li] = acc[j];
    }
    __syncthreads();
  }
  {
    f32x4 acc[4];
#pragma unroll
    for (int c = 0; c < 4; ++c) acc[c] = 0.f;
    for (int kk = 0; kk < 8; ++kk){
      const float* ap = outp + li*264 + kk*32 + lg*8;
      f32x4 v0 = *(const f32x4*)ap, v1 = *(const f32x4*)(ap + 4);
      f16x8 A;
#pragma unroll
      for (int e = 0; e < 4; ++e){ A[e] = (_Float16)v0[e]; A[e+4] = (_Float16)v1[e]; }
#pragma unroll
      for (int c = 0; c < 4; ++c){
        f16x8 B = *(const f16x8*)(GMOUT + (size_t)(64*w + 16*c + li)*256 + kk*32 + lg*8);
        acc[c] = mfma16(A, B, acc[c]);
      }
    }
#pragma unroll
    for (int c = 0; c < 4; ++c){
      int col = 64*w + 16*c + li;
      float bias = gob[col];
#pragma unroll
      for (int j = 0; j < 4; ++j){
        int q = 4*lg + j;
        float v = (acc[c][j] + bias)*(1.f - em[(size_t)b*64 + q]);
        cat_s[q*520 + 256 + col] = (_Float16)v;
      }
    }
  }
  __syncthreads();
  {
    f32x4 acc[4];
#pragma unroll
    for (int c = 0; c < 4; ++c) acc[c] = 0.f;
    for (int kk = 0; kk < 16; ++kk){
      f16x8 A = *(const f16x8*)(cat_s + li*520 + kk*32 + lg*8);
#pragma unroll
      for (int c = 0; c < 4; ++c){
        f16x8 B = *(const f16x8*)(FC2T + (size_t)(64*w + 16*c + li)*512 + kk*32 + lg*8);
        acc[c] = mfma16(A, B, acc[c]);
      }
    }
#pragma unroll
    for (int c = 0; c < 4; ++c){
      int col = 64*w + 16*c + li;
      float bias = fc2b[col];
#pragma unroll
      for (int j = 0; j < 4; ++j)
        x3_s[(4*lg + j)*264 + col] = (_Float16)fmaxf(acc[c][j] + bias, 0.f);
    }
  }
  __syncthreads();
  {
    const int r0 = (b >> 6)*16, t = b & 63;
    f32x4 acc[12];
#pragma unroll
    for (int cc = 0; cc < 12; ++cc) acc[cc] = 0.f;
    for (int kk = 0; kk < 8; ++kk){
      f16x8 A = *(const f16x8*)(x3_s + li*264 + kk*32 + lg*8);
#pragma unroll
      for (int cc = 0; cc < 12; ++cc){
        int col = (w*12 + cc)*16 + li;
        f16x8 B = *(const f16x8*)(GIHT + (size_t)col*256 + kk*32 + lg*8);
        acc[cc] = mfma16(A, B, acc[cc]);
      }
    }
#pragma unroll
    for (int cc = 0; cc < 12; ++cc){
      int col = (w*12 + cc)*16 + li;
      float bias = gib[col];
#pragma unroll
      for (int j = 0; j < 4; ++j){
        int q = 4*lg + j;
        gi[((size_t)((r0 + q)*64 + t))*768 + col] = acc[cc][j] + bias;
      }
    }
  }
}

// ------------------------------------------------------------------ K3: GRU
__global__ __launch_bounds__(256) void k3_gru(
    const _Float16* __restrict__ WHH, const float* __restrict__ bhh,
    const float* __restrict__ gi, const float* __restrict__ h0,
    float* __restrict__ hs)
{
  const int rb = blockIdx.x;
  const int row0 = rb * 16;
  const int tid = threadIdx.x;
  const int w = tid >> 6, lg = (tid >> 4) & 3, li = tid & 15;

  extern __shared__ char smem3[];
  _Float16* hf16 = (_Float16*)smem3;
  float* hf32 = (float*)(smem3 + 8448);
  float* gh   = (float*)(smem3 + 8448 + 16640);
  float* bhs  = (float*)(smem3 + 8448 + 16640 + 49664);

  for (int idx = tid; idx < 768; idx += 256) bhs[idx] = bhh[idx];
  for (int idx = tid; idx < 4096; idx += 256){
    int r = idx >> 8, d = idx & 255;
    float v = h0[(size_t)(row0 + r)*256 + d];
    hf32[r*260 + d] = v;
    hf16[r*264 + d] = (_Float16)v;
  }
  __syncthreads();

  const int er = tid >> 4;
  const int d0 = (tid & 15) * 16;

  for (int t = 0; t < 64; ++t){
    const float* gp = gi + ((size_t)(row0 + er)*64 + t)*768 + d0;
    f32x4 gr[4], gz[4], gn[4];
#pragma unroll
    for (int v = 0; v < 4; ++v){
      gr[v] = *(const f32x4*)(gp + v*4);
      gz[v] = *(const f32x4*)(gp + 256 + v*4);
      gn[v] = *(const f32x4*)(gp + 512 + v*4);
    }
    f16x8 a[8];
#pragma unroll
    for (int kk = 0; kk < 8; ++kk)
      a[kk] = *(const f16x8*)(hf16 + li*264 + kk*32 + lg*8);
    f32x4 acc[12];
#pragma unroll
    for (int c = 0; c < 12; ++c) acc[c] = 0.f;
#pragma unroll
    for (int c = 0; c < 12; ++c){
      const _Float16* bp = WHH + (size_t)(w*192 + c*16 + li)*256 + lg*8;
#pragma unroll
      for (int kk = 0; kk < 8; ++kk)
        acc[c] = mfma16(a[kk], *(const f16x8*)(bp + kk*32), acc[c]);
    }
#pragma unroll
    for (int c = 0; c < 12; ++c){
      int col = w*192 + c*16 + li;
#pragma unroll
      for (int j = 0; j < 4; ++j)
        gh[(4*lg + j)*776 + col] = acc[c][j];
    }
    __syncthreads();
    {
      float* hp32 = hf32 + er*260 + d0;
      float* hsp  = hs + ((size_t)(rb*64 + t)*16 + er)*256 + d0;
      f16x8 hv8[2];
#pragma unroll
      for (int v = 0; v < 4; ++v){
        f32x4 xr = *(const f32x4*)(gh + er*776 +       d0 + v*4);
        f32x4 xz = *(const f32x4*)(gh + er*776 + 256 + d0 + v*4);
        f32x4 xn = *(const f32x4*)(gh + er*776 + 512 + d0 + v*4);
        f32x4 hold = *(const f32x4*)(hp32 + v*4);
        f32x4 hout;
#pragma unroll
        for (int e = 0; e < 4; ++e){
          int d = d0 + v*4 + e;
          float rr_ = 1.f/(1.f + expf(-(gr[v][e] + xr[e] + bhs[d])));
          float zz  = 1.f/(1.f + expf(-(gz[v][e] + xz[e] + bhs[256 + d])));
          float nn  = tanhf(gn[v][e] + rr_*(xn[e] + bhs[512 + d]));
          float hv = (1.f - zz)*nn + zz*hold[e];
          hout[e] = hv;
          int sl = v*4 + e;
          hv8[sl >> 3][sl & 7] = (_Float16)hv;
        }
        *(f32x4*)(hp32 + v*4) = hout;
        *(f32x4*)(hsp + v*4)  = hout;
      }
      *(f16x8*)(hf16 + er*264 + d0)     = hv8[0];
      *(f16x8*)(hf16 + er*264 + d0 + 8) = hv8[1];
    }
    __syncthreads();
  }
}

// ------------------------------------------------------------------ K4: q out
__global__ __launch_bounds__(256) void k4_q(
    const _Float16* __restrict__ FC3T, const float* __restrict__ fc3b,
    const float* __restrict__ em, const float* __restrict__ hs, float* __restrict__ qo)
{
  const int tid = threadIdx.x;
  const int w = tid >> 6, lg = (tid >> 4) & 3, li = tid & 15;
  const int rb = blockIdx.x*64 + 16*w;
  f32x4 acc[2];
#pragma unroll
  for (int c = 0; c < 2; ++c) acc[c] = 0.f;
  for (int kk = 0; kk < 8; ++kk){
    const float* ap = hs + (size_t)(rb + li)*256 + kk*32 + lg*8;
    f32x4 v0 = *(const f32x4*)ap, v1 = *(const f32x4*)(ap + 4);
    f16x8 A;
#pragma unroll
    for (int e = 0; e < 4; ++e){ A[e] = (_Float16)v0[e]; A[e+4] = (_Float16)v1[e]; }
#pragma unroll
    for (int c = 0; c < 2; ++c){
      f16x8 B = *(const f16x8*)(FC3T + (size_t)(16*c + li)*256 + kk*32 + lg*8);
      acc[c] = mfma16(A, B, acc[c]);
    }
  }
#pragma unroll
  for (int c = 0; c < 2; ++c){
    int col = 16*c + li;
    float bias = fc3b[col];
#pragma unroll
    for (int j = 0; j < 4; ++j){
      int row = rb + 4*lg + j;
      float am = em[(size_t)(row >> 4)*64 + (row & 15)];
      qo[(size_t)row*32 + col] = (acc[c][j] + bias)*(1.f - am);
    }
  }
}

// --------------------------------------------------------------------- launch
extern "C" void kernel_launch(void* const* d_in, const int* in_sizes, int n_in,
                              void* d_out, int out_size, void* d_ws, size_t ws_size,
                              hipStream_t stream)
{
  // ws layout (bytes) — r3 layout
  constexpr size_t OFF_FC1T   = 0;
  constexpr size_t OFF_MSG1T  = 49152;
  constexpr size_t OFF_AINT   = 98304;
  constexpr size_t OFF_LINT   = 491520;
  constexpr size_t OFF_AOUTT  = 884736;
  constexpr size_t OFF_LOUTT  = 1015808;
  constexpr size_t OFF_GMINT  = 1146880;
  constexpr size_t OFF_GMOUTT = 1540096;
  constexpr size_t OFF_FC2T   = 1671168;
  constexpr size_t OFF_GIHT   = 1933312;
  constexpr size_t OFF_GHHT   = 2326528;
  constexpr size_t OFF_FC3T   = 2719744;
  constexpr size_t OFF_G1T    = 2736128;   // f16 hi+lo pair
  constexpr size_t OFF_GINT   = 2834432;   // pair
  constexpr size_t OFF_WVEFF  = 3620864;   // pair
  constexpr size_t OFF_BEFF   = 3637248;
  constexpr size_t OFF_GATE   = 3637504;   // 131072
  constexpr size_t OFF_X2     = 3768576;   // 33554432
  constexpr size_t OFF_X2M    = 37323008;  // 33554432
  constexpr size_t OFF_GI     = 70877440;  // 100663296
  constexpr size_t NEED       = 171540736;
  if (ws_size < NEED) return;

  char* ws = (char*)d_ws;
  const float* ent = (const float*)d_in[0];
  const float* om  = (const float*)d_in[1];
  const float* em  = (const float*)d_in[2];

  WJobs jb{};
  int nj = 0;
  auto addj = [&](int src_idx, size_t off, int K, int N, int m){
    jb.src[nj] = (const float*)d_in[src_idx]; jb.off[nj] = (unsigned)off;
    jb.K[nj] = K; jb.N[nj] = N; jb.mode[nj] = m; ++nj;
  };
  addj(4,  OFF_FC1T,   96, 256, 0);
  addj(17, OFF_MSG1T,  96, 256, 0);
  addj(6,  OFF_AINT,  256, 768, 0);
  addj(19, OFF_LINT,  256, 768, 0);
  addj(7,  OFF_AOUTT, 256, 256, 0);
  addj(20, OFF_LOUTT, 256, 256, 0);
  addj(22, OFF_GMINT, 256, 768, 0);
  addj(23, OFF_GMOUTT,256, 256, 0);
  addj(9,  OFF_FC2T,  512, 256, 0);
  addj(11, OFF_GIHT,  256, 768, 0);
  addj(12, OFF_GHHT,  256, 768, 0);
  addj(15, OFF_FC3T,  256,  32, 0);
  addj(28, OFF_G1T,    96, 256, 1);
  addj(25, OFF_GINT,  256, 768, 1);
  k0_conv<<<dim3(96, nj), 256, 0, stream>>>(jb, ws);

  // gate-tail precompute: Weff/Wveff/beff
  k0w_gate<<<1, 256, 0, stream>>>(
      (const float*)d_in[26], (const float*)d_in[30],
      (const float*)d_in[27], (const float*)d_in[25],
      (_Float16*)(ws + OFF_WVEFF), (float*)(ws + OFF_BEFF));

  constexpr int SMB = 156672, SM3 = 77824;
  (void)hipFuncSetAttribute(reinterpret_cast<const void*>(&k1_all),
                            hipFuncAttributeMaxDynamicSharedMemorySize, SMB);
  (void)hipFuncSetAttribute(reinterpret_cast<const void*>(&k3_gru),
                            hipFuncAttributeMaxDynamicSharedMemorySize, SM3);

  float* qout = (float*)d_out;
  float* hsout = qout + 1048576;
  float* gout = qout + 9437184;

  // fused branch2 + gate: 4096 blocks, 512 threads
  k1_all<<<4096, 512, SMB, stream>>>(ent, om, em,
      (const _Float16*)(ws + OFF_FC1T),  (const float*)d_in[5],
      (const _Float16*)(ws + OFF_AINT),
      (const _Float16*)(ws + OFF_AOUTT), (const float*)d_in[8],
      (float*)(ws + OFF_X2),
      (const _Float16*)(ws + OFF_MSG1T), (const float*)d_in[18],
      (const _Float16*)(ws + OFF_LINT),
      (const _Float16*)(ws + OFF_LOUTT), (const float*)d_in[21],
      (float*)(ws + OFF_X2M),
      (const _Float16*)(ws + OFF_G1T),   (const float*)d_in[29],
      (const _Float16*)(ws + OFF_GINT),
      (const _Float16*)(ws + OFF_WVEFF),
      (const float*)(ws + OFF_BEFF), (const float*)d_in[31],
      gout, (float*)(ws + OFF_GATE));

  k2_global<<<2048, 256, 0, stream>>>(em,
      (const float*)(ws + OFF_X2), (const float*)(ws + OFF_X2M),
      (const float*)(ws + OFF_GATE),
      (const _Float16*)(ws + OFF_GMINT), (const _Float16*)(ws + OFF_GMOUTT), (const float*)d_in[24],
      (const _Float16*)(ws + OFF_FC2T), (const float*)d_in[10],
      (const _Float16*)(ws + OFF_GIHT), (const float*)d_in[13],
      (float*)(ws + OFF_GI));

  k3_gru<<<32, 256, SM3, stream>>>(
      (const _Float16*)(ws + OFF_GHHT), (const float*)d_in[14],
      (const float*)(ws + OFF_GI), (const float*)d_in[3], hsout);

  k4_q<<<512, 256, 0, stream>>>(
      (const _Float16*)(ws + OFF_FC3T), (const float*)d_in[16],
      em, hsout, qout);
}

// Round 14
// 1555.269 us; speedup vs baseline: 1.0274x; 1.0132x over previous
//
#include <hip/hip_runtime.h>

// EntityAttentionRNNMsgAgent — fused MI355X implementation.
// r14 = r13 + (1) k2 processes 2 items/block with B-fragment sharing (r10
// pattern; halves per-item L2 weight traffic, cc-outer loops keep VGPRs low;
// outp stored f16 = bit-identical to old f32->f16 cast) and (2) k3 uses
// saturation-safe __expf sigmoid/tanh (elementwise VALU was ~33% busy on
// k3's active CUs). k1_all/k0/k0w/k4 byte-identical to r13 (1575.7us).

#define DEV __device__ __forceinline__

typedef _Float16 f16x8 __attribute__((ext_vector_type(8)));
typedef float    f32x4 __attribute__((ext_vector_type(4)));

DEV f32x4 mfma16(f16x8 a, f16x8 b, f32x4 c){
  return __builtin_amdgcn_mfma_f32_16x16x32_f16(a, b, c, 0, 0, 0);
}

// A/B fragment pair for optional split-precision (MODE=1: value = hi + lo)
template<int MODE> struct AB {
  f16x8 hi, lo;
  DEV void mf(const AB& b, f32x4& c) const {
    if constexpr (MODE){
      c = mfma16(lo, b.hi, c);
      c = mfma16(hi, b.lo, c);
    }
    c = mfma16(hi, b.hi, c);
  }
};

template<int MODE> DEV AB<MODE> ldW(const _Float16* p, int losz){
  AB<MODE> r; r.hi = *(const f16x8*)p;
  if constexpr (MODE) r.lo = *(const f16x8*)(p + losz);
  return r;
}
template<int MODE> DEV AB<MODE> ldL(const _Float16* ph, const _Float16* pl){
  AB<MODE> r; r.hi = *(const f16x8*)ph;
  if constexpr (MODE) r.lo = *(const f16x8*)pl;
  return r;
}
template<int MODE> DEV AB<MODE> ldF(const float* p){
  AB<MODE> r;
  f32x4 v0 = *(const f32x4*)p, v1 = *(const f32x4*)(p + 4);
#pragma unroll
  for (int i = 0; i < 4; ++i){
    float a = v0[i], b = v1[i];
    _Float16 ah = (_Float16)a, bh = (_Float16)b;
    r.hi[i] = ah; r.hi[i+4] = bh;
    if constexpr (MODE){
      r.lo[i]   = (_Float16)(a - (float)ah);
      r.lo[i+4] = (_Float16)(b - (float)bh);
    }
  }
  return r;
}
template<int MODE> DEV void stL(_Float16* ph, _Float16* pl, int idx, float v){
  _Float16 h = (_Float16)v;
  ph[idx] = h;
  if constexpr (MODE) pl[idx] = (_Float16)(v - (float)h);
}

// ---------------------------------------------------------------- K0: weights
struct WJobs {
  const float* src[15];
  unsigned off[15];
  int K[15], N[15], mode[15];
};

__global__ __launch_bounds__(256) void k0_conv(WJobs jb, char* ws){
  const int job = blockIdx.y;
  const int K = jb.K[job], N = jb.N[job];
  const int total = K * N;
  _Float16* dh = (_Float16*)(ws + jb.off[job]);
  const float* src = jb.src[job];
  const int m = jb.mode[job];
  for (int idx = blockIdx.x*256 + threadIdx.x; idx < total; idx += gridDim.x*256){
    int n = idx / K, k = idx - n*K;
    float v = src[(size_t)k*N + n];
    _Float16 h = (_Float16)v;
    dh[idx] = h;
    if (m) dh[total + idx] = (_Float16)(v - (float)h);
  }
}

// ------------------------------------------------- K0w: gate-tail precompute
__global__ __launch_bounds__(256) void k0w_gate(
    const float* __restrict__ Wout, const float* __restrict__ Wg2,
    const float* __restrict__ bo,   const float* __restrict__ Win,
    _Float16* __restrict__ wveff, float* __restrict__ beff)
{
  __shared__ float weff_s[256*2];
  const int tid = threadIdx.x;
  {
    float a0 = 0.f, a1 = 0.f;
    const float* wr = Wout + (size_t)tid*256;
    for (int f = 0; f < 256; ++f){ float x = wr[f]; a0 += x*Wg2[2*f]; a1 += x*Wg2[2*f+1]; }
    weff_s[tid*2] = a0; weff_s[tid*2+1] = a1;
  }
  if (tid < 2){
    float s = 0.f;
    for (int f = 0; f < 256; ++f) s += bo[f]*Wg2[2*f + tid];
    beff[tid] = s;
  }
  __syncthreads();
  {
    const int j = tid;
    for (int n = 0; n < 16; ++n){
      float v = 0.f;
      if (n < 8){
        int h = n >> 1, c = n & 1;
        const float* wr = Win + (size_t)j*768 + 512 + h*64;
        const float* we = weff_s + (h*64)*2 + c;
        for (int d = 0; d < 64; ++d) v += wr[d]*we[2*d];
      }
      _Float16 hi = (_Float16)v;
      wveff[n*256 + j] = hi;
      wveff[16*256 + n*256 + j] = (_Float16)(v - (float)hi);
    }
  }
}

// -------------------------------------------- K1 fused: branch2 + gate roles
// 4096 blocks x 512 threads. Blocks 0..2047: branch2 (br = bid>>10, pair
// p = bid&1023 -> items 2p,2p+1). Blocks 2048..4095: gate (item = bid-2048).
__global__ __launch_bounds__(512) void k1_all(
    const float* __restrict__ ent, const float* __restrict__ om, const float* __restrict__ em,
    const _Float16* __restrict__ W1a, const float* __restrict__ b1a,
    const _Float16* __restrict__ WINa,
    const _Float16* __restrict__ WOUTa, const float* __restrict__ boa,
    float* __restrict__ x2outa,
    const _Float16* __restrict__ W1b, const float* __restrict__ b1b,
    const _Float16* __restrict__ WINb,
    const _Float16* __restrict__ WOUTb, const float* __restrict__ bob,
    float* __restrict__ x2outb,
    const _Float16* __restrict__ W1g, const float* __restrict__ b1g,
    const _Float16* __restrict__ WINg,
    const _Float16* __restrict__ WVEFF,
    const float* __restrict__ beff, const float* __restrict__ gb2,
    float* __restrict__ og, float* __restrict__ gate)
{
  const int tid = threadIdx.x;
  const int w = tid >> 6, lg = (tid >> 4) & 3, li = tid & 15;
  extern __shared__ char smem[];

  if (blockIdx.x < 2048){
    // ============================ branch2 role ============================
    const int br = blockIdx.x >> 10;
    const int p  = blockIdx.x & 1023;
    const int bb2[2] = { 2*p, 2*p + 1 };
    const _Float16* W1   = br ? W1b   : W1a;
    const float*    b1   = br ? b1b   : b1a;
    const _Float16* WIN  = br ? WINb  : WINa;
    const _Float16* WOUT = br ? WOUTb : WOUTa;
    const float*    bo   = br ? bob   : boa;
    float*          x2out= br ? x2outb: x2outa;

    const int wi = w & 3, ih = w >> 2;

    _Float16* x1  = (_Float16*)smem;
    _Float16* Ks  = (_Float16*)(smem + 67584);
    _Float16* Vs  = (_Float16*)(smem + 86016);
    _Float16* Qs  = (_Float16*)(smem + 104448);
    float*    lgs = (float*)(smem + 109056);
    _Float16* Ps  = (_Float16*)(smem + 118272);
    float*    outp= (float*)(smem + 122880);

    {
      const int b = bb2[ih];
      _Float16* x1p = x1 + ih*16896;
      f32x4 acc[4][4];
#pragma unroll
      for (int r = 0; r < 4; ++r)
#pragma unroll
        for (int c = 0; c < 4; ++c) acc[r][c] = 0.f;
#pragma unroll
      for (int kk = 0; kk < 3; ++kk){
        AB<0> a[4];
#pragma unroll
        for (int r = 0; r < 4; ++r)
          a[r] = ldF<0>(ent + ((size_t)b*64 + 16*r + li)*96 + kk*32 + lg*8);
#pragma unroll
        for (int c = 0; c < 4; ++c){
          f16x8 B = *(const f16x8*)(W1 + (size_t)(64*wi + 16*c + li)*96 + kk*32 + lg*8);
#pragma unroll
          for (int r = 0; r < 4; ++r) acc[r][c] = mfma16(a[r].hi, B, acc[r][c]);
        }
      }
#pragma unroll
      for (int c = 0; c < 4; ++c){
        int col = 64*wi + 16*c + li;
        float bias = b1[col];
#pragma unroll
        for (int r = 0; r < 4; ++r)
#pragma unroll
          for (int j = 0; j < 4; ++j){
            float v = fmaxf(acc[r][c][j] + bias, 0.f);
            x1p[(16*r + 4*lg + j)*264 + col] = (_Float16)v;
          }
      }
    }
    __syncthreads();

    for (int h = 0; h < 4; ++h){
      {
        f32x4 acc[2][2];
#pragma unroll
        for (int it = 0; it < 2; ++it)
#pragma unroll
          for (int c = 0; c < 2; ++c) acc[it][c] = 0.f;
        for (int kk = 0; kk < 8; ++kk){
          int ao = (16*wi + li)*264 + kk*32 + lg*8;
          f16x8 A0 = *(const f16x8*)(x1 + ao);
          f16x8 A1 = *(const f16x8*)(x1 + 16896 + ao);
#pragma unroll
          for (int cc = 0; cc < 2; ++cc){
            int c = 2*ih + cc;
            f16x8 B = *(const f16x8*)(WIN + (size_t)(256 + 64*h + 16*c + li)*256 + kk*32 + lg*8);
            acc[0][cc] = mfma16(A0, B, acc[0][cc]);
            acc[1][cc] = mfma16(A1, B, acc[1][cc]);
          }
        }
#pragma unroll
        for (int it = 0; it < 2; ++it)
#pragma unroll
          for (int cc = 0; cc < 2; ++cc){
            int c = 2*ih + cc;
#pragma unroll
            for (int j = 0; j < 4; ++j)
              Ks[it*4608 + (16*wi + 4*lg + j)*72 + 16*c + li] = (_Float16)acc[it][cc][j];
          }
      }
      {
        f32x4 acc[2][2];
#pragma unroll
        for (int it = 0; it < 2; ++it)
#pragma unroll
          for (int c = 0; c < 2; ++c) acc[it][c] = 0.f;
        for (int kk = 0; kk < 8; ++kk){
          int ao = (16*wi + li)*264 + kk*32 + lg*8;
          f16x8 A0 = *(const f16x8*)(x1 + ao);
          f16x8 A1 = *(const f16x8*)(x1 + 16896 + ao);
#pragma unroll
          for (int cc = 0; cc < 2; ++cc){
            int c = 2*ih + cc;
            f16x8 B = *(const f16x8*)(WIN + (size_t)(512 + 64*h + 16*c + li)*256 + kk*32 + lg*8);
            acc[0][cc] = mfma16(A0, B, acc[0][cc]);
            acc[1][cc] = mfma16(A1, B, acc[1][cc]);
          }
        }
#pragma unroll
        for (int it = 0; it < 2; ++it)
#pragma unroll
          for (int cc = 0; cc < 2; ++cc){
            int c = 2*ih + cc;
#pragma unroll
            for (int j = 0; j < 4; ++j)
              Vs[it*4608 + (16*c + li)*72 + 16*wi + 4*lg + j] = (_Float16)acc[it][cc][j];
          }
      }
      {
        f32x4 acc = 0.f;
        for (int kk = 0; kk < 8; ++kk){
          f16x8 A = *(const f16x8*)(x1 + ih*16896 + li*264 + kk*32 + lg*8);
          f16x8 B = *(const f16x8*)(WIN + (size_t)(64*h + 16*wi + li)*256 + kk*32 + lg*8);
          acc = mfma16(A, B, acc);
        }
#pragma unroll
        for (int j = 0; j < 4; ++j)
          Qs[ih*1152 + (4*lg + j)*72 + 16*wi + li] = (_Float16)acc[j];
      }
      __syncthreads();
      {
        const int b = bb2[ih];
        f32x4 acc = 0.f;
#pragma unroll
        for (int kk = 0; kk < 2; ++kk){
          f16x8 A = *(const f16x8*)(Qs + ih*1152 + li*72 + kk*32 + lg*8);
          f16x8 B = *(const f16x8*)(Ks + ih*4608 + (16*wi + li)*72 + kk*32 + lg*8);
          acc = mfma16(A, B, acc);
        }
#pragma unroll
        for (int j = 0; j < 4; ++j){
          int q = 4*lg + j, key = 16*wi + li;
          float v = acc[j] * 0.125f;
          float m = om[((size_t)b*64 + q)*64 + key];
          if (m > 0.f) v = -1e9f;
          lgs[ih*1152 + q*72 + key] = v;
        }
      }
      __syncthreads();
      {
        const int it = tid >> 8, q = (tid >> 4) & 15, i16 = tid & 15;
        const int b = bb2[it];
        float pv[4], mx = -3e38f;
#pragma unroll
        for (int u = 0; u < 4; ++u){ pv[u] = lgs[it*1152 + q*72 + i16 + 16*u]; mx = fmaxf(mx, pv[u]); }
#pragma unroll
        for (int d = 1; d < 16; d <<= 1) mx = fmaxf(mx, __shfl_xor(mx, d, 16));
        float s = 0.f;
#pragma unroll
        for (int u = 0; u < 4; ++u){ pv[u] = expf(pv[u] - mx); s += pv[u]; }
#pragma unroll
        for (int d = 1; d < 16; d <<= 1) s += __shfl_xor(s, d, 16);
#pragma unroll
        for (int u = 0; u < 4; ++u){
          int key = i16 + 16*u;
          float m = om[((size_t)b*64 + q)*64 + key];
          Ps[it*1152 + q*72 + key] = (_Float16)((pv[u]/s)*(1.f - m));
        }
      }
      __syncthreads();
      {
        f32x4 acc = 0.f;
#pragma unroll
        for (int kk = 0; kk < 2; ++kk){
          f16x8 A = *(const f16x8*)(Ps + ih*1152 + li*72 + kk*32 + lg*8);
          f16x8 B = *(const f16x8*)(Vs + ih*4608 + (16*wi + li)*72 + kk*32 + lg*8);
          acc = mfma16(A, B, acc);
        }
#pragma unroll
        for (int j = 0; j < 4; ++j)
          outp[ih*4224 + (4*lg + j)*264 + 64*h + 16*wi + li] = acc[j];
      }
      __syncthreads();
    }

    {
      f32x4 acc[2][2];
#pragma unroll
      for (int it = 0; it < 2; ++it)
#pragma unroll
        for (int c = 0; c < 2; ++c) acc[it][c] = 0.f;
      for (int kk = 0; kk < 8; ++kk){
        AB<0> a0 = ldF<0>(outp + li*264 + kk*32 + lg*8);
        AB<0> a1 = ldF<0>(outp + 4224 + li*264 + kk*32 + lg*8);
#pragma unroll
        for (int cc = 0; cc < 2; ++cc){
          int c = 2*ih + cc;
          f16x8 B = *(const f16x8*)(WOUT + (size_t)(64*wi + 16*c + li)*256 + kk*32 + lg*8);
          acc[0][cc] = mfma16(a0.hi, B, acc[0][cc]);
          acc[1][cc] = mfma16(a1.hi, B, acc[1][cc]);
        }
      }
#pragma unroll
      for (int it = 0; it < 2; ++it){
        const int b = bb2[it];
#pragma unroll
        for (int cc = 0; cc < 2; ++cc){
          int col = 64*wi + 16*(2*ih + cc) + li;
          float bias = bo[col];
#pragma unroll
          for (int j = 0; j < 4; ++j){
            int q = 4*lg + j;
            float v = (acc[it][cc][j] + bias) * (1.f - em[(size_t)b*64 + q]);
            x2out[((size_t)b*16 + q)*256 + col] = v;
          }
        }
      }
    }
    return;
  }

  // ============================== gate role ==============================
  {
    constexpr int W1SZ = 96*256, WINSZ = 256*768, WVSZ = 16*256;
    const int b = blockIdx.x - 2048;

    char* sp = smem;
    _Float16* x1h = (_Float16*)sp; sp += 64*264*2;
    _Float16* x1l = (_Float16*)sp; sp += 64*264*2;
    _Float16* Kh  = (_Float16*)sp; sp += 64*72*2;
    _Float16* Kl  = (_Float16*)sp; sp += 64*72*2;
    _Float16* Qh  = (_Float16*)sp; sp += 16*264*2;
    _Float16* Ql  = (_Float16*)sp; sp += 16*264*2;
    float*    lgs = (float*)sp;    sp += 16*72*4;
    float*    Ps  = (float*)sp;    sp += 16*66*4;
    float*    v2s = (float*)sp;    sp += 64*18*4;
    float*  ogacc = (float*)sp;    sp += 32*4;

    {
      const int mt = w >> 1;
      f32x4 acc[8];
#pragma unroll
      for (int c = 0; c < 8; ++c) acc[c] = 0.f;
#pragma unroll
      for (int kk = 0; kk < 3; ++kk){
        AB<1> a = ldF<1>(ent + ((size_t)b*64 + mt*16 + li)*96 + kk*32 + lg*8);
#pragma unroll
        for (int c = 0; c < 8; ++c){
          int nt = (w & 1)*8 + c;
          AB<1> bb = ldW<1>(W1g + (size_t)(nt*16 + li)*96 + kk*32 + lg*8, W1SZ);
          a.mf(bb, acc[c]);
        }
      }
#pragma unroll
      for (int c = 0; c < 8; ++c){
        int col = ((w & 1)*8 + c)*16 + li;
        float bias = b1g[col];
#pragma unroll
        for (int j = 0; j < 4; ++j){
          float v = fmaxf(acc[c][j] + bias, 0.f);
          stL<1>(x1h, x1l, (mt*16 + 4*lg + j)*264 + col, v);
        }
      }
    }
    if (tid < 32) ogacc[tid] = 0.f;
    __syncthreads();

    {
#pragma unroll
      for (int s = 0; s < 2; ++s){
        int nt = w + s*8;
        f32x4 acc = 0.f;
        for (int kk = 0; kk < 8; ++kk){
          int ao = li*264 + kk*32 + lg*8;
          AB<1> a = ldL<1>(x1h + ao, x1l + ao);
          AB<1> bb = ldW<1>(WINg + (size_t)(nt*16 + li)*256 + kk*32 + lg*8, WINSZ);
          a.mf(bb, acc);
        }
#pragma unroll
        for (int j = 0; j < 4; ++j)
          stL<1>(Qh, Ql, (4*lg + j)*264 + nt*16 + li, acc[j]);
      }
      if (w < 4){
        f32x4 acc = 0.f;
        for (int kk = 0; kk < 8; ++kk){
          int ao = (w*16 + li)*264 + kk*32 + lg*8;
          AB<1> a = ldL<1>(x1h + ao, x1l + ao);
          AB<1> bb = ldW<1>(WVEFF + (size_t)li*256 + kk*32 + lg*8, WVSZ);
          a.mf(bb, acc);
        }
#pragma unroll
        for (int j = 0; j < 4; ++j)
          v2s[(w*16 + 4*lg + j)*18 + li] = acc[j];
      }
    }
    __syncthreads();

    for (int h = 0; h < 4; ++h){
      {
        const int mt = w >> 1;
        f32x4 acc[2];
        acc[0] = 0.f; acc[1] = 0.f;
        for (int kk = 0; kk < 8; ++kk){
          int ao = (mt*16 + li)*264 + kk*32 + lg*8;
          AB<1> a = ldL<1>(x1h + ao, x1l + ao);
#pragma unroll
          for (int c = 0; c < 2; ++c){
            int nt = (w & 1)*2 + c;
            AB<1> bb = ldW<1>(WINg + (size_t)(256 + h*64 + nt*16 + li)*256 + kk*32 + lg*8, WINSZ);
            a.mf(bb, acc[c]);
          }
        }
#pragma unroll
        for (int c = 0; c < 2; ++c){
          int colb = ((w & 1)*2 + c)*16 + li;
#pragma unroll
          for (int j = 0; j < 4; ++j)
            stL<1>(Kh, Kl, (mt*16 + 4*lg + j)*72 + colb, acc[c][j]);
        }
      }
      __syncthreads();
      if (w < 4){
        f32x4 acc = 0.f;
#pragma unroll
        for (int kk = 0; kk < 2; ++kk){
          int ao = li*264 + h*64 + kk*32 + lg*8;
          AB<1> a = ldL<1>(Qh + ao, Ql + ao);
          int bo_ = (16*w + li)*72 + kk*32 + lg*8;
          AB<1> bb = ldL<1>(Kh + bo_, Kl + bo_);
          a.mf(bb, acc);
        }
#pragma unroll
        for (int j = 0; j < 4; ++j){
          int q = 4*lg + j, key = 16*w + li;
          float v = acc[j] * 0.125f;
          float m = om[((size_t)b*64 + q)*64 + key];
          if (m > 0.f) v = -1e9f;
          lgs[q*72 + key] = v;
        }
      }
      __syncthreads();
      if (tid < 256){
        int q = tid >> 4, i16 = tid & 15;
        float pv[4], mx = -3e38f;
#pragma unroll
        for (int u = 0; u < 4; ++u){ pv[u] = lgs[q*72 + i16 + 16*u]; mx = fmaxf(mx, pv[u]); }
#pragma unroll
        for (int d = 1; d < 16; d <<= 1) mx = fmaxf(mx, __shfl_xor(mx, d, 16));
        float s = 0.f;
#pragma unroll
        for (int u = 0; u < 4; ++u){ pv[u] = expf(pv[u] - mx); s += pv[u]; }
#pragma unroll
        for (int d = 1; d < 16; d <<= 1) s += __shfl_xor(s, d, 16);
#pragma unroll
        for (int u = 0; u < 4; ++u){
          int key = i16 + 16*u;
          float m = om[((size_t)b*64 + q)*64 + key];
          Ps[q*66 + key] = (pv[u]/s)*(1.f - m);
        }
      }
      __syncthreads();
      if (tid < 256){
        int q = tid >> 4, l16 = tid & 15;
        float a0 = 0.f, a1 = 0.f;
#pragma unroll
        for (int u = 0; u < 4; ++u){
          int k = l16 + 16*u;
          float p2 = Ps[q*66 + k];
          a0 += p2 * v2s[k*18 + h*2];
          a1 += p2 * v2s[k*18 + h*2 + 1];
        }
#pragma unroll
        for (int d = 1; d < 16; d <<= 1){ a0 += __shfl_xor(a0, d, 16); a1 += __shfl_xor(a1, d, 16); }
        if (l16 == 0){ ogacc[q*2] += a0; ogacc[q*2 + 1] += a1; }
      }
      __syncthreads();
    }
    if (tid < 16){
      int q = tid;
      float am = em[(size_t)b*64 + q];
      float g0 = (1.f - am)*(ogacc[2*q]     + beff[0]) + gb2[0];
      float g1 = (1.f - am)*(ogacc[2*q + 1] + beff[1]) + gb2[1];
      og[((size_t)b*16 + q)*2]     = g0;
      og[((size_t)b*16 + q)*2 + 1] = g1;
      gate[(size_t)b*16 + q] = (g1 > g0) ? 1.f : 0.f;
    }
  }
}

// ------------------- K2: gate, global attention, fc2, gi — 2 items/block
// 1024 blocks x 256 threads; pair p -> items 2p, 2p+1 (same gi row-group).
// Weight fragments (GMIN/GMOUT/FC2T/GIHT) loaded once, applied to both items.
__global__ __launch_bounds__(256) void k2_global(
    const float* __restrict__ em,
    const float* __restrict__ x2, const float* __restrict__ x2m,
    const float* __restrict__ gate,
    const _Float16* __restrict__ GMIN, const _Float16* __restrict__ GMOUT, const float* __restrict__ gob,
    const _Float16* __restrict__ FC2T, const float* __restrict__ fc2b,
    const _Float16* __restrict__ GIHT, const float* __restrict__ gib,
    float* __restrict__ gi)
{
  const int p = blockIdx.x;
  const int tid = threadIdx.x;
  const int w = tid >> 6, lg = (tid >> 4) & 3, li = tid & 15;

  extern __shared__ char smem[];
  float*    gate_s = (float*)smem;                    // [2][16]        128 B
  _Float16* gm_s   = (_Float16*)(smem + 128);         // [2][16*264]  16896 B
  _Float16* Q2     = (_Float16*)(smem + 17024);       // [2][16*72]    4608 B
  _Float16* K2s    = (_Float16*)(smem + 21632);       // [2][16*72]    4608 B
  _Float16* Vt2    = (_Float16*)(smem + 26240);       // [2][64*40]   10240 B
  float*    lg2    = (float*)(smem + 36480);          // [2][16*24]    3072 B
  _Float16* P2     = (_Float16*)(smem + 39552);       // [2][16*40]    2560 B
  _Float16* outp   = (_Float16*)(smem + 42112);       // [2][16*264]  16896 B
  _Float16* cat_s  = (_Float16*)(smem + 59008);       // [2][16*520]  33280 B
  _Float16* x3_s   = (_Float16*)(smem + 92288);       // [2][16*264]  16896 B
  // total 109184 B

  if (tid < 32){
    int it = tid >> 4, q = tid & 15;
    gate_s[it*16 + q] = gate[(size_t)(2*p + it)*16 + q];
  }
  __syncthreads();
  // staging: gm, cat[:,0:256]; zero Vt2/P2 pads
#pragma unroll
  for (int it = 0; it < 2; ++it){
    const int b = 2*p + it;
    for (int idx = tid; idx < 4096; idx += 256){
      int q = idx >> 8, d = idx & 255;
      gm_s[it*4224 + q*264 + d]  = (_Float16)(x2m[((size_t)b*16 + q)*256 + d] * gate_s[it*16 + q]);
      cat_s[it*8320 + q*520 + d] = (_Float16)(x2[((size_t)b*16 + q)*256 + d]);
    }
  }
  for (int idx = tid; idx < 2*64*40; idx += 256) Vt2[idx] = (_Float16)0.f;
  for (int idx = tid; idx < 2*16*40; idx += 256) P2[idx] = (_Float16)0.f;
  __syncthreads();
  // global attention over 16 agents, both items
  for (int h = 0; h < 4; ++h){
    { // QKV gemms, B shared across items
      f32x4 aq0 = 0.f, aq1 = 0.f, ak0 = 0.f, ak1 = 0.f, av0 = 0.f, av1 = 0.f;
      for (int kk = 0; kk < 8; ++kk){
        f16x8 A0 = *(const f16x8*)(gm_s + li*264 + kk*32 + lg*8);
        f16x8 A1 = *(const f16x8*)(gm_s + 4224 + li*264 + kk*32 + lg*8);
        f16x8 Bq = *(const f16x8*)(GMIN + (size_t)(      64*h + 16*w + li)*256 + kk*32 + lg*8);
        f16x8 Bk = *(const f16x8*)(GMIN + (size_t)(256 + 64*h + 16*w + li)*256 + kk*32 + lg*8);
        f16x8 Bv = *(const f16x8*)(GMIN + (size_t)(512 + 64*h + 16*w + li)*256 + kk*32 + lg*8);
        aq0 = mfma16(A0, Bq, aq0); aq1 = mfma16(A1, Bq, aq1);
        ak0 = mfma16(A0, Bk, ak0); ak1 = mfma16(A1, Bk, ak1);
        av0 = mfma16(A0, Bv, av0); av1 = mfma16(A1, Bv, av1);
      }
#pragma unroll
      for (int j = 0; j < 4; ++j){
        int rw = 4*lg + j, dim = 16*w + li;
        Q2[rw*72 + dim]         = (_Float16)aq0[j];
        Q2[1152 + rw*72 + dim]  = (_Float16)aq1[j];
        K2s[rw*72 + dim]        = (_Float16)ak0[j];
        K2s[1152 + rw*72 + dim] = (_Float16)ak1[j];
        Vt2[dim*40 + rw]        = (_Float16)av0[j];
        Vt2[2560 + dim*40 + rw] = (_Float16)av1[j];
      }
    }
    __syncthreads();
    if (w < 2){ // 16x16 logits; wave w -> item w
      const int it = w, b = 2*p + it;
      f32x4 acc = 0.f;
#pragma unroll
      for (int kk = 0; kk < 2; ++kk){
        f16x8 A = *(const f16x8*)(Q2  + it*1152 + li*72 + kk*32 + lg*8);
        f16x8 B = *(const f16x8*)(K2s + it*1152 + li*72 + kk*32 + lg*8);
        acc = mfma16(A, B, acc);
      }
      float amk = em[(size_t)b*64 + li];
#pragma unroll
      for (int j = 0; j < 4; ++j){
        int q = 4*lg + j;
        float amq = em[(size_t)b*64 + q];
        float m = 1.f - (1.f - amq)*(1.f - amk);
        float v = acc[j]*0.125f;
        if (m > 0.f) v = -1e9f;
        lg2[it*384 + q*24 + li] = v;
      }
    }
    __syncthreads();
    { // softmax, both items
      int q = tid >> 4, key = tid & 15;
#pragma unroll
      for (int it = 0; it < 2; ++it){
        const int b = 2*p + it;
        float v = lg2[it*384 + q*24 + key];
        float mx = v;
#pragma unroll
        for (int d = 1; d < 16; d <<= 1) mx = fmaxf(mx, __shfl_xor(mx, d, 16));
        float pe = expf(v - mx);
        float s = pe;
#pragma unroll
        for (int d = 1; d < 16; d <<= 1) s += __shfl_xor(s, d, 16);
        float amq = em[(size_t)b*64 + q], amk = em[(size_t)b*64 + key];
        float m = 1.f - (1.f - amq)*(1.f - amk);
        P2[it*640 + q*40 + key] = (_Float16)((pe/s)*(1.f - m));
      }
    }
    __syncthreads();
    { // PV, both items (LDS-only)
#pragma unroll
      for (int it = 0; it < 2; ++it){
        f32x4 acc = 0.f;
        f16x8 A = *(const f16x8*)(P2 + it*640 + li*40 + lg*8);
        f16x8 B = *(const f16x8*)(Vt2 + it*2560 + (16*w + li)*40 + lg*8);
        acc = mfma16(A, B, acc);
#pragma unroll
        for (int j = 0; j < 4; ++j)
          outp[it*4224 + (4*lg + j)*264 + 64*h + 16*w + li] = (_Float16)acc[j];
      }
    }
    __syncthreads();
  }
  // gmsg out-proj -> cat[:,256:512]; B shared, cc-outer
  {
#pragma unroll
    for (int c = 0; c < 4; ++c){
      int col = 64*w + 16*c + li;
      f32x4 a0 = 0.f, a1 = 0.f;
      for (int kk = 0; kk < 8; ++kk){
        f16x8 B  = *(const f16x8*)(GMOUT + (size_t)col*256 + kk*32 + lg*8);
        f16x8 A0 = *(const f16x8*)(outp + li*264 + kk*32 + lg*8);
        f16x8 A1 = *(const f16x8*)(outp + 4224 + li*264 + kk*32 + lg*8);
        a0 = mfma16(A0, B, a0);
        a1 = mfma16(A1, B, a1);
      }
      float bias = gob[col];
#pragma unroll
      for (int j = 0; j < 4; ++j){
        int q = 4*lg + j;
        float m0 = 1.f - em[(size_t)(2*p)*64 + q];
        float m1 = 1.f - em[(size_t)(2*p + 1)*64 + q];
        cat_s[q*520 + 256 + col]        = (_Float16)((a0[j] + bias)*m0);
        cat_s[8320 + q*520 + 256 + col] = (_Float16)((a1[j] + bias)*m1);
      }
    }
  }
  __syncthreads();
  // x3 = relu(cat @ fc2 + b); B shared, cc-outer
  {
#pragma unroll
    for (int c = 0; c < 4; ++c){
      int col = 64*w + 16*c + li;
      f32x4 a0 = 0.f, a1 = 0.f;
      for (int kk = 0; kk < 16; ++kk){
        f16x8 B  = *(const f16x8*)(FC2T + (size_t)col*512 + kk*32 + lg*8);
        f16x8 A0 = *(const f16x8*)(cat_s + li*520 + kk*32 + lg*8);
        f16x8 A1 = *(const f16x8*)(cat_s + 8320 + li*520 + kk*32 + lg*8);
        a0 = mfma16(A0, B, a0);
        a1 = mfma16(A1, B, a1);
      }
      float bias = fc2b[col];
#pragma unroll
      for (int j = 0; j < 4; ++j){
        x3_s[(4*lg + j)*264 + col]        = (_Float16)fmaxf(a0[j] + bias, 0.f);
        x3_s[4224 + (4*lg + j)*264 + col] = (_Float16)fmaxf(a1[j] + bias, 0.f);
      }
    }
  }
  __syncthreads();
  // gi = x3 @ gru_w_ih + b_ih; B shared, cc-outer. items share r0; t = t0, t0+1
  {
    const int r0 = ((2*p) >> 6)*16, t0 = (2*p) & 63;
#pragma unroll
    for (int cc = 0; cc < 12; ++cc){
      int col = (w*12 + cc)*16 + li;
      f32x4 a0 = 0.f, a1 = 0.f;
      for (int kk = 0; kk < 8; ++kk){
        f16x8 B  = *(const f16x8*)(GIHT + (size_t)col*256 + kk*32 + lg*8);
        f16x8 A0 = *(const f16x8*)(x3_s + li*264 + kk*32 + lg*8);
        f16x8 A1 = *(const f16x8*)(x3_s + 4224 + li*264 + kk*32 + lg*8);
        a0 = mfma16(A0, B, a0);
        a1 = mfma16(A1, B, a1);
      }
      float bias = gib[col];
#pragma unroll
      for (int j = 0; j < 4; ++j){
        int q = 4*lg + j;
        gi[((size_t)((r0 + q)*64 + t0))*768 + col]     = a0[j] + bias;
        gi[((size_t)((r0 + q)*64 + t0 + 1))*768 + col] = a1[j] + bias;
      }
    }
  }
}

// ------------------------------------------------------------------ K3: GRU
// r14: saturation-safe fast transcendentals (__expf) in the elementwise cell.
__global__ __launch_bounds__(256) void k3_gru(
    const _Float16* __restrict__ WHH, const float* __restrict__ bhh,
    const float* __restrict__ gi, const float* __restrict__ h0,
    float* __restrict__ hs)
{
  const int rb = blockIdx.x;
  const int row0 = rb * 16;
  const int tid = threadIdx.x;
  const int w = tid >> 6, lg = (tid >> 4) & 3, li = tid & 15;

  extern __shared__ char smem3[];
  _Float16* hf16 = (_Float16*)smem3;
  float* hf32 = (float*)(smem3 + 8448);
  float* gh   = (float*)(smem3 + 8448 + 16640);
  float* bhs  = (float*)(smem3 + 8448 + 16640 + 49664);

  for (int idx = tid; idx < 768; idx += 256) bhs[idx] = bhh[idx];
  for (int idx = tid; idx < 4096; idx += 256){
    int r = idx >> 8, d = idx & 255;
    float v = h0[(size_t)(row0 + r)*256 + d];
    hf32[r*260 + d] = v;
    hf16[r*264 + d] = (_Float16)v;
  }
  __syncthreads();

  const int er = tid >> 4;
  const int d0 = (tid & 15) * 16;

  for (int t = 0; t < 64; ++t){
    const float* gp = gi + ((size_t)(row0 + er)*64 + t)*768 + d0;
    f32x4 gr[4], gz[4], gn[4];
#pragma unroll
    for (int v = 0; v < 4; ++v){
      gr[v] = *(const f32x4*)(gp + v*4);
      gz[v] = *(const f32x4*)(gp + 256 + v*4);
      gn[v] = *(const f32x4*)(gp + 512 + v*4);
    }
    f16x8 a[8];
#pragma unroll
    for (int kk = 0; kk < 8; ++kk)
      a[kk] = *(const f16x8*)(hf16 + li*264 + kk*32 + lg*8);
    f32x4 acc[12];
#pragma unroll
    for (int c = 0; c < 12; ++c) acc[c] = 0.f;
#pragma unroll
    for (int c = 0; c < 12; ++c){
      const _Float16* bp = WHH + (size_t)(w*192 + c*16 + li)*256 + lg*8;
#pragma unroll
      for (int kk = 0; kk < 8; ++kk)
        acc[c] = mfma16(a[kk], *(const f16x8*)(bp + kk*32), acc[c]);
    }
#pragma unroll
    for (int c = 0; c < 12; ++c){
      int col = w*192 + c*16 + li;
#pragma unroll
      for (int j = 0; j < 4; ++j)
        gh[(4*lg + j)*776 + col] = acc[c][j];
    }
    __syncthreads();
    {
      float* hp32 = hf32 + er*260 + d0;
      float* hsp  = hs + ((size_t)(rb*64 + t)*16 + er)*256 + d0;
      f16x8 hv8[2];
#pragma unroll
      for (int v = 0; v < 4; ++v){
        f32x4 xr = *(const f32x4*)(gh + er*776 +       d0 + v*4);
        f32x4 xz = *(const f32x4*)(gh + er*776 + 256 + d0 + v*4);
        f32x4 xn = *(const f32x4*)(gh + er*776 + 512 + d0 + v*4);
        f32x4 hold = *(const f32x4*)(hp32 + v*4);
        f32x4 hout;
#pragma unroll
        for (int e = 0; e < 4; ++e){
          int d = d0 + v*4 + e;
          float rr_ = 1.f/(1.f + __expf(-(gr[v][e] + xr[e] + bhs[d])));
          float zz  = 1.f/(1.f + __expf(-(gz[v][e] + xz[e] + bhs[256 + d])));
          float pre = gn[v][e] + rr_*(xn[e] + bhs[512 + d]);
          float nn  = 1.f - 2.f/(1.f + __expf(2.f*pre));
          float hv = (1.f - zz)*nn + zz*hold[e];
          hout[e] = hv;
          int sl = v*4 + e;
          hv8[sl >> 3][sl & 7] = (_Float16)hv;
        }
        *(f32x4*)(hp32 + v*4) = hout;
        *(f32x4*)(hsp + v*4)  = hout;
      }
      *(f16x8*)(hf16 + er*264 + d0)     = hv8[0];
      *(f16x8*)(hf16 + er*264 + d0 + 8) = hv8[1];
    }
    __syncthreads();
  }
}

// ------------------------------------------------------------------ K4: q out
__global__ __launch_bounds__(256) void k4_q(
    const _Float16* __restrict__ FC3T, const float* __restrict__ fc3b,
    const float* __restrict__ em, const float* __restrict__ hs, float* __restrict__ qo)
{
  const int tid = threadIdx.x;
  const int w = tid >> 6, lg = (tid >> 4) & 3, li = tid & 15;
  const int rb = blockIdx.x*64 + 16*w;
  f32x4 acc[2];
#pragma unroll
  for (int c = 0; c < 2; ++c) acc[c] = 0.f;
  for (int kk = 0; kk < 8; ++kk){
    const float* ap = hs + (size_t)(rb + li)*256 + kk*32 + lg*8;
    f32x4 v0 = *(const f32x4*)ap, v1 = *(const f32x4*)(ap + 4);
    f16x8 A;
#pragma unroll
    for (int e = 0; e < 4; ++e){ A[e] = (_Float16)v0[e]; A[e+4] = (_Float16)v1[e]; }
#pragma unroll
    for (int c = 0; c < 2; ++c){
      f16x8 B = *(const f16x8*)(FC3T + (size_t)(16*c + li)*256 + kk*32 + lg*8);
      acc[c] = mfma16(A, B, acc[c]);
    }
  }
#pragma unroll
  for (int c = 0; c < 2; ++c){
    int col = 16*c + li;
    float bias = fc3b[col];
#pragma unroll
    for (int j = 0; j < 4; ++j){
      int row = rb + 4*lg + j;
      float am = em[(size_t)(row >> 4)*64 + (row & 15)];
      qo[(size_t)row*32 + col] = (acc[c][j] + bias)*(1.f - am);
    }
  }
}

// --------------------------------------------------------------------- launch
extern "C" void kernel_launch(void* const* d_in, const int* in_sizes, int n_in,
                              void* d_out, int out_size, void* d_ws, size_t ws_size,
                              hipStream_t stream)
{
  // ws layout (bytes) — r3 layout
  constexpr size_t OFF_FC1T   = 0;
  constexpr size_t OFF_MSG1T  = 49152;
  constexpr size_t OFF_AINT   = 98304;
  constexpr size_t OFF_LINT   = 491520;
  constexpr size_t OFF_AOUTT  = 884736;
  constexpr size_t OFF_LOUTT  = 1015808;
  constexpr size_t OFF_GMINT  = 1146880;
  constexpr size_t OFF_GMOUTT = 1540096;
  constexpr size_t OFF_FC2T   = 1671168;
  constexpr size_t OFF_GIHT   = 1933312;
  constexpr size_t OFF_GHHT   = 2326528;
  constexpr size_t OFF_FC3T   = 2719744;
  constexpr size_t OFF_G1T    = 2736128;   // f16 hi+lo pair
  constexpr size_t OFF_GINT   = 2834432;   // pair
  constexpr size_t OFF_WVEFF  = 3620864;   // pair
  constexpr size_t OFF_BEFF   = 3637248;
  constexpr size_t OFF_GATE   = 3637504;   // 131072
  constexpr size_t OFF_X2     = 3768576;   // 33554432
  constexpr size_t OFF_X2M    = 37323008;  // 33554432
  constexpr size_t OFF_GI     = 70877440;  // 100663296
  constexpr size_t NEED       = 171540736;
  if (ws_size < NEED) return;

  char* ws = (char*)d_ws;
  const float* ent = (const float*)d_in[0];
  const float* om  = (const float*)d_in[1];
  const float* em  = (const float*)d_in[2];

  WJobs jb{};
  int nj = 0;
  auto addj = [&](int src_idx, size_t off, int K, int N, int m){
    jb.src[nj] = (const float*)d_in[src_idx]; jb.off[nj] = (unsigned)off;
    jb.K[nj] = K; jb.N[nj] = N; jb.mode[nj] = m; ++nj;
  };
  addj(4,  OFF_FC1T,   96, 256, 0);
  addj(17, OFF_MSG1T,  96, 256, 0);
  addj(6,  OFF_AINT,  256, 768, 0);
  addj(19, OFF_LINT,  256, 768, 0);
  addj(7,  OFF_AOUTT, 256, 256, 0);
  addj(20, OFF_LOUTT, 256, 256, 0);
  addj(22, OFF_GMINT, 256, 768, 0);
  addj(23, OFF_GMOUTT,256, 256, 0);
  addj(9,  OFF_FC2T,  512, 256, 0);
  addj(11, OFF_GIHT,  256, 768, 0);
  addj(12, OFF_GHHT,  256, 768, 0);
  addj(15, OFF_FC3T,  256,  32, 0);
  addj(28, OFF_G1T,    96, 256, 1);
  addj(25, OFF_GINT,  256, 768, 1);
  k0_conv<<<dim3(96, nj), 256, 0, stream>>>(jb, ws);

  k0w_gate<<<1, 256, 0, stream>>>(
      (const float*)d_in[26], (const float*)d_in[30],
      (const float*)d_in[27], (const float*)d_in[25],
      (_Float16*)(ws + OFF_WVEFF), (float*)(ws + OFF_BEFF));

  constexpr int SMB = 156672, SMK2 = 109184, SM3 = 77824;
  (void)hipFuncSetAttribute(reinterpret_cast<const void*>(&k1_all),
                            hipFuncAttributeMaxDynamicSharedMemorySize, SMB);
  (void)hipFuncSetAttribute(reinterpret_cast<const void*>(&k2_global),
                            hipFuncAttributeMaxDynamicSharedMemorySize, SMK2);
  (void)hipFuncSetAttribute(reinterpret_cast<const void*>(&k3_gru),
                            hipFuncAttributeMaxDynamicSharedMemorySize, SM3);

  float* qout = (float*)d_out;
  float* hsout = qout + 1048576;
  float* gout = qout + 9437184;

  // fused branch2 + gate: 4096 blocks, 512 threads
  k1_all<<<4096, 512, SMB, stream>>>(ent, om, em,
      (const _Float16*)(ws + OFF_FC1T),  (const float*)d_in[5],
      (const _Float16*)(ws + OFF_AINT),
      (const _Float16*)(ws + OFF_AOUTT), (const float*)d_in[8],
      (float*)(ws + OFF_X2),
      (const _Float16*)(ws + OFF_MSG1T), (const float*)d_in[18],
      (const _Float16*)(ws + OFF_LINT),
      (const _Float16*)(ws + OFF_LOUTT), (const float*)d_in[21],
      (float*)(ws + OFF_X2M),
      (const _Float16*)(ws + OFF_G1T),   (const float*)d_in[29],
      (const _Float16*)(ws + OFF_GINT),
      (const _Float16*)(ws + OFF_WVEFF),
      (const float*)(ws + OFF_BEFF), (const float*)d_in[31],
      gout, (float*)(ws + OFF_GATE));

  // k2: 1024 blocks, 2 items each
  k2_global<<<1024, 256, SMK2, stream>>>(em,
      (const float*)(ws + OFF_X2), (const float*)(ws + OFF_X2M),
      (const float*)(ws + OFF_GATE),
      (const _Float16*)(ws + OFF_GMINT), (const _Float16*)(ws + OFF_GMOUTT), (const float*)d_in[24],
      (const _Float16*)(ws + OFF_FC2T), (const float*)d_in[10],
      (const _Float16*)(ws + OFF_GIHT), (const float*)d_in[13],
      (float*)(ws + OFF_GI));

  k3_gru<<<32, 256, SM3, stream>>>(
      (const _Float16*)(ws + OFF_GHHT), (const float*)d_in[14],
      (const float*)(ws + OFF_GI), (const float*)d_in[3], hsout);

  k4_q<<<512, 256, 0, stream>>>(
      (const _Float16*)(ws + OFF_FC3T), (const float*)d_in[16],
      em, hsout, qout);
}

// Round 15
// 1455.723 us; speedup vs baseline: 1.0977x; 1.0684x over previous
//
#include <hip/hip_runtime.h>

// EntityAttentionRNNMsgAgent — fused MI355X implementation.
// r15 = r14 + branch2 K_h/V_h phases converted to v_mfma_f32_32x32x16_f16:
// waves 0-3 compute K tiles, waves 4-7 V tiles (same phase, both items per
// wave, B shared) — halves MFMA and B-load issue in the two dominant GEMM
// phases. C-layout per HW-verified mapping (col=lane&31,
// row=(reg&3)+8*(reg>>2)+4*(lane>>5)); Ks/Vs LDS layouts unchanged so
// logits/PV readers are untouched. Everything else byte-identical to r14
// (1555.3us verified).

#define DEV __device__ __forceinline__

typedef _Float16 f16x8 __attribute__((ext_vector_type(8)));
typedef _Float16 f16x4 __attribute__((ext_vector_type(4)));
typedef float    f32x4 __attribute__((ext_vector_type(4)));
typedef float    f32x16 __attribute__((ext_vector_type(16)));

DEV f32x4 mfma16(f16x8 a, f16x8 b, f32x4 c){
  return __builtin_amdgcn_mfma_f32_16x16x32_f16(a, b, c, 0, 0, 0);
}
DEV f32x16 mfma32(f16x8 a, f16x8 b, f32x16 c){
  return __builtin_amdgcn_mfma_f32_32x32x16_f16(a, b, c, 0, 0, 0);
}

// A/B fragment pair for optional split-precision (MODE=1: value = hi + lo)
template<int MODE> struct AB {
  f16x8 hi, lo;
  DEV void mf(const AB& b, f32x4& c) const {
    if constexpr (MODE){
      c = mfma16(lo, b.hi, c);
      c = mfma16(hi, b.lo, c);
    }
    c = mfma16(hi, b.hi, c);
  }
};

template<int MODE> DEV AB<MODE> ldW(const _Float16* p, int losz){
  AB<MODE> r; r.hi = *(const f16x8*)p;
  if constexpr (MODE) r.lo = *(const f16x8*)(p + losz);
  return r;
}
template<int MODE> DEV AB<MODE> ldL(const _Float16* ph, const _Float16* pl){
  AB<MODE> r; r.hi = *(const f16x8*)ph;
  if constexpr (MODE) r.lo = *(const f16x8*)pl;
  return r;
}
template<int MODE> DEV AB<MODE> ldF(const float* p){
  AB<MODE> r;
  f32x4 v0 = *(const f32x4*)p, v1 = *(const f32x4*)(p + 4);
#pragma unroll
  for (int i = 0; i < 4; ++i){
    float a = v0[i], b = v1[i];
    _Float16 ah = (_Float16)a, bh = (_Float16)b;
    r.hi[i] = ah; r.hi[i+4] = bh;
    if constexpr (MODE){
      r.lo[i]   = (_Float16)(a - (float)ah);
      r.lo[i+4] = (_Float16)(b - (float)bh);
    }
  }
  return r;
}
template<int MODE> DEV void stL(_Float16* ph, _Float16* pl, int idx, float v){
  _Float16 h = (_Float16)v;
  ph[idx] = h;
  if constexpr (MODE) pl[idx] = (_Float16)(v - (float)h);
}

// ---------------------------------------------------------------- K0: weights
struct WJobs {
  const float* src[15];
  unsigned off[15];
  int K[15], N[15], mode[15];
};

__global__ __launch_bounds__(256) void k0_conv(WJobs jb, char* ws){
  const int job = blockIdx.y;
  const int K = jb.K[job], N = jb.N[job];
  const int total = K * N;
  _Float16* dh = (_Float16*)(ws + jb.off[job]);
  const float* src = jb.src[job];
  const int m = jb.mode[job];
  for (int idx = blockIdx.x*256 + threadIdx.x; idx < total; idx += gridDim.x*256){
    int n = idx / K, k = idx - n*K;
    float v = src[(size_t)k*N + n];
    _Float16 h = (_Float16)v;
    dh[idx] = h;
    if (m) dh[total + idx] = (_Float16)(v - (float)h);
  }
}

// ------------------------------------------------- K0w: gate-tail precompute
__global__ __launch_bounds__(256) void k0w_gate(
    const float* __restrict__ Wout, const float* __restrict__ Wg2,
    const float* __restrict__ bo,   const float* __restrict__ Win,
    _Float16* __restrict__ wveff, float* __restrict__ beff)
{
  __shared__ float weff_s[256*2];
  const int tid = threadIdx.x;
  {
    float a0 = 0.f, a1 = 0.f;
    const float* wr = Wout + (size_t)tid*256;
    for (int f = 0; f < 256; ++f){ float x = wr[f]; a0 += x*Wg2[2*f]; a1 += x*Wg2[2*f+1]; }
    weff_s[tid*2] = a0; weff_s[tid*2+1] = a1;
  }
  if (tid < 2){
    float s = 0.f;
    for (int f = 0; f < 256; ++f) s += bo[f]*Wg2[2*f + tid];
    beff[tid] = s;
  }
  __syncthreads();
  {
    const int j = tid;
    for (int n = 0; n < 16; ++n){
      float v = 0.f;
      if (n < 8){
        int h = n >> 1, c = n & 1;
        const float* wr = Win + (size_t)j*768 + 512 + h*64;
        const float* we = weff_s + (h*64)*2 + c;
        for (int d = 0; d < 64; ++d) v += wr[d]*we[2*d];
      }
      _Float16 hi = (_Float16)v;
      wveff[n*256 + j] = hi;
      wveff[16*256 + n*256 + j] = (_Float16)(v - (float)hi);
    }
  }
}

// -------------------------------------------- K1 fused: branch2 + gate roles
__global__ __launch_bounds__(512) void k1_all(
    const float* __restrict__ ent, const float* __restrict__ om, const float* __restrict__ em,
    const _Float16* __restrict__ W1a, const float* __restrict__ b1a,
    const _Float16* __restrict__ WINa,
    const _Float16* __restrict__ WOUTa, const float* __restrict__ boa,
    float* __restrict__ x2outa,
    const _Float16* __restrict__ W1b, const float* __restrict__ b1b,
    const _Float16* __restrict__ WINb,
    const _Float16* __restrict__ WOUTb, const float* __restrict__ bob,
    float* __restrict__ x2outb,
    const _Float16* __restrict__ W1g, const float* __restrict__ b1g,
    const _Float16* __restrict__ WINg,
    const _Float16* __restrict__ WVEFF,
    const float* __restrict__ beff, const float* __restrict__ gb2,
    float* __restrict__ og, float* __restrict__ gate)
{
  const int tid = threadIdx.x;
  const int w = tid >> 6, lg = (tid >> 4) & 3, li = tid & 15;
  extern __shared__ char smem[];

  if (blockIdx.x < 2048){
    // ============================ branch2 role ============================
    const int br = blockIdx.x >> 10;
    const int p  = blockIdx.x & 1023;
    const int bb2[2] = { 2*p, 2*p + 1 };
    const _Float16* W1   = br ? W1b   : W1a;
    const float*    b1   = br ? b1b   : b1a;
    const _Float16* WIN  = br ? WINb  : WINa;
    const _Float16* WOUT = br ? WOUTb : WOUTa;
    const float*    bo   = br ? bob   : boa;
    float*          x2out= br ? x2outb: x2outa;

    const int wi = w & 3, ih = w >> 2;
    const int l = tid & 63;              // lane within wave
    const int r32 = l & 31, kh = (l >> 5)*8;

    _Float16* x1  = (_Float16*)smem;
    _Float16* Ks  = (_Float16*)(smem + 67584);
    _Float16* Vs  = (_Float16*)(smem + 86016);
    _Float16* Qs  = (_Float16*)(smem + 104448);
    float*    lgs = (float*)(smem + 109056);
    _Float16* Ps  = (_Float16*)(smem + 118272);
    float*    outp= (float*)(smem + 122880);

    {
      const int b = bb2[ih];
      _Float16* x1p = x1 + ih*16896;
      f32x4 acc[4][4];
#pragma unroll
      for (int r = 0; r < 4; ++r)
#pragma unroll
        for (int c = 0; c < 4; ++c) acc[r][c] = 0.f;
#pragma unroll
      for (int kk = 0; kk < 3; ++kk){
        AB<0> a[4];
#pragma unroll
        for (int r = 0; r < 4; ++r)
          a[r] = ldF<0>(ent + ((size_t)b*64 + 16*r + li)*96 + kk*32 + lg*8);
#pragma unroll
        for (int c = 0; c < 4; ++c){
          f16x8 B = *(const f16x8*)(W1 + (size_t)(64*wi + 16*c + li)*96 + kk*32 + lg*8);
#pragma unroll
          for (int r = 0; r < 4; ++r) acc[r][c] = mfma16(a[r].hi, B, acc[r][c]);
        }
      }
#pragma unroll
      for (int c = 0; c < 4; ++c){
        int col = 64*wi + 16*c + li;
        float bias = b1[col];
#pragma unroll
        for (int r = 0; r < 4; ++r)
#pragma unroll
          for (int j = 0; j < 4; ++j){
            float v = fmaxf(acc[r][c][j] + bias, 0.f);
            x1p[(16*r + 4*lg + j)*264 + col] = (_Float16)v;
          }
      }
    }
    __syncthreads();

    for (int h = 0; h < 4; ++h){
      // K (waves 0-3) / V (waves 4-7) via 32x32x16, both items per wave
      if (w < 4){
        const int kt = w >> 1, dt = w & 1;
        f32x16 acc0 = 0.f, acc1 = 0.f;
        for (int kk = 0; kk < 16; ++kk){
          int ao = (kt*32 + r32)*264 + kk*16 + kh;
          f16x8 A0 = *(const f16x8*)(x1 + ao);
          f16x8 A1 = *(const f16x8*)(x1 + 16896 + ao);
          f16x8 B = *(const f16x8*)(WIN + (size_t)(256 + 64*h + dt*32 + r32)*256 + kk*16 + kh);
          acc0 = mfma32(A0, B, acc0);
          acc1 = mfma32(A1, B, acc1);
        }
#pragma unroll
        for (int reg = 0; reg < 16; ++reg){
          int row = (reg & 3) + 8*(reg >> 2) + 4*(l >> 5);
          Ks[(kt*32 + row)*72 + dt*32 + r32]        = (_Float16)acc0[reg];
          Ks[4608 + (kt*32 + row)*72 + dt*32 + r32] = (_Float16)acc1[reg];
        }
      } else {
        const int wv = w - 4;
        const int kt = wv >> 1, dt = wv & 1;
        f32x16 acc0 = 0.f, acc1 = 0.f;
        for (int kk = 0; kk < 16; ++kk){
          int ao = (kt*32 + r32)*264 + kk*16 + kh;
          f16x8 A0 = *(const f16x8*)(x1 + ao);
          f16x8 A1 = *(const f16x8*)(x1 + 16896 + ao);
          f16x8 B = *(const f16x8*)(WIN + (size_t)(512 + 64*h + dt*32 + r32)*256 + kk*16 + kh);
          acc0 = mfma32(A0, B, acc0);
          acc1 = mfma32(A1, B, acc1);
        }
        // Vs[dim][key]: keys (reg&3)+8*(reg>>2)+4*(l>>5) -> pack 4 per rr
#pragma unroll
        for (int rr = 0; rr < 4; ++rr){
          f16x4 p0, p1;
#pragma unroll
          for (int q4 = 0; q4 < 4; ++q4){
            p0[q4] = (_Float16)acc0[rr*4 + q4];
            p1[q4] = (_Float16)acc1[rr*4 + q4];
          }
          int key = kt*32 + rr*8 + 4*(l >> 5);
          *(f16x4*)(Vs + (dt*32 + r32)*72 + key)        = p0;
          *(f16x4*)(Vs + 4608 + (dt*32 + r32)*72 + key) = p1;
        }
      }
      { // Q_h: rows 0..15, wave -> dim tile wi, item ih (16x16 path)
        f32x4 acc = 0.f;
        for (int kk = 0; kk < 8; ++kk){
          f16x8 A = *(const f16x8*)(x1 + ih*16896 + li*264 + kk*32 + lg*8);
          f16x8 B = *(const f16x8*)(WIN + (size_t)(64*h + 16*wi + li)*256 + kk*32 + lg*8);
          acc = mfma16(A, B, acc);
        }
#pragma unroll
        for (int j = 0; j < 4; ++j)
          Qs[ih*1152 + (4*lg + j)*72 + 16*wi + li] = (_Float16)acc[j];
      }
      __syncthreads();
      { // logits
        const int b = bb2[ih];
        f32x4 acc = 0.f;
#pragma unroll
        for (int kk = 0; kk < 2; ++kk){
          f16x8 A = *(const f16x8*)(Qs + ih*1152 + li*72 + kk*32 + lg*8);
          f16x8 B = *(const f16x8*)(Ks + ih*4608 + (16*wi + li)*72 + kk*32 + lg*8);
          acc = mfma16(A, B, acc);
        }
#pragma unroll
        for (int j = 0; j < 4; ++j){
          int q = 4*lg + j, key = 16*wi + li;
          float v = acc[j] * 0.125f;
          float m = om[((size_t)b*64 + q)*64 + key];
          if (m > 0.f) v = -1e9f;
          lgs[ih*1152 + q*72 + key] = v;
        }
      }
      __syncthreads();
      { // softmax
        const int it = tid >> 8, q = (tid >> 4) & 15, i16 = tid & 15;
        const int b = bb2[it];
        float pv[4], mx = -3e38f;
#pragma unroll
        for (int u = 0; u < 4; ++u){ pv[u] = lgs[it*1152 + q*72 + i16 + 16*u]; mx = fmaxf(mx, pv[u]); }
#pragma unroll
        for (int d = 1; d < 16; d <<= 1) mx = fmaxf(mx, __shfl_xor(mx, d, 16));
        float s = 0.f;
#pragma unroll
        for (int u = 0; u < 4; ++u){ pv[u] = expf(pv[u] - mx); s += pv[u]; }
#pragma unroll
        for (int d = 1; d < 16; d <<= 1) s += __shfl_xor(s, d, 16);
#pragma unroll
        for (int u = 0; u < 4; ++u){
          int key = i16 + 16*u;
          float m = om[((size_t)b*64 + q)*64 + key];
          Ps[it*1152 + q*72 + key] = (_Float16)((pv[u]/s)*(1.f - m));
        }
      }
      __syncthreads();
      { // out_h = P @ V_h
        f32x4 acc = 0.f;
#pragma unroll
        for (int kk = 0; kk < 2; ++kk){
          f16x8 A = *(const f16x8*)(Ps + ih*1152 + li*72 + kk*32 + lg*8);
          f16x8 B = *(const f16x8*)(Vs + ih*4608 + (16*wi + li)*72 + kk*32 + lg*8);
          acc = mfma16(A, B, acc);
        }
#pragma unroll
        for (int j = 0; j < 4; ++j)
          outp[ih*4224 + (4*lg + j)*264 + 64*h + 16*wi + li] = acc[j];
      }
      __syncthreads();
    }

    {
      f32x4 acc[2][2];
#pragma unroll
      for (int it = 0; it < 2; ++it)
#pragma unroll
        for (int c = 0; c < 2; ++c) acc[it][c] = 0.f;
      for (int kk = 0; kk < 8; ++kk){
        AB<0> a0 = ldF<0>(outp + li*264 + kk*32 + lg*8);
        AB<0> a1 = ldF<0>(outp + 4224 + li*264 + kk*32 + lg*8);
#pragma unroll
        for (int cc = 0; cc < 2; ++cc){
          int c = 2*ih + cc;
          f16x8 B = *(const f16x8*)(WOUT + (size_t)(64*wi + 16*c + li)*256 + kk*32 + lg*8);
          acc[0][cc] = mfma16(a0.hi, B, acc[0][cc]);
          acc[1][cc] = mfma16(a1.hi, B, acc[1][cc]);
        }
      }
#pragma unroll
      for (int it = 0; it < 2; ++it){
        const int b = bb2[it];
#pragma unroll
        for (int cc = 0; cc < 2; ++cc){
          int col = 64*wi + 16*(2*ih + cc) + li;
          float bias = bo[col];
#pragma unroll
          for (int j = 0; j < 4; ++j){
            int q = 4*lg + j;
            float v = (acc[it][cc][j] + bias) * (1.f - em[(size_t)b*64 + q]);
            x2out[((size_t)b*16 + q)*256 + col] = v;
          }
        }
      }
    }
    return;
  }

  // ============================== gate role ==============================
  {
    constexpr int W1SZ = 96*256, WINSZ = 256*768, WVSZ = 16*256;
    const int b = blockIdx.x - 2048;

    char* sp = smem;
    _Float16* x1h = (_Float16*)sp; sp += 64*264*2;
    _Float16* x1l = (_Float16*)sp; sp += 64*264*2;
    _Float16* Kh  = (_Float16*)sp; sp += 64*72*2;
    _Float16* Kl  = (_Float16*)sp; sp += 64*72*2;
    _Float16* Qh  = (_Float16*)sp; sp += 16*264*2;
    _Float16* Ql  = (_Float16*)sp; sp += 16*264*2;
    float*    lgs = (float*)sp;    sp += 16*72*4;
    float*    Ps  = (float*)sp;    sp += 16*66*4;
    float*    v2s = (float*)sp;    sp += 64*18*4;
    float*  ogacc = (float*)sp;    sp += 32*4;

    {
      const int mt = w >> 1;
      f32x4 acc[8];
#pragma unroll
      for (int c = 0; c < 8; ++c) acc[c] = 0.f;
#pragma unroll
      for (int kk = 0; kk < 3; ++kk){
        AB<1> a = ldF<1>(ent + ((size_t)b*64 + mt*16 + li)*96 + kk*32 + lg*8);
#pragma unroll
        for (int c = 0; c < 8; ++c){
          int nt = (w & 1)*8 + c;
          AB<1> bb = ldW<1>(W1g + (size_t)(nt*16 + li)*96 + kk*32 + lg*8, W1SZ);
          a.mf(bb, acc[c]);
        }
      }
#pragma unroll
      for (int c = 0; c < 8; ++c){
        int col = ((w & 1)*8 + c)*16 + li;
        float bias = b1g[col];
#pragma unroll
        for (int j = 0; j < 4; ++j){
          float v = fmaxf(acc[c][j] + bias, 0.f);
          stL<1>(x1h, x1l, (mt*16 + 4*lg + j)*264 + col, v);
        }
      }
    }
    if (tid < 32) ogacc[tid] = 0.f;
    __syncthreads();

    {
#pragma unroll
      for (int s = 0; s < 2; ++s){
        int nt = w + s*8;
        f32x4 acc = 0.f;
        for (int kk = 0; kk < 8; ++kk){
          int ao = li*264 + kk*32 + lg*8;
          AB<1> a = ldL<1>(x1h + ao, x1l + ao);
          AB<1> bb = ldW<1>(WINg + (size_t)(nt*16 + li)*256 + kk*32 + lg*8, WINSZ);
          a.mf(bb, acc);
        }
#pragma unroll
        for (int j = 0; j < 4; ++j)
          stL<1>(Qh, Ql, (4*lg + j)*264 + nt*16 + li, acc[j]);
      }
      if (w < 4){
        f32x4 acc = 0.f;
        for (int kk = 0; kk < 8; ++kk){
          int ao = (w*16 + li)*264 + kk*32 + lg*8;
          AB<1> a = ldL<1>(x1h + ao, x1l + ao);
          AB<1> bb = ldW<1>(WVEFF + (size_t)li*256 + kk*32 + lg*8, WVSZ);
          a.mf(bb, acc);
        }
#pragma unroll
        for (int j = 0; j < 4; ++j)
          v2s[(w*16 + 4*lg + j)*18 + li] = acc[j];
      }
    }
    __syncthreads();

    for (int h = 0; h < 4; ++h){
      {
        const int mt = w >> 1;
        f32x4 acc[2];
        acc[0] = 0.f; acc[1] = 0.f;
        for (int kk = 0; kk < 8; ++kk){
          int ao = (mt*16 + li)*264 + kk*32 + lg*8;
          AB<1> a = ldL<1>(x1h + ao, x1l + ao);
#pragma unroll
          for (int c = 0; c < 2; ++c){
            int nt = (w & 1)*2 + c;
            AB<1> bb = ldW<1>(WINg + (size_t)(256 + h*64 + nt*16 + li)*256 + kk*32 + lg*8, WINSZ);
            a.mf(bb, acc[c]);
          }
        }
#pragma unroll
        for (int c = 0; c < 2; ++c){
          int colb = ((w & 1)*2 + c)*16 + li;
#pragma unroll
          for (int j = 0; j < 4; ++j)
            stL<1>(Kh, Kl, (mt*16 + 4*lg + j)*72 + colb, acc[c][j]);
        }
      }
      __syncthreads();
      if (w < 4){
        f32x4 acc = 0.f;
#pragma unroll
        for (int kk = 0; kk < 2; ++kk){
          int ao = li*264 + h*64 + kk*32 + lg*8;
          AB<1> a = ldL<1>(Qh + ao, Ql + ao);
          int bo_ = (16*w + li)*72 + kk*32 + lg*8;
          AB<1> bb = ldL<1>(Kh + bo_, Kl + bo_);
          a.mf(bb, acc);
        }
#pragma unroll
        for (int j = 0; j < 4; ++j){
          int q = 4*lg + j, key = 16*w + li;
          float v = acc[j] * 0.125f;
          float m = om[((size_t)b*64 + q)*64 + key];
          if (m > 0.f) v = -1e9f;
          lgs[q*72 + key] = v;
        }
      }
      __syncthreads();
      if (tid < 256){
        int q = tid >> 4, i16 = tid & 15;
        float pv[4], mx = -3e38f;
#pragma unroll
        for (int u = 0; u < 4; ++u){ pv[u] = lgs[q*72 + i16 + 16*u]; mx = fmaxf(mx, pv[u]); }
#pragma unroll
        for (int d = 1; d < 16; d <<= 1) mx = fmaxf(mx, __shfl_xor(mx, d, 16));
        float s = 0.f;
#pragma unroll
        for (int u = 0; u < 4; ++u){ pv[u] = expf(pv[u] - mx); s += pv[u]; }
#pragma unroll
        for (int d = 1; d < 16; d <<= 1) s += __shfl_xor(s, d, 16);
#pragma unroll
        for (int u = 0; u < 4; ++u){
          int key = i16 + 16*u;
          float m = om[((size_t)b*64 + q)*64 + key];
          Ps[q*66 + key] = (pv[u]/s)*(1.f - m);
        }
      }
      __syncthreads();
      if (tid < 256){
        int q = tid >> 4, l16 = tid & 15;
        float a0 = 0.f, a1 = 0.f;
#pragma unroll
        for (int u = 0; u < 4; ++u){
          int k = l16 + 16*u;
          float p2 = Ps[q*66 + k];
          a0 += p2 * v2s[k*18 + h*2];
          a1 += p2 * v2s[k*18 + h*2 + 1];
        }
#pragma unroll
        for (int d = 1; d < 16; d <<= 1){ a0 += __shfl_xor(a0, d, 16); a1 += __shfl_xor(a1, d, 16); }
        if (l16 == 0){ ogacc[q*2] += a0; ogacc[q*2 + 1] += a1; }
      }
      __syncthreads();
    }
    if (tid < 16){
      int q = tid;
      float am = em[(size_t)b*64 + q];
      float g0 = (1.f - am)*(ogacc[2*q]     + beff[0]) + gb2[0];
      float g1 = (1.f - am)*(ogacc[2*q + 1] + beff[1]) + gb2[1];
      og[((size_t)b*16 + q)*2]     = g0;
      og[((size_t)b*16 + q)*2 + 1] = g1;
      gate[(size_t)b*16 + q] = (g1 > g0) ? 1.f : 0.f;
    }
  }
}

// ------------------- K2: gate, global attention, fc2, gi — 2 items/block
__global__ __launch_bounds__(256) void k2_global(
    const float* __restrict__ em,
    const float* __restrict__ x2, const float* __restrict__ x2m,
    const float* __restrict__ gate,
    const _Float16* __restrict__ GMIN, const _Float16* __restrict__ GMOUT, const float* __restrict__ gob,
    const _Float16* __restrict__ FC2T, const float* __restrict__ fc2b,
    const _Float16* __restrict__ GIHT, const float* __restrict__ gib,
    float* __restrict__ gi)
{
  const int p = blockIdx.x;
  const int tid = threadIdx.x;
  const int w = tid >> 6, lg = (tid >> 4) & 3, li = tid & 15;

  extern __shared__ char smem[];
  float*    gate_s = (float*)smem;
  _Float16* gm_s   = (_Float16*)(smem + 128);
  _Float16* Q2     = (_Float16*)(smem + 17024);
  _Float16* K2s    = (_Float16*)(smem + 21632);
  _Float16* Vt2    = (_Float16*)(smem + 26240);
  float*    lg2    = (float*)(smem + 36480);
  _Float16* P2     = (_Float16*)(smem + 39552);
  _Float16* outp   = (_Float16*)(smem + 42112);
  _Float16* cat_s  = (_Float16*)(smem + 59008);
  _Float16* x3_s   = (_Float16*)(smem + 92288);

  if (tid < 32){
    int it = tid >> 4, q = tid & 15;
    gate_s[it*16 + q] = gate[(size_t)(2*p + it)*16 + q];
  }
  __syncthreads();
#pragma unroll
  for (int it = 0; it < 2; ++it){
    const int b = 2*p + it;
    for (int idx = tid; idx < 4096; idx += 256){
      int q = idx >> 8, d = idx & 255;
      gm_s[it*4224 + q*264 + d]  = (_Float16)(x2m[((size_t)b*16 + q)*256 + d] * gate_s[it*16 + q]);
      cat_s[it*8320 + q*520 + d] = (_Float16)(x2[((size_t)b*16 + q)*256 + d]);
    }
  }
  for (int idx = tid; idx < 2*64*40; idx += 256) Vt2[idx] = (_Float16)0.f;
  for (int idx = tid; idx < 2*16*40; idx += 256) P2[idx] = (_Float16)0.f;
  __syncthreads();
  for (int h = 0; h < 4; ++h){
    {
      f32x4 aq0 = 0.f, aq1 = 0.f, ak0 = 0.f, ak1 = 0.f, av0 = 0.f, av1 = 0.f;
      for (int kk = 0; kk < 8; ++kk){
        f16x8 A0 = *(const f16x8*)(gm_s + li*264 + kk*32 + lg*8);
        f16x8 A1 = *(const f16x8*)(gm_s + 4224 + li*264 + kk*32 + lg*8);
        f16x8 Bq = *(const f16x8*)(GMIN + (size_t)(      64*h + 16*w + li)*256 + kk*32 + lg*8);
        f16x8 Bk = *(const f16x8*)(GMIN + (size_t)(256 + 64*h + 16*w + li)*256 + kk*32 + lg*8);
        f16x8 Bv = *(const f16x8*)(GMIN + (size_t)(512 + 64*h + 16*w + li)*256 + kk*32 + lg*8);
        aq0 = mfma16(A0, Bq, aq0); aq1 = mfma16(A1, Bq, aq1);
        ak0 = mfma16(A0, Bk, ak0); ak1 = mfma16(A1, Bk, ak1);
        av0 = mfma16(A0, Bv, av0); av1 = mfma16(A1, Bv, av1);
      }
#pragma unroll
      for (int j = 0; j < 4; ++j){
        int rw = 4*lg + j, dim = 16*w + li;
        Q2[rw*72 + dim]         = (_Float16)aq0[j];
        Q2[1152 + rw*72 + dim]  = (_Float16)aq1[j];
        K2s[rw*72 + dim]        = (_Float16)ak0[j];
        K2s[1152 + rw*72 + dim] = (_Float16)ak1[j];
        Vt2[dim*40 + rw]        = (_Float16)av0[j];
        Vt2[2560 + dim*40 + rw] = (_Float16)av1[j];
      }
    }
    __syncthreads();
    if (w < 2){
      const int it = w, b = 2*p + it;
      f32x4 acc = 0.f;
#pragma unroll
      for (int kk = 0; kk < 2; ++kk){
        f16x8 A = *(const f16x8*)(Q2  + it*1152 + li*72 + kk*32 + lg*8);
        f16x8 B = *(const f16x8*)(K2s + it*1152 + li*72 + kk*32 + lg*8);
        acc = mfma16(A, B, acc);
      }
      float amk = em[(size_t)b*64 + li];
#pragma unroll
      for (int j = 0; j < 4; ++j){
        int q = 4*lg + j;
        float amq = em[(size_t)b*64 + q];
        float m = 1.f - (1.f - amq)*(1.f - amk);
        float v = acc[j]*0.125f;
        if (m > 0.f) v = -1e9f;
        lg2[it*384 + q*24 + li] = v;
      }
    }
    __syncthreads();
    {
      int q = tid >> 4, key = tid & 15;
#pragma unroll
      for (int it = 0; it < 2; ++it){
        const int b = 2*p + it;
        float v = lg2[it*384 + q*24 + key];
        float mx = v;
#pragma unroll
        for (int d = 1; d < 16; d <<= 1) mx = fmaxf(mx, __shfl_xor(mx, d, 16));
        float pe = expf(v - mx);
        float s = pe;
#pragma unroll
        for (int d = 1; d < 16; d <<= 1) s += __shfl_xor(s, d, 16);
        float amq = em[(size_t)b*64 + q], amk = em[(size_t)b*64 + key];
        float m = 1.f - (1.f - amq)*(1.f - amk);
        P2[it*640 + q*40 + key] = (_Float16)((pe/s)*(1.f - m));
      }
    }
    __syncthreads();
    {
#pragma unroll
      for (int it = 0; it < 2; ++it){
        f32x4 acc = 0.f;
        f16x8 A = *(const f16x8*)(P2 + it*640 + li*40 + lg*8);
        f16x8 B = *(const f16x8*)(Vt2 + it*2560 + (16*w + li)*40 + lg*8);
        acc = mfma16(A, B, acc);
#pragma unroll
        for (int j = 0; j < 4; ++j)
          outp[it*4224 + (4*lg + j)*264 + 64*h + 16*w + li] = (_Float16)acc[j];
      }
    }
    __syncthreads();
  }
  {
#pragma unroll
    for (int c = 0; c < 4; ++c){
      int col = 64*w + 16*c + li;
      f32x4 a0 = 0.f, a1 = 0.f;
      for (int kk = 0; kk < 8; ++kk){
        f16x8 B  = *(const f16x8*)(GMOUT + (size_t)col*256 + kk*32 + lg*8);
        f16x8 A0 = *(const f16x8*)(outp + li*264 + kk*32 + lg*8);
        f16x8 A1 = *(const f16x8*)(outp + 4224 + li*264 + kk*32 + lg*8);
        a0 = mfma16(A0, B, a0);
        a1 = mfma16(A1, B, a1);
      }
      float bias = gob[col];
#pragma unroll
      for (int j = 0; j < 4; ++j){
        int q = 4*lg + j;
        float m0 = 1.f - em[(size_t)(2*p)*64 + q];
        float m1 = 1.f - em[(size_t)(2*p + 1)*64 + q];
        cat_s[q*520 + 256 + col]        = (_Float16)((a0[j] + bias)*m0);
        cat_s[8320 + q*520 + 256 + col] = (_Float16)((a1[j] + bias)*m1);
      }
    }
  }
  __syncthreads();
  {
#pragma unroll
    for (int c = 0; c < 4; ++c){
      int col = 64*w + 16*c + li;
      f32x4 a0 = 0.f, a1 = 0.f;
      for (int kk = 0; kk < 16; ++kk){
        f16x8 B  = *(const f16x8*)(FC2T + (size_t)col*512 + kk*32 + lg*8);
        f16x8 A0 = *(const f16x8*)(cat_s + li*520 + kk*32 + lg*8);
        f16x8 A1 = *(const f16x8*)(cat_s + 8320 + li*520 + kk*32 + lg*8);
        a0 = mfma16(A0, B, a0);
        a1 = mfma16(A1, B, a1);
      }
      float bias = fc2b[col];
#pragma unroll
      for (int j = 0; j < 4; ++j){
        x3_s[(4*lg + j)*264 + col]        = (_Float16)fmaxf(a0[j] + bias, 0.f);
        x3_s[4224 + (4*lg + j)*264 + col] = (_Float16)fmaxf(a1[j] + bias, 0.f);
      }
    }
  }
  __syncthreads();
  {
    const int r0 = ((2*p) >> 6)*16, t0 = (2*p) & 63;
#pragma unroll
    for (int cc = 0; cc < 12; ++cc){
      int col = (w*12 + cc)*16 + li;
      f32x4 a0 = 0.f, a1 = 0.f;
      for (int kk = 0; kk < 8; ++kk){
        f16x8 B  = *(const f16x8*)(GIHT + (size_t)col*256 + kk*32 + lg*8);
        f16x8 A0 = *(const f16x8*)(x3_s + li*264 + kk*32 + lg*8);
        f16x8 A1 = *(const f16x8*)(x3_s + 4224 + li*264 + kk*32 + lg*8);
        a0 = mfma16(A0, B, a0);
        a1 = mfma16(A1, B, a1);
      }
      float bias = gib[col];
#pragma unroll
      for (int j = 0; j < 4; ++j){
        int q = 4*lg + j;
        gi[((size_t)((r0 + q)*64 + t0))*768 + col]     = a0[j] + bias;
        gi[((size_t)((r0 + q)*64 + t0 + 1))*768 + col] = a1[j] + bias;
      }
    }
  }
}

// ------------------------------------------------------------------ K3: GRU
__global__ __launch_bounds__(256) void k3_gru(
    const _Float16* __restrict__ WHH, const float* __restrict__ bhh,
    const float* __restrict__ gi, const float* __restrict__ h0,
    float* __restrict__ hs)
{
  const int rb = blockIdx.x;
  const int row0 = rb * 16;
  const int tid = threadIdx.x;
  const int w = tid >> 6, lg = (tid >> 4) & 3, li = tid & 15;

  extern __shared__ char smem3[];
  _Float16* hf16 = (_Float16*)smem3;
  float* hf32 = (float*)(smem3 + 8448);
  float* gh   = (float*)(smem3 + 8448 + 16640);
  float* bhs  = (float*)(smem3 + 8448 + 16640 + 49664);

  for (int idx = tid; idx < 768; idx += 256) bhs[idx] = bhh[idx];
  for (int idx = tid; idx < 4096; idx += 256){
    int r = idx >> 8, d = idx & 255;
    float v = h0[(size_t)(row0 + r)*256 + d];
    hf32[r*260 + d] = v;
    hf16[r*264 + d] = (_Float16)v;
  }
  __syncthreads();

  const int er = tid >> 4;
  const int d0 = (tid & 15) * 16;

  for (int t = 0; t < 64; ++t){
    const float* gp = gi + ((size_t)(row0 + er)*64 + t)*768 + d0;
    f32x4 gr[4], gz[4], gn[4];
#pragma unroll
    for (int v = 0; v < 4; ++v){
      gr[v] = *(const f32x4*)(gp + v*4);
      gz[v] = *(const f32x4*)(gp + 256 + v*4);
      gn[v] = *(const f32x4*)(gp + 512 + v*4);
    }
    f16x8 a[8];
#pragma unroll
    for (int kk = 0; kk < 8; ++kk)
      a[kk] = *(const f16x8*)(hf16 + li*264 + kk*32 + lg*8);
    f32x4 acc[12];
#pragma unroll
    for (int c = 0; c < 12; ++c) acc[c] = 0.f;
#pragma unroll
    for (int c = 0; c < 12; ++c){
      const _Float16* bp = WHH + (size_t)(w*192 + c*16 + li)*256 + lg*8;
#pragma unroll
      for (int kk = 0; kk < 8; ++kk)
        acc[c] = mfma16(a[kk], *(const f16x8*)(bp + kk*32), acc[c]);
    }
#pragma unroll
    for (int c = 0; c < 12; ++c){
      int col = w*192 + c*16 + li;
#pragma unroll
      for (int j = 0; j < 4; ++j)
        gh[(4*lg + j)*776 + col] = acc[c][j];
    }
    __syncthreads();
    {
      float* hp32 = hf32 + er*260 + d0;
      float* hsp  = hs + ((size_t)(rb*64 + t)*16 + er)*256 + d0;
      f16x8 hv8[2];
#pragma unroll
      for (int v = 0; v < 4; ++v){
        f32x4 xr = *(const f32x4*)(gh + er*776 +       d0 + v*4);
        f32x4 xz = *(const f32x4*)(gh + er*776 + 256 + d0 + v*4);
        f32x4 xn = *(const f32x4*)(gh + er*776 + 512 + d0 + v*4);
        f32x4 hold = *(const f32x4*)(hp32 + v*4);
        f32x4 hout;
#pragma unroll
        for (int e = 0; e < 4; ++e){
          int d = d0 + v*4 + e;
          float rr_ = 1.f/(1.f + __expf(-(gr[v][e] + xr[e] + bhs[d])));
          float zz  = 1.f/(1.f + __expf(-(gz[v][e] + xz[e] + bhs[256 + d])));
          float pre = gn[v][e] + rr_*(xn[e] + bhs[512 + d]);
          float nn  = 1.f - 2.f/(1.f + __expf(2.f*pre));
          float hv = (1.f - zz)*nn + zz*hold[e];
          hout[e] = hv;
          int sl = v*4 + e;
          hv8[sl >> 3][sl & 7] = (_Float16)hv;
        }
        *(f32x4*)(hp32 + v*4) = hout;
        *(f32x4*)(hsp + v*4)  = hout;
      }
      *(f16x8*)(hf16 + er*264 + d0)     = hv8[0];
      *(f16x8*)(hf16 + er*264 + d0 + 8) = hv8[1];
    }
    __syncthreads();
  }
}

// ------------------------------------------------------------------ K4: q out
__global__ __launch_bounds__(256) void k4_q(
    const _Float16* __restrict__ FC3T, const float* __restrict__ fc3b,
    const float* __restrict__ em, const float* __restrict__ hs, float* __restrict__ qo)
{
  const int tid = threadIdx.x;
  const int w = tid >> 6, lg = (tid >> 4) & 3, li = tid & 15;
  const int rb = blockIdx.x*64 + 16*w;
  f32x4 acc[2];
#pragma unroll
  for (int c = 0; c < 2; ++c) acc[c] = 0.f;
  for (int kk = 0; kk < 8; ++kk){
    const float* ap = hs + (size_t)(rb + li)*256 + kk*32 + lg*8;
    f32x4 v0 = *(const f32x4*)ap, v1 = *(const f32x4*)(ap + 4);
    f16x8 A;
#pragma unroll
    for (int e = 0; e < 4; ++e){ A[e] = (_Float16)v0[e]; A[e+4] = (_Float16)v1[e]; }
#pragma unroll
    for (int c = 0; c < 2; ++c){
      f16x8 B = *(const f16x8*)(FC3T + (size_t)(16*c + li)*256 + kk*32 + lg*8);
      acc[c] = mfma16(A, B, acc[c]);
    }
  }
#pragma unroll
  for (int c = 0; c < 2; ++c){
    int col = 16*c + li;
    float bias = fc3b[col];
#pragma unroll
    for (int j = 0; j < 4; ++j){
      int row = rb + 4*lg + j;
      float am = em[(size_t)(row >> 4)*64 + (row & 15)];
      qo[(size_t)row*32 + col] = (acc[c][j] + bias)*(1.f - am);
    }
  }
}

// --------------------------------------------------------------------- launch
extern "C" void kernel_launch(void* const* d_in, const int* in_sizes, int n_in,
                              void* d_out, int out_size, void* d_ws, size_t ws_size,
                              hipStream_t stream)
{
  constexpr size_t OFF_FC1T   = 0;
  constexpr size_t OFF_MSG1T  = 49152;
  constexpr size_t OFF_AINT   = 98304;
  constexpr size_t OFF_LINT   = 491520;
  constexpr size_t OFF_AOUTT  = 884736;
  constexpr size_t OFF_LOUTT  = 1015808;
  constexpr size_t OFF_GMINT  = 1146880;
  constexpr size_t OFF_GMOUTT = 1540096;
  constexpr size_t OFF_FC2T   = 1671168;
  constexpr size_t OFF_GIHT   = 1933312;
  constexpr size_t OFF_GHHT   = 2326528;
  constexpr size_t OFF_FC3T   = 2719744;
  constexpr size_t OFF_G1T    = 2736128;
  constexpr size_t OFF_GINT   = 2834432;
  constexpr size_t OFF_WVEFF  = 3620864;
  constexpr size_t OFF_BEFF   = 3637248;
  constexpr size_t OFF_GATE   = 3637504;
  constexpr size_t OFF_X2     = 3768576;
  constexpr size_t OFF_X2M    = 37323008;
  constexpr size_t OFF_GI     = 70877440;
  constexpr size_t NEED       = 171540736;
  if (ws_size < NEED) return;

  char* ws = (char*)d_ws;
  const float* ent = (const float*)d_in[0];
  const float* om  = (const float*)d_in[1];
  const float* em  = (const float*)d_in[2];

  WJobs jb{};
  int nj = 0;
  auto addj = [&](int src_idx, size_t off, int K, int N, int m){
    jb.src[nj] = (const float*)d_in[src_idx]; jb.off[nj] = (unsigned)off;
    jb.K[nj] = K; jb.N[nj] = N; jb.mode[nj] = m; ++nj;
  };
  addj(4,  OFF_FC1T,   96, 256, 0);
  addj(17, OFF_MSG1T,  96, 256, 0);
  addj(6,  OFF_AINT,  256, 768, 0);
  addj(19, OFF_LINT,  256, 768, 0);
  addj(7,  OFF_AOUTT, 256, 256, 0);
  addj(20, OFF_LOUTT, 256, 256, 0);
  addj(22, OFF_GMINT, 256, 768, 0);
  addj(23, OFF_GMOUTT,256, 256, 0);
  addj(9,  OFF_FC2T,  512, 256, 0);
  addj(11, OFF_GIHT,  256, 768, 0);
  addj(12, OFF_GHHT,  256, 768, 0);
  addj(15, OFF_FC3T,  256,  32, 0);
  addj(28, OFF_G1T,    96, 256, 1);
  addj(25, OFF_GINT,  256, 768, 1);
  k0_conv<<<dim3(96, nj), 256, 0, stream>>>(jb, ws);

  k0w_gate<<<1, 256, 0, stream>>>(
      (const float*)d_in[26], (const float*)d_in[30],
      (const float*)d_in[27], (const float*)d_in[25],
      (_Float16*)(ws + OFF_WVEFF), (float*)(ws + OFF_BEFF));

  constexpr int SMB = 156672, SMK2 = 109184, SM3 = 77824;
  (void)hipFuncSetAttribute(reinterpret_cast<const void*>(&k1_all),
                            hipFuncAttributeMaxDynamicSharedMemorySize, SMB);
  (void)hipFuncSetAttribute(reinterpret_cast<const void*>(&k2_global),
                            hipFuncAttributeMaxDynamicSharedMemorySize, SMK2);
  (void)hipFuncSetAttribute(reinterpret_cast<const void*>(&k3_gru),
                            hipFuncAttributeMaxDynamicSharedMemorySize, SM3);

  float* qout = (float*)d_out;
  float* hsout = qout + 1048576;
  float* gout = qout + 9437184;

  k1_all<<<4096, 512, SMB, stream>>>(ent, om, em,
      (const _Float16*)(ws + OFF_FC1T),  (const float*)d_in[5],
      (const _Float16*)(ws + OFF_AINT),
      (const _Float16*)(ws + OFF_AOUTT), (const float*)d_in[8],
      (float*)(ws + OFF_X2),
      (const _Float16*)(ws + OFF_MSG1T), (const float*)d_in[18],
      (const _Float16*)(ws + OFF_LINT),
      (const _Float16*)(ws + OFF_LOUTT), (const float*)d_in[21],
      (float*)(ws + OFF_X2M),
      (const _Float16*)(ws + OFF_G1T),   (const float*)d_in[29],
      (const _Float16*)(ws + OFF_GINT),
      (const _Float16*)(ws + OFF_WVEFF),
      (const float*)(ws + OFF_BEFF), (const float*)d_in[31],
      gout, (float*)(ws + OFF_GATE));

  k2_global<<<1024, 256, SMK2, stream>>>(em,
      (const float*)(ws + OFF_X2), (const float*)(ws + OFF_X2M),
      (const float*)(ws + OFF_GATE),
      (const _Float16*)(ws + OFF_GMINT), (const _Float16*)(ws + OFF_GMOUTT), (const float*)d_in[24],
      (const _Float16*)(ws + OFF_FC2T), (const float*)d_in[10],
      (const _Float16*)(ws + OFF_GIHT), (const float*)d_in[13],
      (float*)(ws + OFF_GI));

  k3_gru<<<32, 256, SM3, stream>>>(
      (const _Float16*)(ws + OFF_GHHT), (const float*)d_in[14],
      (const float*)(ws + OFF_GI), (const float*)d_in[3], hsout);

  k4_q<<<512, 256, 0, stream>>>(
      (const _Float16*)(ws + OFF_FC3T), (const float*)d_in[16],
      em, hsout, qout);
}

// Round 16
// 1332.596 us; speedup vs baseline: 1.1991x; 1.0924x over previous
//
#include <hip/hip_runtime.h>

// EntityAttentionRNNMsgAgent — fused MI355X implementation.
// r16 = r15 + 32x32 MFMA conversion of the remaining large-M phases in
// k1_all: branch2 x1 (24 mfma32/wave vs 48 mfma16), gate x1 split-2
// (36 vs 72), gate K_h split-2 k-split across 8 waves with f32 LDS
// partial-reduce (24 mfma32/wave vs 48 mfma16; Kpart scratch fits in the
// existing 156.7KB LDS alloc). Q/logits/PV/out-proj stay 16x16 (M=16).
// Everything else byte-identical to r15 (1455.7us verified).

#define DEV __device__ __forceinline__

typedef _Float16 f16x8 __attribute__((ext_vector_type(8)));
typedef _Float16 f16x4 __attribute__((ext_vector_type(4)));
typedef float    f32x4 __attribute__((ext_vector_type(4)));
typedef float    f32x16 __attribute__((ext_vector_type(16)));

DEV f32x4 mfma16(f16x8 a, f16x8 b, f32x4 c){
  return __builtin_amdgcn_mfma_f32_16x16x32_f16(a, b, c, 0, 0, 0);
}
DEV f32x16 mfma32(f16x8 a, f16x8 b, f32x16 c){
  return __builtin_amdgcn_mfma_f32_32x32x16_f16(a, b, c, 0, 0, 0);
}

// A/B fragment pair for optional split-precision (MODE=1: value = hi + lo)
template<int MODE> struct AB {
  f16x8 hi, lo;
  DEV void mf(const AB& b, f32x4& c) const {
    if constexpr (MODE){
      c = mfma16(lo, b.hi, c);
      c = mfma16(hi, b.lo, c);
    }
    c = mfma16(hi, b.hi, c);
  }
};

template<int MODE> DEV AB<MODE> ldW(const _Float16* p, int losz){
  AB<MODE> r; r.hi = *(const f16x8*)p;
  if constexpr (MODE) r.lo = *(const f16x8*)(p + losz);
  return r;
}
template<int MODE> DEV AB<MODE> ldL(const _Float16* ph, const _Float16* pl){
  AB<MODE> r; r.hi = *(const f16x8*)ph;
  if constexpr (MODE) r.lo = *(const f16x8*)pl;
  return r;
}
template<int MODE> DEV AB<MODE> ldF(const float* p){
  AB<MODE> r;
  f32x4 v0 = *(const f32x4*)p, v1 = *(const f32x4*)(p + 4);
#pragma unroll
  for (int i = 0; i < 4; ++i){
    float a = v0[i], b = v1[i];
    _Float16 ah = (_Float16)a, bh = (_Float16)b;
    r.hi[i] = ah; r.hi[i+4] = bh;
    if constexpr (MODE){
      r.lo[i]   = (_Float16)(a - (float)ah);
      r.lo[i+4] = (_Float16)(b - (float)bh);
    }
  }
  return r;
}
template<int MODE> DEV void stL(_Float16* ph, _Float16* pl, int idx, float v){
  _Float16 h = (_Float16)v;
  ph[idx] = h;
  if constexpr (MODE) pl[idx] = (_Float16)(v - (float)h);
}

// ---------------------------------------------------------------- K0: weights
struct WJobs {
  const float* src[15];
  unsigned off[15];
  int K[15], N[15], mode[15];
};

__global__ __launch_bounds__(256) void k0_conv(WJobs jb, char* ws){
  const int job = blockIdx.y;
  const int K = jb.K[job], N = jb.N[job];
  const int total = K * N;
  _Float16* dh = (_Float16*)(ws + jb.off[job]);
  const float* src = jb.src[job];
  const int m = jb.mode[job];
  for (int idx = blockIdx.x*256 + threadIdx.x; idx < total; idx += gridDim.x*256){
    int n = idx / K, k = idx - n*K;
    float v = src[(size_t)k*N + n];
    _Float16 h = (_Float16)v;
    dh[idx] = h;
    if (m) dh[total + idx] = (_Float16)(v - (float)h);
  }
}

// ------------------------------------------------- K0w: gate-tail precompute
__global__ __launch_bounds__(256) void k0w_gate(
    const float* __restrict__ Wout, const float* __restrict__ Wg2,
    const float* __restrict__ bo,   const float* __restrict__ Win,
    _Float16* __restrict__ wveff, float* __restrict__ beff)
{
  __shared__ float weff_s[256*2];
  const int tid = threadIdx.x;
  {
    float a0 = 0.f, a1 = 0.f;
    const float* wr = Wout + (size_t)tid*256;
    for (int f = 0; f < 256; ++f){ float x = wr[f]; a0 += x*Wg2[2*f]; a1 += x*Wg2[2*f+1]; }
    weff_s[tid*2] = a0; weff_s[tid*2+1] = a1;
  }
  if (tid < 2){
    float s = 0.f;
    for (int f = 0; f < 256; ++f) s += bo[f]*Wg2[2*f + tid];
    beff[tid] = s;
  }
  __syncthreads();
  {
    const int j = tid;
    for (int n = 0; n < 16; ++n){
      float v = 0.f;
      if (n < 8){
        int h = n >> 1, c = n & 1;
        const float* wr = Win + (size_t)j*768 + 512 + h*64;
        const float* we = weff_s + (h*64)*2 + c;
        for (int d = 0; d < 64; ++d) v += wr[d]*we[2*d];
      }
      _Float16 hi = (_Float16)v;
      wveff[n*256 + j] = hi;
      wveff[16*256 + n*256 + j] = (_Float16)(v - (float)hi);
    }
  }
}

// -------------------------------------------- K1 fused: branch2 + gate roles
__global__ __launch_bounds__(512) void k1_all(
    const float* __restrict__ ent, const float* __restrict__ om, const float* __restrict__ em,
    const _Float16* __restrict__ W1a, const float* __restrict__ b1a,
    const _Float16* __restrict__ WINa,
    const _Float16* __restrict__ WOUTa, const float* __restrict__ boa,
    float* __restrict__ x2outa,
    const _Float16* __restrict__ W1b, const float* __restrict__ b1b,
    const _Float16* __restrict__ WINb,
    const _Float16* __restrict__ WOUTb, const float* __restrict__ bob,
    float* __restrict__ x2outb,
    const _Float16* __restrict__ W1g, const float* __restrict__ b1g,
    const _Float16* __restrict__ WINg,
    const _Float16* __restrict__ WVEFF,
    const float* __restrict__ beff, const float* __restrict__ gb2,
    float* __restrict__ og, float* __restrict__ gate)
{
  const int tid = threadIdx.x;
  const int w = tid >> 6, lg = (tid >> 4) & 3, li = tid & 15;
  extern __shared__ char smem[];

  if (blockIdx.x < 2048){
    // ============================ branch2 role ============================
    const int br = blockIdx.x >> 10;
    const int p  = blockIdx.x & 1023;
    const int bb2[2] = { 2*p, 2*p + 1 };
    const _Float16* W1   = br ? W1b   : W1a;
    const float*    b1   = br ? b1b   : b1a;
    const _Float16* WIN  = br ? WINb  : WINa;
    const _Float16* WOUT = br ? WOUTb : WOUTa;
    const float*    bo   = br ? bob   : boa;
    float*          x2out= br ? x2outb: x2outa;

    const int wi = w & 3, ih = w >> 2;
    const int l = tid & 63;              // lane within wave
    const int r32 = l & 31, kh = (l >> 5)*8;

    _Float16* x1  = (_Float16*)smem;
    _Float16* Ks  = (_Float16*)(smem + 67584);
    _Float16* Vs  = (_Float16*)(smem + 86016);
    _Float16* Qs  = (_Float16*)(smem + 104448);
    float*    lgs = (float*)(smem + 109056);
    _Float16* Ps  = (_Float16*)(smem + 118272);
    float*    outp= (float*)(smem + 122880);

    { // phase 1: x1 = relu(ent @ W1 + b1) via 32x32x16
      // wave (wi, ih): item ih, mt = wi&1, n-tiles {(wi>>1)*4 .. +3}
      const int b = bb2[ih];
      _Float16* x1p = x1 + ih*16896;
      const int mt = wi & 1, ntb = (wi >> 1)*4;
      f32x16 acc0 = 0.f, acc1 = 0.f, acc2 = 0.f, acc3 = 0.f;
#pragma unroll
      for (int kk = 0; kk < 6; ++kk){
        AB<0> a = ldF<0>(ent + ((size_t)b*64 + mt*32 + r32)*96 + kk*16 + kh);
        f16x8 B0 = *(const f16x8*)(W1 + (size_t)((ntb + 0)*32 + r32)*96 + kk*16 + kh);
        f16x8 B1 = *(const f16x8*)(W1 + (size_t)((ntb + 1)*32 + r32)*96 + kk*16 + kh);
        f16x8 B2 = *(const f16x8*)(W1 + (size_t)((ntb + 2)*32 + r32)*96 + kk*16 + kh);
        f16x8 B3 = *(const f16x8*)(W1 + (size_t)((ntb + 3)*32 + r32)*96 + kk*16 + kh);
        acc0 = mfma32(a.hi, B0, acc0);
        acc1 = mfma32(a.hi, B1, acc1);
        acc2 = mfma32(a.hi, B2, acc2);
        acc3 = mfma32(a.hi, B3, acc3);
      }
#pragma unroll
      for (int s = 0; s < 4; ++s){
        const f32x16& ac = (s == 0) ? acc0 : (s == 1) ? acc1 : (s == 2) ? acc2 : acc3;
        int col = (ntb + s)*32 + r32;
        float bias = b1[col];
#pragma unroll
        for (int reg = 0; reg < 16; ++reg){
          int row = (reg & 3) + 8*(reg >> 2) + 4*(l >> 5);
          x1p[(mt*32 + row)*264 + col] = (_Float16)fmaxf(ac[reg] + bias, 0.f);
        }
      }
    }
    __syncthreads();

    for (int h = 0; h < 4; ++h){
      // K (waves 0-3) / V (waves 4-7) via 32x32x16, both items per wave
      if (w < 4){
        const int kt = w >> 1, dt = w & 1;
        f32x16 acc0 = 0.f, acc1 = 0.f;
        for (int kk = 0; kk < 16; ++kk){
          int ao = (kt*32 + r32)*264 + kk*16 + kh;
          f16x8 A0 = *(const f16x8*)(x1 + ao);
          f16x8 A1 = *(const f16x8*)(x1 + 16896 + ao);
          f16x8 B = *(const f16x8*)(WIN + (size_t)(256 + 64*h + dt*32 + r32)*256 + kk*16 + kh);
          acc0 = mfma32(A0, B, acc0);
          acc1 = mfma32(A1, B, acc1);
        }
#pragma unroll
        for (int reg = 0; reg < 16; ++reg){
          int row = (reg & 3) + 8*(reg >> 2) + 4*(l >> 5);
          Ks[(kt*32 + row)*72 + dt*32 + r32]        = (_Float16)acc0[reg];
          Ks[4608 + (kt*32 + row)*72 + dt*32 + r32] = (_Float16)acc1[reg];
        }
      } else {
        const int wv = w - 4;
        const int kt = wv >> 1, dt = wv & 1;
        f32x16 acc0 = 0.f, acc1 = 0.f;
        for (int kk = 0; kk < 16; ++kk){
          int ao = (kt*32 + r32)*264 + kk*16 + kh;
          f16x8 A0 = *(const f16x8*)(x1 + ao);
          f16x8 A1 = *(const f16x8*)(x1 + 16896 + ao);
          f16x8 B = *(const f16x8*)(WIN + (size_t)(512 + 64*h + dt*32 + r32)*256 + kk*16 + kh);
          acc0 = mfma32(A0, B, acc0);
          acc1 = mfma32(A1, B, acc1);
        }
#pragma unroll
        for (int rr = 0; rr < 4; ++rr){
          f16x4 p0, p1;
#pragma unroll
          for (int q4 = 0; q4 < 4; ++q4){
            p0[q4] = (_Float16)acc0[rr*4 + q4];
            p1[q4] = (_Float16)acc1[rr*4 + q4];
          }
          int key = kt*32 + rr*8 + 4*(l >> 5);
          *(f16x4*)(Vs + (dt*32 + r32)*72 + key)        = p0;
          *(f16x4*)(Vs + 4608 + (dt*32 + r32)*72 + key) = p1;
        }
      }
      { // Q_h: rows 0..15, wave -> dim tile wi, item ih (16x16 path)
        f32x4 acc = 0.f;
        for (int kk = 0; kk < 8; ++kk){
          f16x8 A = *(const f16x8*)(x1 + ih*16896 + li*264 + kk*32 + lg*8);
          f16x8 B = *(const f16x8*)(WIN + (size_t)(64*h + 16*wi + li)*256 + kk*32 + lg*8);
          acc = mfma16(A, B, acc);
        }
#pragma unroll
        for (int j = 0; j < 4; ++j)
          Qs[ih*1152 + (4*lg + j)*72 + 16*wi + li] = (_Float16)acc[j];
      }
      __syncthreads();
      { // logits
        const int b = bb2[ih];
        f32x4 acc = 0.f;
#pragma unroll
        for (int kk = 0; kk < 2; ++kk){
          f16x8 A = *(const f16x8*)(Qs + ih*1152 + li*72 + kk*32 + lg*8);
          f16x8 B = *(const f16x8*)(Ks + ih*4608 + (16*wi + li)*72 + kk*32 + lg*8);
          acc = mfma16(A, B, acc);
        }
#pragma unroll
        for (int j = 0; j < 4; ++j){
          int q = 4*lg + j, key = 16*wi + li;
          float v = acc[j] * 0.125f;
          float m = om[((size_t)b*64 + q)*64 + key];
          if (m > 0.f) v = -1e9f;
          lgs[ih*1152 + q*72 + key] = v;
        }
      }
      __syncthreads();
      { // softmax
        const int it = tid >> 8, q = (tid >> 4) & 15, i16 = tid & 15;
        const int b = bb2[it];
        float pv[4], mx = -3e38f;
#pragma unroll
        for (int u = 0; u < 4; ++u){ pv[u] = lgs[it*1152 + q*72 + i16 + 16*u]; mx = fmaxf(mx, pv[u]); }
#pragma unroll
        for (int d = 1; d < 16; d <<= 1) mx = fmaxf(mx, __shfl_xor(mx, d, 16));
        float s = 0.f;
#pragma unroll
        for (int u = 0; u < 4; ++u){ pv[u] = expf(pv[u] - mx); s += pv[u]; }
#pragma unroll
        for (int d = 1; d < 16; d <<= 1) s += __shfl_xor(s, d, 16);
#pragma unroll
        for (int u = 0; u < 4; ++u){
          int key = i16 + 16*u;
          float m = om[((size_t)b*64 + q)*64 + key];
          Ps[it*1152 + q*72 + key] = (_Float16)((pv[u]/s)*(1.f - m));
        }
      }
      __syncthreads();
      { // out_h = P @ V_h
        f32x4 acc = 0.f;
#pragma unroll
        for (int kk = 0; kk < 2; ++kk){
          f16x8 A = *(const f16x8*)(Ps + ih*1152 + li*72 + kk*32 + lg*8);
          f16x8 B = *(const f16x8*)(Vs + ih*4608 + (16*wi + li)*72 + kk*32 + lg*8);
          acc = mfma16(A, B, acc);
        }
#pragma unroll
        for (int j = 0; j < 4; ++j)
          outp[ih*4224 + (4*lg + j)*264 + 64*h + 16*wi + li] = acc[j];
      }
      __syncthreads();
    }

    {
      f32x4 acc[2][2];
#pragma unroll
      for (int it = 0; it < 2; ++it)
#pragma unroll
        for (int c = 0; c < 2; ++c) acc[it][c] = 0.f;
      for (int kk = 0; kk < 8; ++kk){
        AB<0> a0 = ldF<0>(outp + li*264 + kk*32 + lg*8);
        AB<0> a1 = ldF<0>(outp + 4224 + li*264 + kk*32 + lg*8);
#pragma unroll
        for (int cc = 0; cc < 2; ++cc){
          int c = 2*ih + cc;
          f16x8 B = *(const f16x8*)(WOUT + (size_t)(64*wi + 16*c + li)*256 + kk*32 + lg*8);
          acc[0][cc] = mfma16(a0.hi, B, acc[0][cc]);
          acc[1][cc] = mfma16(a1.hi, B, acc[1][cc]);
        }
      }
#pragma unroll
      for (int it = 0; it < 2; ++it){
        const int b = bb2[it];
#pragma unroll
        for (int cc = 0; cc < 2; ++cc){
          int col = 64*wi + 16*(2*ih + cc) + li;
          float bias = bo[col];
#pragma unroll
          for (int j = 0; j < 4; ++j){
            int q = 4*lg + j;
            float v = (acc[it][cc][j] + bias) * (1.f - em[(size_t)b*64 + q]);
            x2out[((size_t)b*16 + q)*256 + col] = v;
          }
        }
      }
    }
    return;
  }

  // ============================== gate role ==============================
  {
    constexpr int W1SZ = 96*256, WINSZ = 256*768, WVSZ = 16*256;
    const int b = blockIdx.x - 2048;
    const int l = tid & 63;
    const int r32 = l & 31, kh = (l >> 5)*8;

    char* sp = smem;
    _Float16* x1h = (_Float16*)sp; sp += 64*264*2;
    _Float16* x1l = (_Float16*)sp; sp += 64*264*2;
    _Float16* Kh  = (_Float16*)sp; sp += 64*72*2;
    _Float16* Kl  = (_Float16*)sp; sp += 64*72*2;
    _Float16* Qh  = (_Float16*)sp; sp += 16*264*2;
    _Float16* Ql  = (_Float16*)sp; sp += 16*264*2;
    float*    lgs = (float*)sp;    sp += 16*72*4;
    float*    Ps  = (float*)sp;    sp += 16*66*4;
    float*    v2s = (float*)sp;    sp += 64*18*4;
    float*  ogacc = (float*)sp;    sp += 32*4;
    float*  Kpart = (float*)sp;    sp += 8192*4;   // 2 k-halves x 4 tiles x 32x32

    { // phase 1: x1 = relu(ent @ W1g + b1g), 32x32 split-2
      // wave w: mt = w&1, n-tiles {(w>>1)*2, +1}
      const int mt = w & 1, ntb = (w >> 1)*2;
      f32x16 acc0 = 0.f, acc1 = 0.f;
#pragma unroll
      for (int kk = 0; kk < 6; ++kk){
        AB<1> a = ldF<1>(ent + ((size_t)b*64 + mt*32 + r32)*96 + kk*16 + kh);
#pragma unroll
        for (int s = 0; s < 2; ++s){
          const _Float16* bp = W1g + (size_t)((ntb + s)*32 + r32)*96 + kk*16 + kh;
          f16x8 Bh = *(const f16x8*)bp;
          f16x8 Bl = *(const f16x8*)(bp + W1SZ);
          f32x16& ac = s ? acc1 : acc0;
          ac = mfma32(a.lo, Bh, ac);
          ac = mfma32(a.hi, Bl, ac);
          ac = mfma32(a.hi, Bh, ac);
        }
      }
#pragma unroll
      for (int s = 0; s < 2; ++s){
        const f32x16& ac = s ? acc1 : acc0;
        int col = (ntb + s)*32 + r32;
        float bias = b1g[col];
#pragma unroll
        for (int reg = 0; reg < 16; ++reg){
          int row = (reg & 3) + 8*(reg >> 2) + 4*(l >> 5);
          stL<1>(x1h, x1l, (mt*32 + row)*264 + col, fmaxf(ac[reg] + bias, 0.f));
        }
      }
    }
    if (tid < 32) ogacc[tid] = 0.f;
    __syncthreads();

    { // phase 2: Qfull (16x16 path), v2
#pragma unroll
      for (int s = 0; s < 2; ++s){
        int nt = w + s*8;
        f32x4 acc = 0.f;
        for (int kk = 0; kk < 8; ++kk){
          int ao = li*264 + kk*32 + lg*8;
          AB<1> a = ldL<1>(x1h + ao, x1l + ao);
          AB<1> bb = ldW<1>(WINg + (size_t)(nt*16 + li)*256 + kk*32 + lg*8, WINSZ);
          a.mf(bb, acc);
        }
#pragma unroll
        for (int j = 0; j < 4; ++j)
          stL<1>(Qh, Ql, (4*lg + j)*264 + nt*16 + li, acc[j]);
      }
      if (w < 4){
        f32x4 acc = 0.f;
        for (int kk = 0; kk < 8; ++kk){
          int ao = (w*16 + li)*264 + kk*32 + lg*8;
          AB<1> a = ldL<1>(x1h + ao, x1l + ao);
          AB<1> bb = ldW<1>(WVEFF + (size_t)li*256 + kk*32 + lg*8, WVSZ);
          a.mf(bb, acc);
        }
#pragma unroll
        for (int j = 0; j < 4; ++j)
          v2s[(w*16 + 4*lg + j)*18 + li] = acc[j];
      }
    }
    __syncthreads();

    for (int h = 0; h < 4; ++h){
      { // K_h partials: 32x32 split-2, tiles x k-halves across 8 waves
        const int t = w & 3, kt = t >> 1, dt = t & 1, khalf = w >> 2;
        f32x16 acc = 0.f;
#pragma unroll
        for (int k8 = 0; k8 < 8; ++k8){
          int ko = (khalf*8 + k8)*16 + kh;
          int ao = (kt*32 + r32)*264 + ko;
          f16x8 ah = *(const f16x8*)(x1h + ao);
          f16x8 al = *(const f16x8*)(x1l + ao);
          const _Float16* bp = WINg + (size_t)(256 + h*64 + dt*32 + r32)*256 + ko;
          f16x8 Bh = *(const f16x8*)bp;
          f16x8 Bl = *(const f16x8*)(bp + WINSZ);
          acc = mfma32(al, Bh, acc);
          acc = mfma32(ah, Bl, acc);
          acc = mfma32(ah, Bh, acc);
        }
#pragma unroll
        for (int reg = 0; reg < 16; ++reg){
          int row = (reg & 3) + 8*(reg >> 2) + 4*(l >> 5);
          Kpart[((khalf*4 + t)*32 + row)*32 + r32] = acc[reg];
        }
      }
      __syncthreads();
      { // reduce k-halves -> Kh/Kl
        for (int e = tid; e < 4096; e += 512){
          float s2 = Kpart[e] + Kpart[4096 + e];
          int t2 = e >> 10, idx = e & 1023, row = idx >> 5, col = idx & 31;
          stL<1>(Kh, Kl, ((t2 >> 1)*32 + row)*72 + (t2 & 1)*32 + col, s2);
        }
      }
      __syncthreads();
      if (w < 4){ // logits
        f32x4 acc = 0.f;
#pragma unroll
        for (int kk = 0; kk < 2; ++kk){
          int ao = li*264 + h*64 + kk*32 + lg*8;
          AB<1> a = ldL<1>(Qh + ao, Ql + ao);
          int bo_ = (16*w + li)*72 + kk*32 + lg*8;
          AB<1> bb = ldL<1>(Kh + bo_, Kl + bo_);
          a.mf(bb, acc);
        }
#pragma unroll
        for (int j = 0; j < 4; ++j){
          int q = 4*lg + j, key = 16*w + li;
          float v = acc[j] * 0.125f;
          float m = om[((size_t)b*64 + q)*64 + key];
          if (m > 0.f) v = -1e9f;
          lgs[q*72 + key] = v;
        }
      }
      __syncthreads();
      if (tid < 256){ // softmax
        int q = tid >> 4, i16 = tid & 15;
        float pv[4], mx = -3e38f;
#pragma unroll
        for (int u = 0; u < 4; ++u){ pv[u] = lgs[q*72 + i16 + 16*u]; mx = fmaxf(mx, pv[u]); }
#pragma unroll
        for (int d = 1; d < 16; d <<= 1) mx = fmaxf(mx, __shfl_xor(mx, d, 16));
        float s = 0.f;
#pragma unroll
        for (int u = 0; u < 4; ++u){ pv[u] = expf(pv[u] - mx); s += pv[u]; }
#pragma unroll
        for (int d = 1; d < 16; d <<= 1) s += __shfl_xor(s, d, 16);
#pragma unroll
        for (int u = 0; u < 4; ++u){
          int key = i16 + 16*u;
          float m = om[((size_t)b*64 + q)*64 + key];
          Ps[q*66 + key] = (pv[u]/s)*(1.f - m);
        }
      }
      __syncthreads();
      if (tid < 256){ // og += P_h . v2_h
        int q = tid >> 4, l16 = tid & 15;
        float a0 = 0.f, a1 = 0.f;
#pragma unroll
        for (int u = 0; u < 4; ++u){
          int k = l16 + 16*u;
          float p2 = Ps[q*66 + k];
          a0 += p2 * v2s[k*18 + h*2];
          a1 += p2 * v2s[k*18 + h*2 + 1];
        }
#pragma unroll
        for (int d = 1; d < 16; d <<= 1){ a0 += __shfl_xor(a0, d, 16); a1 += __shfl_xor(a1, d, 16); }
        if (l16 == 0){ ogacc[q*2] += a0; ogacc[q*2 + 1] += a1; }
      }
      __syncthreads();
    }
    if (tid < 16){
      int q = tid;
      float am = em[(size_t)b*64 + q];
      float g0 = (1.f - am)*(ogacc[2*q]     + beff[0]) + gb2[0];
      float g1 = (1.f - am)*(ogacc[2*q + 1] + beff[1]) + gb2[1];
      og[((size_t)b*16 + q)*2]     = g0;
      og[((size_t)b*16 + q)*2 + 1] = g1;
      gate[(size_t)b*16 + q] = (g1 > g0) ? 1.f : 0.f;
    }
  }
}

// ------------------- K2: gate, global attention, fc2, gi — 2 items/block
__global__ __launch_bounds__(256) void k2_global(
    const float* __restrict__ em,
    const float* __restrict__ x2, const float* __restrict__ x2m,
    const float* __restrict__ gate,
    const _Float16* __restrict__ GMIN, const _Float16* __restrict__ GMOUT, const float* __restrict__ gob,
    const _Float16* __restrict__ FC2T, const float* __restrict__ fc2b,
    const _Float16* __restrict__ GIHT, const float* __restrict__ gib,
    float* __restrict__ gi)
{
  const int p = blockIdx.x;
  const int tid = threadIdx.x;
  const int w = tid >> 6, lg = (tid >> 4) & 3, li = tid & 15;

  extern __shared__ char smem[];
  float*    gate_s = (float*)smem;
  _Float16* gm_s   = (_Float16*)(smem + 128);
  _Float16* Q2     = (_Float16*)(smem + 17024);
  _Float16* K2s    = (_Float16*)(smem + 21632);
  _Float16* Vt2    = (_Float16*)(smem + 26240);
  float*    lg2    = (float*)(smem + 36480);
  _Float16* P2     = (_Float16*)(smem + 39552);
  _Float16* outp   = (_Float16*)(smem + 42112);
  _Float16* cat_s  = (_Float16*)(smem + 59008);
  _Float16* x3_s   = (_Float16*)(smem + 92288);

  if (tid < 32){
    int it = tid >> 4, q = tid & 15;
    gate_s[it*16 + q] = gate[(size_t)(2*p + it)*16 + q];
  }
  __syncthreads();
#pragma unroll
  for (int it = 0; it < 2; ++it){
    const int b = 2*p + it;
    for (int idx = tid; idx < 4096; idx += 256){
      int q = idx >> 8, d = idx & 255;
      gm_s[it*4224 + q*264 + d]  = (_Float16)(x2m[((size_t)b*16 + q)*256 + d] * gate_s[it*16 + q]);
      cat_s[it*8320 + q*520 + d] = (_Float16)(x2[((size_t)b*16 + q)*256 + d]);
    }
  }
  for (int idx = tid; idx < 2*64*40; idx += 256) Vt2[idx] = (_Float16)0.f;
  for (int idx = tid; idx < 2*16*40; idx += 256) P2[idx] = (_Float16)0.f;
  __syncthreads();
  for (int h = 0; h < 4; ++h){
    {
      f32x4 aq0 = 0.f, aq1 = 0.f, ak0 = 0.f, ak1 = 0.f, av0 = 0.f, av1 = 0.f;
      for (int kk = 0; kk < 8; ++kk){
        f16x8 A0 = *(const f16x8*)(gm_s + li*264 + kk*32 + lg*8);
        f16x8 A1 = *(const f16x8*)(gm_s + 4224 + li*264 + kk*32 + lg*8);
        f16x8 Bq = *(const f16x8*)(GMIN + (size_t)(      64*h + 16*w + li)*256 + kk*32 + lg*8);
        f16x8 Bk = *(const f16x8*)(GMIN + (size_t)(256 + 64*h + 16*w + li)*256 + kk*32 + lg*8);
        f16x8 Bv = *(const f16x8*)(GMIN + (size_t)(512 + 64*h + 16*w + li)*256 + kk*32 + lg*8);
        aq0 = mfma16(A0, Bq, aq0); aq1 = mfma16(A1, Bq, aq1);
        ak0 = mfma16(A0, Bk, ak0); ak1 = mfma16(A1, Bk, ak1);
        av0 = mfma16(A0, Bv, av0); av1 = mfma16(A1, Bv, av1);
      }
#pragma unroll
      for (int j = 0; j < 4; ++j){
        int rw = 4*lg + j, dim = 16*w + li;
        Q2[rw*72 + dim]         = (_Float16)aq0[j];
        Q2[1152 + rw*72 + dim]  = (_Float16)aq1[j];
        K2s[rw*72 + dim]        = (_Float16)ak0[j];
        K2s[1152 + rw*72 + dim] = (_Float16)ak1[j];
        Vt2[dim*40 + rw]        = (_Float16)av0[j];
        Vt2[2560 + dim*40 + rw] = (_Float16)av1[j];
      }
    }
    __syncthreads();
    if (w < 2){
      const int it = w, b = 2*p + it;
      f32x4 acc = 0.f;
#pragma unroll
      for (int kk = 0; kk < 2; ++kk){
        f16x8 A = *(const f16x8*)(Q2  + it*1152 + li*72 + kk*32 + lg*8);
        f16x8 B = *(const f16x8*)(K2s + it*1152 + li*72 + kk*32 + lg*8);
        acc = mfma16(A, B, acc);
      }
      float amk = em[(size_t)b*64 + li];
#pragma unroll
      for (int j = 0; j < 4; ++j){
        int q = 4*lg + j;
        float amq = em[(size_t)b*64 + q];
        float m = 1.f - (1.f - amq)*(1.f - amk);
        float v = acc[j]*0.125f;
        if (m > 0.f) v = -1e9f;
        lg2[it*384 + q*24 + li] = v;
      }
    }
    __syncthreads();
    {
      int q = tid >> 4, key = tid & 15;
#pragma unroll
      for (int it = 0; it < 2; ++it){
        const int b = 2*p + it;
        float v = lg2[it*384 + q*24 + key];
        float mx = v;
#pragma unroll
        for (int d = 1; d < 16; d <<= 1) mx = fmaxf(mx, __shfl_xor(mx, d, 16));
        float pe = expf(v - mx);
        float s = pe;
#pragma unroll
        for (int d = 1; d < 16; d <<= 1) s += __shfl_xor(s, d, 16);
        float amq = em[(size_t)b*64 + q], amk = em[(size_t)b*64 + key];
        float m = 1.f - (1.f - amq)*(1.f - amk);
        P2[it*640 + q*40 + key] = (_Float16)((pe/s)*(1.f - m));
      }
    }
    __syncthreads();
    {
#pragma unroll
      for (int it = 0; it < 2; ++it){
        f32x4 acc = 0.f;
        f16x8 A = *(const f16x8*)(P2 + it*640 + li*40 + lg*8);
        f16x8 B = *(const f16x8*)(Vt2 + it*2560 + (16*w + li)*40 + lg*8);
        acc = mfma16(A, B, acc);
#pragma unroll
        for (int j = 0; j < 4; ++j)
          outp[it*4224 + (4*lg + j)*264 + 64*h + 16*w + li] = (_Float16)acc[j];
      }
    }
    __syncthreads();
  }
  {
#pragma unroll
    for (int c = 0; c < 4; ++c){
      int col = 64*w + 16*c + li;
      f32x4 a0 = 0.f, a1 = 0.f;
      for (int kk = 0; kk < 8; ++kk){
        f16x8 B  = *(const f16x8*)(GMOUT + (size_t)col*256 + kk*32 + lg*8);
        f16x8 A0 = *(const f16x8*)(outp + li*264 + kk*32 + lg*8);
        f16x8 A1 = *(const f16x8*)(outp + 4224 + li*264 + kk*32 + lg*8);
        a0 = mfma16(A0, B, a0);
        a1 = mfma16(A1, B, a1);
      }
      float bias = gob[col];
#pragma unroll
      for (int j = 0; j < 4; ++j){
        int q = 4*lg + j;
        float m0 = 1.f - em[(size_t)(2*p)*64 + q];
        float m1 = 1.f - em[(size_t)(2*p + 1)*64 + q];
        cat_s[q*520 + 256 + col]        = (_Float16)((a0[j] + bias)*m0);
        cat_s[8320 + q*520 + 256 + col] = (_Float16)((a1[j] + bias)*m1);
      }
    }
  }
  __syncthreads();
  {
#pragma unroll
    for (int c = 0; c < 4; ++c){
      int col = 64*w + 16*c + li;
      f32x4 a0 = 0.f, a1 = 0.f;
      for (int kk = 0; kk < 16; ++kk){
        f16x8 B  = *(const f16x8*)(FC2T + (size_t)col*512 + kk*32 + lg*8);
        f16x8 A0 = *(const f16x8*)(cat_s + li*520 + kk*32 + lg*8);
        f16x8 A1 = *(const f16x8*)(cat_s + 8320 + li*520 + kk*32 + lg*8);
        a0 = mfma16(A0, B, a0);
        a1 = mfma16(A1, B, a1);
      }
      float bias = fc2b[col];
#pragma unroll
      for (int j = 0; j < 4; ++j){
        x3_s[(4*lg + j)*264 + col]        = (_Float16)fmaxf(a0[j] + bias, 0.f);
        x3_s[4224 + (4*lg + j)*264 + col] = (_Float16)fmaxf(a1[j] + bias, 0.f);
      }
    }
  }
  __syncthreads();
  {
    const int r0 = ((2*p) >> 6)*16, t0 = (2*p) & 63;
#pragma unroll
    for (int cc = 0; cc < 12; ++cc){
      int col = (w*12 + cc)*16 + li;
      f32x4 a0 = 0.f, a1 = 0.f;
      for (int kk = 0; kk < 8; ++kk){
        f16x8 B  = *(const f16x8*)(GIHT + (size_t)col*256 + kk*32 + lg*8);
        f16x8 A0 = *(const f16x8*)(x3_s + li*264 + kk*32 + lg*8);
        f16x8 A1 = *(const f16x8*)(x3_s + 4224 + li*264 + kk*32 + lg*8);
        a0 = mfma16(A0, B, a0);
        a1 = mfma16(A1, B, a1);
      }
      float bias = gib[col];
#pragma unroll
      for (int j = 0; j < 4; ++j){
        int q = 4*lg + j;
        gi[((size_t)((r0 + q)*64 + t0))*768 + col]     = a0[j] + bias;
        gi[((size_t)((r0 + q)*64 + t0 + 1))*768 + col] = a1[j] + bias;
      }
    }
  }
}

// ------------------------------------------------------------------ K3: GRU
__global__ __launch_bounds__(256) void k3_gru(
    const _Float16* __restrict__ WHH, const float* __restrict__ bhh,
    const float* __restrict__ gi, const float* __restrict__ h0,
    float* __restrict__ hs)
{
  const int rb = blockIdx.x;
  const int row0 = rb * 16;
  const int tid = threadIdx.x;
  const int w = tid >> 6, lg = (tid >> 4) & 3, li = tid & 15;

  extern __shared__ char smem3[];
  _Float16* hf16 = (_Float16*)smem3;
  float* hf32 = (float*)(smem3 + 8448);
  float* gh   = (float*)(smem3 + 8448 + 16640);
  float* bhs  = (float*)(smem3 + 8448 + 16640 + 49664);

  for (int idx = tid; idx < 768; idx += 256) bhs[idx] = bhh[idx];
  for (int idx = tid; idx < 4096; idx += 256){
    int r = idx >> 8, d = idx & 255;
    float v = h0[(size_t)(row0 + r)*256 + d];
    hf32[r*260 + d] = v;
    hf16[r*264 + d] = (_Float16)v;
  }
  __syncthreads();

  const int er = tid >> 4;
  const int d0 = (tid & 15) * 16;

  for (int t = 0; t < 64; ++t){
    const float* gp = gi + ((size_t)(row0 + er)*64 + t)*768 + d0;
    f32x4 gr[4], gz[4], gn[4];
#pragma unroll
    for (int v = 0; v < 4; ++v){
      gr[v] = *(const f32x4*)(gp + v*4);
      gz[v] = *(const f32x4*)(gp + 256 + v*4);
      gn[v] = *(const f32x4*)(gp + 512 + v*4);
    }
    f16x8 a[8];
#pragma unroll
    for (int kk = 0; kk < 8; ++kk)
      a[kk] = *(const f16x8*)(hf16 + li*264 + kk*32 + lg*8);
    f32x4 acc[12];
#pragma unroll
    for (int c = 0; c < 12; ++c) acc[c] = 0.f;
#pragma unroll
    for (int c = 0; c < 12; ++c){
      const _Float16* bp = WHH + (size_t)(w*192 + c*16 + li)*256 + lg*8;
#pragma unroll
      for (int kk = 0; kk < 8; ++kk)
        acc[c] = mfma16(a[kk], *(const f16x8*)(bp + kk*32), acc[c]);
    }
#pragma unroll
    for (int c = 0; c < 12; ++c){
      int col = w*192 + c*16 + li;
#pragma unroll
      for (int j = 0; j < 4; ++j)
        gh[(4*lg + j)*776 + col] = acc[c][j];
    }
    __syncthreads();
    {
      float* hp32 = hf32 + er*260 + d0;
      float* hsp  = hs + ((size_t)(rb*64 + t)*16 + er)*256 + d0;
      f16x8 hv8[2];
#pragma unroll
      for (int v = 0; v < 4; ++v){
        f32x4 xr = *(const f32x4*)(gh + er*776 +       d0 + v*4);
        f32x4 xz = *(const f32x4*)(gh + er*776 + 256 + d0 + v*4);
        f32x4 xn = *(const f32x4*)(gh + er*776 + 512 + d0 + v*4);
        f32x4 hold = *(const f32x4*)(hp32 + v*4);
        f32x4 hout;
#pragma unroll
        for (int e = 0; e < 4; ++e){
          int d = d0 + v*4 + e;
          float rr_ = 1.f/(1.f + __expf(-(gr[v][e] + xr[e] + bhs[d])));
          float zz  = 1.f/(1.f + __expf(-(gz[v][e] + xz[e] + bhs[256 + d])));
          float pre = gn[v][e] + rr_*(xn[e] + bhs[512 + d]);
          float nn  = 1.f - 2.f/(1.f + __expf(2.f*pre));
          float hv = (1.f - zz)*nn + zz*hold[e];
          hout[e] = hv;
          int sl = v*4 + e;
          hv8[sl >> 3][sl & 7] = (_Float16)hv;
        }
        *(f32x4*)(hp32 + v*4) = hout;
        *(f32x4*)(hsp + v*4)  = hout;
      }
      *(f16x8*)(hf16 + er*264 + d0)     = hv8[0];
      *(f16x8*)(hf16 + er*264 + d0 + 8) = hv8[1];
    }
    __syncthreads();
  }
}

// ------------------------------------------------------------------ K4: q out
__global__ __launch_bounds__(256) void k4_q(
    const _Float16* __restrict__ FC3T, const float* __restrict__ fc3b,
    const float* __restrict__ em, const float* __restrict__ hs, float* __restrict__ qo)
{
  const int tid = threadIdx.x;
  const int w = tid >> 6, lg = (tid >> 4) & 3, li = tid & 15;
  const int rb = blockIdx.x*64 + 16*w;
  f32x4 acc[2];
#pragma unroll
  for (int c = 0; c < 2; ++c) acc[c] = 0.f;
  for (int kk = 0; kk < 8; ++kk){
    const float* ap = hs + (size_t)(rb + li)*256 + kk*32 + lg*8;
    f32x4 v0 = *(const f32x4*)ap, v1 = *(const f32x4*)(ap + 4);
    f16x8 A;
#pragma unroll
    for (int e = 0; e < 4; ++e){ A[e] = (_Float16)v0[e]; A[e+4] = (_Float16)v1[e]; }
#pragma unroll
    for (int c = 0; c < 2; ++c){
      f16x8 B = *(const f16x8*)(FC3T + (size_t)(16*c + li)*256 + kk*32 + lg*8);
      acc[c] = mfma16(A, B, acc[c]);
    }
  }
#pragma unroll
  for (int c = 0; c < 2; ++c){
    int col = 16*c + li;
    float bias = fc3b[col];
#pragma unroll
    for (int j = 0; j < 4; ++j){
      int row = rb + 4*lg + j;
      float am = em[(size_t)(row >> 4)*64 + (row & 15)];
      qo[(size_t)row*32 + col] = (acc[c][j] + bias)*(1.f - am);
    }
  }
}

// --------------------------------------------------------------------- launch
extern "C" void kernel_launch(void* const* d_in, const int* in_sizes, int n_in,
                              void* d_out, int out_size, void* d_ws, size_t ws_size,
                              hipStream_t stream)
{
  constexpr size_t OFF_FC1T   = 0;
  constexpr size_t OFF_MSG1T  = 49152;
  constexpr size_t OFF_AINT   = 98304;
  constexpr size_t OFF_LINT   = 491520;
  constexpr size_t OFF_AOUTT  = 884736;
  constexpr size_t OFF_LOUTT  = 1015808;
  constexpr size_t OFF_GMINT  = 1146880;
  constexpr size_t OFF_GMOUTT = 1540096;
  constexpr size_t OFF_FC2T   = 1671168;
  constexpr size_t OFF_GIHT   = 1933312;
  constexpr size_t OFF_GHHT   = 2326528;
  constexpr size_t OFF_FC3T   = 2719744;
  constexpr size_t OFF_G1T    = 2736128;
  constexpr size_t OFF_GINT   = 2834432;
  constexpr size_t OFF_WVEFF  = 3620864;
  constexpr size_t OFF_BEFF   = 3637248;
  constexpr size_t OFF_GATE   = 3637504;
  constexpr size_t OFF_X2     = 3768576;
  constexpr size_t OFF_X2M    = 37323008;
  constexpr size_t OFF_GI     = 70877440;
  constexpr size_t NEED       = 171540736;
  if (ws_size < NEED) return;

  char* ws = (char*)d_ws;
  const float* ent = (const float*)d_in[0];
  const float* om  = (const float*)d_in[1];
  const float* em  = (const float*)d_in[2];

  WJobs jb{};
  int nj = 0;
  auto addj = [&](int src_idx, size_t off, int K, int N, int m){
    jb.src[nj] = (const float*)d_in[src_idx]; jb.off[nj] = (unsigned)off;
    jb.K[nj] = K; jb.N[nj] = N; jb.mode[nj] = m; ++nj;
  };
  addj(4,  OFF_FC1T,   96, 256, 0);
  addj(17, OFF_MSG1T,  96, 256, 0);
  addj(6,  OFF_AINT,  256, 768, 0);
  addj(19, OFF_LINT,  256, 768, 0);
  addj(7,  OFF_AOUTT, 256, 256, 0);
  addj(20, OFF_LOUTT, 256, 256, 0);
  addj(22, OFF_GMINT, 256, 768, 0);
  addj(23, OFF_GMOUTT,256, 256, 0);
  addj(9,  OFF_FC2T,  512, 256, 0);
  addj(11, OFF_GIHT,  256, 768, 0);
  addj(12, OFF_GHHT,  256, 768, 0);
  addj(15, OFF_FC3T,  256,  32, 0);
  addj(28, OFF_G1T,    96, 256, 1);
  addj(25, OFF_GINT,  256, 768, 1);
  k0_conv<<<dim3(96, nj), 256, 0, stream>>>(jb, ws);

  k0w_gate<<<1, 256, 0, stream>>>(
      (const float*)d_in[26], (const float*)d_in[30],
      (const float*)d_in[27], (const float*)d_in[25],
      (_Float16*)(ws + OFF_WVEFF), (float*)(ws + OFF_BEFF));

  constexpr int SMB = 156672, SMK2 = 109184, SM3 = 77824;
  (void)hipFuncSetAttribute(reinterpret_cast<const void*>(&k1_all),
                            hipFuncAttributeMaxDynamicSharedMemorySize, SMB);
  (void)hipFuncSetAttribute(reinterpret_cast<const void*>(&k2_global),
                            hipFuncAttributeMaxDynamicSharedMemorySize, SMK2);
  (void)hipFuncSetAttribute(reinterpret_cast<const void*>(&k3_gru),
                            hipFuncAttributeMaxDynamicSharedMemorySize, SM3);

  float* qout = (float*)d_out;
  float* hsout = qout + 1048576;
  float* gout = qout + 9437184;

  k1_all<<<4096, 512, SMB, stream>>>(ent, om, em,
      (const _Float16*)(ws + OFF_FC1T),  (const float*)d_in[5],
      (const _Float16*)(ws + OFF_AINT),
      (const _Float16*)(ws + OFF_AOUTT), (const float*)d_in[8],
      (float*)(ws + OFF_X2),
      (const _Float16*)(ws + OFF_MSG1T), (const float*)d_in[18],
      (const _Float16*)(ws + OFF_LINT),
      (const _Float16*)(ws + OFF_LOUTT), (const float*)d_in[21],
      (float*)(ws + OFF_X2M),
      (const _Float16*)(ws + OFF_G1T),   (const float*)d_in[29],
      (const _Float16*)(ws + OFF_GINT),
      (const _Float16*)(ws + OFF_WVEFF),
      (const float*)(ws + OFF_BEFF), (const float*)d_in[31],
      gout, (float*)(ws + OFF_GATE));

  k2_global<<<1024, 256, SMK2, stream>>>(em,
      (const float*)(ws + OFF_X2), (const float*)(ws + OFF_X2M),
      (const float*)(ws + OFF_GATE),
      (const _Float16*)(ws + OFF_GMINT), (const _Float16*)(ws + OFF_GMOUTT), (const float*)d_in[24],
      (const _Float16*)(ws + OFF_FC2T), (const float*)d_in[10],
      (const _Float16*)(ws + OFF_GIHT), (const float*)d_in[13],
      (float*)(ws + OFF_GI));

  k3_gru<<<32, 256, SM3, stream>>>(
      (const _Float16*)(ws + OFF_GHHT), (const float*)d_in[14],
      (const float*)(ws + OFF_GI), (const float*)d_in[3], hsout);

  k4_q<<<512, 256, 0, stream>>>(
      (const _Float16*)(ws + OFF_FC3T), (const float*)d_in[16],
      em, hsout, qout);
}

// Round 17
// 1312.314 us; speedup vs baseline: 1.2176x; 1.0155x over previous
//
#include <hip/hip_runtime.h>

// EntityAttentionRNNMsgAgent — fused MI355X implementation.
// r17 = r16 + branch2: Q hoisted out of the head loop as one stacked-M=32
// 32x32 GEMM (removes 4x redundant Wq loads + per-head Q phase), out-proj
// converted to stacked-M=32 32x32, outp stored f16 (bit-identical).
// Gate role / k0 / k0w / k2 / k3 / k4 byte-identical to r16 (1332.6us).

#define DEV __device__ __forceinline__

typedef _Float16 f16x8 __attribute__((ext_vector_type(8)));
typedef _Float16 f16x4 __attribute__((ext_vector_type(4)));
typedef float    f32x4 __attribute__((ext_vector_type(4)));
typedef float    f32x16 __attribute__((ext_vector_type(16)));

DEV f32x4 mfma16(f16x8 a, f16x8 b, f32x4 c){
  return __builtin_amdgcn_mfma_f32_16x16x32_f16(a, b, c, 0, 0, 0);
}
DEV f32x16 mfma32(f16x8 a, f16x8 b, f32x16 c){
  return __builtin_amdgcn_mfma_f32_32x32x16_f16(a, b, c, 0, 0, 0);
}

// A/B fragment pair for optional split-precision (MODE=1: value = hi + lo)
template<int MODE> struct AB {
  f16x8 hi, lo;
  DEV void mf(const AB& b, f32x4& c) const {
    if constexpr (MODE){
      c = mfma16(lo, b.hi, c);
      c = mfma16(hi, b.lo, c);
    }
    c = mfma16(hi, b.hi, c);
  }
};

template<int MODE> DEV AB<MODE> ldW(const _Float16* p, int losz){
  AB<MODE> r; r.hi = *(const f16x8*)p;
  if constexpr (MODE) r.lo = *(const f16x8*)(p + losz);
  return r;
}
template<int MODE> DEV AB<MODE> ldL(const _Float16* ph, const _Float16* pl){
  AB<MODE> r; r.hi = *(const f16x8*)ph;
  if constexpr (MODE) r.lo = *(const f16x8*)pl;
  return r;
}
template<int MODE> DEV AB<MODE> ldF(const float* p){
  AB<MODE> r;
  f32x4 v0 = *(const f32x4*)p, v1 = *(const f32x4*)(p + 4);
#pragma unroll
  for (int i = 0; i < 4; ++i){
    float a = v0[i], b = v1[i];
    _Float16 ah = (_Float16)a, bh = (_Float16)b;
    r.hi[i] = ah; r.hi[i+4] = bh;
    if constexpr (MODE){
      r.lo[i]   = (_Float16)(a - (float)ah);
      r.lo[i+4] = (_Float16)(b - (float)bh);
    }
  }
  return r;
}
template<int MODE> DEV void stL(_Float16* ph, _Float16* pl, int idx, float v){
  _Float16 h = (_Float16)v;
  ph[idx] = h;
  if constexpr (MODE) pl[idx] = (_Float16)(v - (float)h);
}

// ---------------------------------------------------------------- K0: weights
struct WJobs {
  const float* src[15];
  unsigned off[15];
  int K[15], N[15], mode[15];
};

__global__ __launch_bounds__(256) void k0_conv(WJobs jb, char* ws){
  const int job = blockIdx.y;
  const int K = jb.K[job], N = jb.N[job];
  const int total = K * N;
  _Float16* dh = (_Float16*)(ws + jb.off[job]);
  const float* src = jb.src[job];
  const int m = jb.mode[job];
  for (int idx = blockIdx.x*256 + threadIdx.x; idx < total; idx += gridDim.x*256){
    int n = idx / K, k = idx - n*K;
    float v = src[(size_t)k*N + n];
    _Float16 h = (_Float16)v;
    dh[idx] = h;
    if (m) dh[total + idx] = (_Float16)(v - (float)h);
  }
}

// ------------------------------------------------- K0w: gate-tail precompute
__global__ __launch_bounds__(256) void k0w_gate(
    const float* __restrict__ Wout, const float* __restrict__ Wg2,
    const float* __restrict__ bo,   const float* __restrict__ Win,
    _Float16* __restrict__ wveff, float* __restrict__ beff)
{
  __shared__ float weff_s[256*2];
  const int tid = threadIdx.x;
  {
    float a0 = 0.f, a1 = 0.f;
    const float* wr = Wout + (size_t)tid*256;
    for (int f = 0; f < 256; ++f){ float x = wr[f]; a0 += x*Wg2[2*f]; a1 += x*Wg2[2*f+1]; }
    weff_s[tid*2] = a0; weff_s[tid*2+1] = a1;
  }
  if (tid < 2){
    float s = 0.f;
    for (int f = 0; f < 256; ++f) s += bo[f]*Wg2[2*f + tid];
    beff[tid] = s;
  }
  __syncthreads();
  {
    const int j = tid;
    for (int n = 0; n < 16; ++n){
      float v = 0.f;
      if (n < 8){
        int h = n >> 1, c = n & 1;
        const float* wr = Win + (size_t)j*768 + 512 + h*64;
        const float* we = weff_s + (h*64)*2 + c;
        for (int d = 0; d < 64; ++d) v += wr[d]*we[2*d];
      }
      _Float16 hi = (_Float16)v;
      wveff[n*256 + j] = hi;
      wveff[16*256 + n*256 + j] = (_Float16)(v - (float)hi);
    }
  }
}

// -------------------------------------------- K1 fused: branch2 + gate roles
__global__ __launch_bounds__(512) void k1_all(
    const float* __restrict__ ent, const float* __restrict__ om, const float* __restrict__ em,
    const _Float16* __restrict__ W1a, const float* __restrict__ b1a,
    const _Float16* __restrict__ WINa,
    const _Float16* __restrict__ WOUTa, const float* __restrict__ boa,
    float* __restrict__ x2outa,
    const _Float16* __restrict__ W1b, const float* __restrict__ b1b,
    const _Float16* __restrict__ WINb,
    const _Float16* __restrict__ WOUTb, const float* __restrict__ bob,
    float* __restrict__ x2outb,
    const _Float16* __restrict__ W1g, const float* __restrict__ b1g,
    const _Float16* __restrict__ WINg,
    const _Float16* __restrict__ WVEFF,
    const float* __restrict__ beff, const float* __restrict__ gb2,
    float* __restrict__ og, float* __restrict__ gate)
{
  const int tid = threadIdx.x;
  const int w = tid >> 6, lg = (tid >> 4) & 3, li = tid & 15;
  extern __shared__ char smem[];

  if (blockIdx.x < 2048){
    // ============================ branch2 role ============================
    const int br = blockIdx.x >> 10;
    const int p  = blockIdx.x & 1023;
    const int bb2[2] = { 2*p, 2*p + 1 };
    const _Float16* W1   = br ? W1b   : W1a;
    const float*    b1   = br ? b1b   : b1a;
    const _Float16* WIN  = br ? WINb  : WINa;
    const _Float16* WOUT = br ? WOUTb : WOUTa;
    const float*    bo   = br ? bob   : boa;
    float*          x2out= br ? x2outb: x2outa;

    const int wi = w & 3, ih = w >> 2;
    const int l = tid & 63;              // lane within wave
    const int r32 = l & 31, kh = (l >> 5)*8;

    // LDS layout (bytes): x1 0..67584, Ks 67584, Vs 86016, Qful 104448,
    // lgs 121344, Ps 130560, outp(f16) 135168..152064
    _Float16* x1   = (_Float16*)smem;
    _Float16* Ks   = (_Float16*)(smem + 67584);
    _Float16* Vs   = (_Float16*)(smem + 86016);
    _Float16* Qful = (_Float16*)(smem + 104448);
    float*    lgs  = (float*)(smem + 121344);
    _Float16* Ps   = (_Float16*)(smem + 130560);
    _Float16* outp = (_Float16*)(smem + 135168);

    { // phase 1: x1 = relu(ent @ W1 + b1) via 32x32x16
      const int b = bb2[ih];
      _Float16* x1p = x1 + ih*16896;
      const int mt = wi & 1, ntb = (wi >> 1)*4;
      f32x16 acc0 = 0.f, acc1 = 0.f, acc2 = 0.f, acc3 = 0.f;
#pragma unroll
      for (int kk = 0; kk < 6; ++kk){
        AB<0> a = ldF<0>(ent + ((size_t)b*64 + mt*32 + r32)*96 + kk*16 + kh);
        f16x8 B0 = *(const f16x8*)(W1 + (size_t)((ntb + 0)*32 + r32)*96 + kk*16 + kh);
        f16x8 B1 = *(const f16x8*)(W1 + (size_t)((ntb + 1)*32 + r32)*96 + kk*16 + kh);
        f16x8 B2 = *(const f16x8*)(W1 + (size_t)((ntb + 2)*32 + r32)*96 + kk*16 + kh);
        f16x8 B3 = *(const f16x8*)(W1 + (size_t)((ntb + 3)*32 + r32)*96 + kk*16 + kh);
        acc0 = mfma32(a.hi, B0, acc0);
        acc1 = mfma32(a.hi, B1, acc1);
        acc2 = mfma32(a.hi, B2, acc2);
        acc3 = mfma32(a.hi, B3, acc3);
      }
#pragma unroll
      for (int s = 0; s < 4; ++s){
        const f32x16& ac = (s == 0) ? acc0 : (s == 1) ? acc1 : (s == 2) ? acc2 : acc3;
        int col = (ntb + s)*32 + r32;
        float bias = b1[col];
#pragma unroll
        for (int reg = 0; reg < 16; ++reg){
          int row = (reg & 3) + 8*(reg >> 2) + 4*(l >> 5);
          x1p[(mt*32 + row)*264 + col] = (_Float16)fmaxf(ac[reg] + bias, 0.f);
        }
      }
    }
    __syncthreads();

    { // Qfull = x1[rows 0..15, both items stacked M=32] @ Wq; wave -> n-tile w
      f32x16 acc = 0.f;
      const int itq = r32 >> 4, qr = r32 & 15;
      for (int kk = 0; kk < 16; ++kk){
        f16x8 A = *(const f16x8*)(x1 + itq*16896 + qr*264 + kk*16 + kh);
        f16x8 B = *(const f16x8*)(WIN + (size_t)(w*32 + r32)*256 + kk*16 + kh);
        acc = mfma32(A, B, acc);
      }
#pragma unroll
      for (int reg = 0; reg < 16; ++reg){
        int row = (reg & 3) + 8*(reg >> 2) + 4*(l >> 5);
        Qful[(row >> 4)*4224 + (row & 15)*264 + w*32 + r32] = (_Float16)acc[reg];
      }
    }
    __syncthreads();

    for (int h = 0; h < 4; ++h){
      // K (waves 0-3) / V (waves 4-7) via 32x32x16, both items per wave
      if (w < 4){
        const int kt = w >> 1, dt = w & 1;
        f32x16 acc0 = 0.f, acc1 = 0.f;
        for (int kk = 0; kk < 16; ++kk){
          int ao = (kt*32 + r32)*264 + kk*16 + kh;
          f16x8 A0 = *(const f16x8*)(x1 + ao);
          f16x8 A1 = *(const f16x8*)(x1 + 16896 + ao);
          f16x8 B = *(const f16x8*)(WIN + (size_t)(256 + 64*h + dt*32 + r32)*256 + kk*16 + kh);
          acc0 = mfma32(A0, B, acc0);
          acc1 = mfma32(A1, B, acc1);
        }
#pragma unroll
        for (int reg = 0; reg < 16; ++reg){
          int row = (reg & 3) + 8*(reg >> 2) + 4*(l >> 5);
          Ks[(kt*32 + row)*72 + dt*32 + r32]        = (_Float16)acc0[reg];
          Ks[4608 + (kt*32 + row)*72 + dt*32 + r32] = (_Float16)acc1[reg];
        }
      } else {
        const int wv = w - 4;
        const int kt = wv >> 1, dt = wv & 1;
        f32x16 acc0 = 0.f, acc1 = 0.f;
        for (int kk = 0; kk < 16; ++kk){
          int ao = (kt*32 + r32)*264 + kk*16 + kh;
          f16x8 A0 = *(const f16x8*)(x1 + ao);
          f16x8 A1 = *(const f16x8*)(x1 + 16896 + ao);
          f16x8 B = *(const f16x8*)(WIN + (size_t)(512 + 64*h + dt*32 + r32)*256 + kk*16 + kh);
          acc0 = mfma32(A0, B, acc0);
          acc1 = mfma32(A1, B, acc1);
        }
#pragma unroll
        for (int rr = 0; rr < 4; ++rr){
          f16x4 p0, p1;
#pragma unroll
          for (int q4 = 0; q4 < 4; ++q4){
            p0[q4] = (_Float16)acc0[rr*4 + q4];
            p1[q4] = (_Float16)acc1[rr*4 + q4];
          }
          int key = kt*32 + rr*8 + 4*(l >> 5);
          *(f16x4*)(Vs + (dt*32 + r32)*72 + key)        = p0;
          *(f16x4*)(Vs + 4608 + (dt*32 + r32)*72 + key) = p1;
        }
      }
      __syncthreads();
      { // logits: A from Qful
        const int b = bb2[ih];
        f32x4 acc = 0.f;
#pragma unroll
        for (int kk = 0; kk < 2; ++kk){
          f16x8 A = *(const f16x8*)(Qful + ih*4224 + li*264 + 64*h + kk*32 + lg*8);
          f16x8 B = *(const f16x8*)(Ks + ih*4608 + (16*wi + li)*72 + kk*32 + lg*8);
          acc = mfma16(A, B, acc);
        }
#pragma unroll
        for (int j = 0; j < 4; ++j){
          int q = 4*lg + j, key = 16*wi + li;
          float v = acc[j] * 0.125f;
          float m = om[((size_t)b*64 + q)*64 + key];
          if (m > 0.f) v = -1e9f;
          lgs[ih*1152 + q*72 + key] = v;
        }
      }
      __syncthreads();
      { // softmax
        const int it = tid >> 8, q = (tid >> 4) & 15, i16 = tid & 15;
        const int b = bb2[it];
        float pv[4], mx = -3e38f;
#pragma unroll
        for (int u = 0; u < 4; ++u){ pv[u] = lgs[it*1152 + q*72 + i16 + 16*u]; mx = fmaxf(mx, pv[u]); }
#pragma unroll
        for (int d = 1; d < 16; d <<= 1) mx = fmaxf(mx, __shfl_xor(mx, d, 16));
        float s = 0.f;
#pragma unroll
        for (int u = 0; u < 4; ++u){ pv[u] = expf(pv[u] - mx); s += pv[u]; }
#pragma unroll
        for (int d = 1; d < 16; d <<= 1) s += __shfl_xor(s, d, 16);
#pragma unroll
        for (int u = 0; u < 4; ++u){
          int key = i16 + 16*u;
          float m = om[((size_t)b*64 + q)*64 + key];
          Ps[it*1152 + q*72 + key] = (_Float16)((pv[u]/s)*(1.f - m));
        }
      }
      __syncthreads();
      { // out_h = P @ V_h; outp stored f16
        f32x4 acc = 0.f;
#pragma unroll
        for (int kk = 0; kk < 2; ++kk){
          f16x8 A = *(const f16x8*)(Ps + ih*1152 + li*72 + kk*32 + lg*8);
          f16x8 B = *(const f16x8*)(Vs + ih*4608 + (16*wi + li)*72 + kk*32 + lg*8);
          acc = mfma16(A, B, acc);
        }
#pragma unroll
        for (int j = 0; j < 4; ++j)
          outp[ih*4224 + (4*lg + j)*264 + 64*h + 16*wi + li] = (_Float16)acc[j];
      }
      __syncthreads();
    }

    { // out-proj via 32x32, stacked M=32 (both items); wave -> n-tile w
      f32x16 acc = 0.f;
      const int ito = r32 >> 4, qr = r32 & 15;
      for (int kk = 0; kk < 16; ++kk){
        f16x8 A = *(const f16x8*)(outp + ito*4224 + qr*264 + kk*16 + kh);
        f16x8 B = *(const f16x8*)(WOUT + (size_t)(w*32 + r32)*256 + kk*16 + kh);
        acc = mfma32(A, B, acc);
      }
      int col = w*32 + r32;
      float bias = bo[col];
#pragma unroll
      for (int reg = 0; reg < 16; ++reg){
        int row = (reg & 3) + 8*(reg >> 2) + 4*(l >> 5);
        int it2 = row >> 4, q2 = row & 15;
        const int b = bb2[it2];
        float v = (acc[reg] + bias) * (1.f - em[(size_t)b*64 + q2]);
        x2out[((size_t)b*16 + q2)*256 + col] = v;
      }
    }
    return;
  }

  // ============================== gate role ==============================
  {
    constexpr int W1SZ = 96*256, WINSZ = 256*768, WVSZ = 16*256;
    const int b = blockIdx.x - 2048;
    const int l = tid & 63;
    const int r32 = l & 31, kh = (l >> 5)*8;

    char* sp = smem;
    _Float16* x1h = (_Float16*)sp; sp += 64*264*2;
    _Float16* x1l = (_Float16*)sp; sp += 64*264*2;
    _Float16* Kh  = (_Float16*)sp; sp += 64*72*2;
    _Float16* Kl  = (_Float16*)sp; sp += 64*72*2;
    _Float16* Qh  = (_Float16*)sp; sp += 16*264*2;
    _Float16* Ql  = (_Float16*)sp; sp += 16*264*2;
    float*    lgs = (float*)sp;    sp += 16*72*4;
    float*    Ps  = (float*)sp;    sp += 16*66*4;
    float*    v2s = (float*)sp;    sp += 64*18*4;
    float*  ogacc = (float*)sp;    sp += 32*4;
    float*  Kpart = (float*)sp;    sp += 8192*4;

    { // phase 1: x1 = relu(ent @ W1g + b1g), 32x32 split-2
      const int mt = w & 1, ntb = (w >> 1)*2;
      f32x16 acc0 = 0.f, acc1 = 0.f;
#pragma unroll
      for (int kk = 0; kk < 6; ++kk){
        AB<1> a = ldF<1>(ent + ((size_t)b*64 + mt*32 + r32)*96 + kk*16 + kh);
#pragma unroll
        for (int s = 0; s < 2; ++s){
          const _Float16* bp = W1g + (size_t)((ntb + s)*32 + r32)*96 + kk*16 + kh;
          f16x8 Bh = *(const f16x8*)bp;
          f16x8 Bl = *(const f16x8*)(bp + W1SZ);
          f32x16& ac = s ? acc1 : acc0;
          ac = mfma32(a.lo, Bh, ac);
          ac = mfma32(a.hi, Bl, ac);
          ac = mfma32(a.hi, Bh, ac);
        }
      }
#pragma unroll
      for (int s = 0; s < 2; ++s){
        const f32x16& ac = s ? acc1 : acc0;
        int col = (ntb + s)*32 + r32;
        float bias = b1g[col];
#pragma unroll
        for (int reg = 0; reg < 16; ++reg){
          int row = (reg & 3) + 8*(reg >> 2) + 4*(l >> 5);
          stL<1>(x1h, x1l, (mt*32 + row)*264 + col, fmaxf(ac[reg] + bias, 0.f));
        }
      }
    }
    if (tid < 32) ogacc[tid] = 0.f;
    __syncthreads();

    { // phase 2: Qfull (16x16 split-2), v2
#pragma unroll
      for (int s = 0; s < 2; ++s){
        int nt = w + s*8;
        f32x4 acc = 0.f;
        for (int kk = 0; kk < 8; ++kk){
          int ao = li*264 + kk*32 + lg*8;
          AB<1> a = ldL<1>(x1h + ao, x1l + ao);
          AB<1> bb = ldW<1>(WINg + (size_t)(nt*16 + li)*256 + kk*32 + lg*8, WINSZ);
          a.mf(bb, acc);
        }
#pragma unroll
        for (int j = 0; j < 4; ++j)
          stL<1>(Qh, Ql, (4*lg + j)*264 + nt*16 + li, acc[j]);
      }
      if (w < 4){
        f32x4 acc = 0.f;
        for (int kk = 0; kk < 8; ++kk){
          int ao = (w*16 + li)*264 + kk*32 + lg*8;
          AB<1> a = ldL<1>(x1h + ao, x1l + ao);
          AB<1> bb = ldW<1>(WVEFF + (size_t)li*256 + kk*32 + lg*8, WVSZ);
          a.mf(bb, acc);
        }
#pragma unroll
        for (int j = 0; j < 4; ++j)
          v2s[(w*16 + 4*lg + j)*18 + li] = acc[j];
      }
    }
    __syncthreads();

    for (int h = 0; h < 4; ++h){
      { // K_h partials: 32x32 split-2, tiles x k-halves across 8 waves
        const int t = w & 3, kt = t >> 1, dt = t & 1, khalf = w >> 2;
        f32x16 acc = 0.f;
#pragma unroll
        for (int k8 = 0; k8 < 8; ++k8){
          int ko = (khalf*8 + k8)*16 + kh;
          int ao = (kt*32 + r32)*264 + ko;
          f16x8 ah = *(const f16x8*)(x1h + ao);
          f16x8 al = *(const f16x8*)(x1l + ao);
          const _Float16* bp = WINg + (size_t)(256 + h*64 + dt*32 + r32)*256 + ko;
          f16x8 Bh = *(const f16x8*)bp;
          f16x8 Bl = *(const f16x8*)(bp + WINSZ);
          acc = mfma32(al, Bh, acc);
          acc = mfma32(ah, Bl, acc);
          acc = mfma32(ah, Bh, acc);
        }
#pragma unroll
        for (int reg = 0; reg < 16; ++reg){
          int row = (reg & 3) + 8*(reg >> 2) + 4*(l >> 5);
          Kpart[((khalf*4 + t)*32 + row)*32 + r32] = acc[reg];
        }
      }
      __syncthreads();
      { // reduce k-halves -> Kh/Kl
        for (int e = tid; e < 4096; e += 512){
          float s2 = Kpart[e] + Kpart[4096 + e];
          int t2 = e >> 10, idx = e & 1023, row = idx >> 5, col = idx & 31;
          stL<1>(Kh, Kl, ((t2 >> 1)*32 + row)*72 + (t2 & 1)*32 + col, s2);
        }
      }
      __syncthreads();
      if (w < 4){ // logits
        f32x4 acc = 0.f;
#pragma unroll
        for (int kk = 0; kk < 2; ++kk){
          int ao = li*264 + h*64 + kk*32 + lg*8;
          AB<1> a = ldL<1>(Qh + ao, Ql + ao);
          int bo_ = (16*w + li)*72 + kk*32 + lg*8;
          AB<1> bb = ldL<1>(Kh + bo_, Kl + bo_);
          a.mf(bb, acc);
        }
#pragma unroll
        for (int j = 0; j < 4; ++j){
          int q = 4*lg + j, key = 16*w + li;
          float v = acc[j] * 0.125f;
          float m = om[((size_t)b*64 + q)*64 + key];
          if (m > 0.f) v = -1e9f;
          lgs[q*72 + key] = v;
        }
      }
      __syncthreads();
      if (tid < 256){ // softmax
        int q = tid >> 4, i16 = tid & 15;
        float pv[4], mx = -3e38f;
#pragma unroll
        for (int u = 0; u < 4; ++u){ pv[u] = lgs[q*72 + i16 + 16*u]; mx = fmaxf(mx, pv[u]); }
#pragma unroll
        for (int d = 1; d < 16; d <<= 1) mx = fmaxf(mx, __shfl_xor(mx, d, 16));
        float s = 0.f;
#pragma unroll
        for (int u = 0; u < 4; ++u){ pv[u] = expf(pv[u] - mx); s += pv[u]; }
#pragma unroll
        for (int d = 1; d < 16; d <<= 1) s += __shfl_xor(s, d, 16);
#pragma unroll
        for (int u = 0; u < 4; ++u){
          int key = i16 + 16*u;
          float m = om[((size_t)b*64 + q)*64 + key];
          Ps[q*66 + key] = (pv[u]/s)*(1.f - m);
        }
      }
      __syncthreads();
      if (tid < 256){ // og += P_h . v2_h
        int q = tid >> 4, l16 = tid & 15;
        float a0 = 0.f, a1 = 0.f;
#pragma unroll
        for (int u = 0; u < 4; ++u){
          int k = l16 + 16*u;
          float p2 = Ps[q*66 + k];
          a0 += p2 * v2s[k*18 + h*2];
          a1 += p2 * v2s[k*18 + h*2 + 1];
        }
#pragma unroll
        for (int d = 1; d < 16; d <<= 1){ a0 += __shfl_xor(a0, d, 16); a1 += __shfl_xor(a1, d, 16); }
        if (l16 == 0){ ogacc[q*2] += a0; ogacc[q*2 + 1] += a1; }
      }
      __syncthreads();
    }
    if (tid < 16){
      int q = tid;
      float am = em[(size_t)b*64 + q];
      float g0 = (1.f - am)*(ogacc[2*q]     + beff[0]) + gb2[0];
      float g1 = (1.f - am)*(ogacc[2*q + 1] + beff[1]) + gb2[1];
      og[((size_t)b*16 + q)*2]     = g0;
      og[((size_t)b*16 + q)*2 + 1] = g1;
      gate[(size_t)b*16 + q] = (g1 > g0) ? 1.f : 0.f;
    }
  }
}

// ------------------- K2: gate, global attention, fc2, gi — 2 items/block
__global__ __launch_bounds__(256) void k2_global(
    const float* __restrict__ em,
    const float* __restrict__ x2, const float* __restrict__ x2m,
    const float* __restrict__ gate,
    const _Float16* __restrict__ GMIN, const _Float16* __restrict__ GMOUT, const float* __restrict__ gob,
    const _Float16* __restrict__ FC2T, const float* __restrict__ fc2b,
    const _Float16* __restrict__ GIHT, const float* __restrict__ gib,
    float* __restrict__ gi)
{
  const int p = blockIdx.x;
  const int tid = threadIdx.x;
  const int w = tid >> 6, lg = (tid >> 4) & 3, li = tid & 15;

  extern __shared__ char smem[];
  float*    gate_s = (float*)smem;
  _Float16* gm_s   = (_Float16*)(smem + 128);
  _Float16* Q2     = (_Float16*)(smem + 17024);
  _Float16* K2s    = (_Float16*)(smem + 21632);
  _Float16* Vt2    = (_Float16*)(smem + 26240);
  float*    lg2    = (float*)(smem + 36480);
  _Float16* P2     = (_Float16*)(smem + 39552);
  _Float16* outp   = (_Float16*)(smem + 42112);
  _Float16* cat_s  = (_Float16*)(smem + 59008);
  _Float16* x3_s   = (_Float16*)(smem + 92288);

  if (tid < 32){
    int it = tid >> 4, q = tid & 15;
    gate_s[it*16 + q] = gate[(size_t)(2*p + it)*16 + q];
  }
  __syncthreads();
#pragma unroll
  for (int it = 0; it < 2; ++it){
    const int b = 2*p + it;
    for (int idx = tid; idx < 4096; idx += 256){
      int q = idx >> 8, d = idx & 255;
      gm_s[it*4224 + q*264 + d]  = (_Float16)(x2m[((size_t)b*16 + q)*256 + d] * gate_s[it*16 + q]);
      cat_s[it*8320 + q*520 + d] = (_Float16)(x2[((size_t)b*16 + q)*256 + d]);
    }
  }
  for (int idx = tid; idx < 2*64*40; idx += 256) Vt2[idx] = (_Float16)0.f;
  for (int idx = tid; idx < 2*16*40; idx += 256) P2[idx] = (_Float16)0.f;
  __syncthreads();
  for (int h = 0; h < 4; ++h){
    {
      f32x4 aq0 = 0.f, aq1 = 0.f, ak0 = 0.f, ak1 = 0.f, av0 = 0.f, av1 = 0.f;
      for (int kk = 0; kk < 8; ++kk){
        f16x8 A0 = *(const f16x8*)(gm_s + li*264 + kk*32 + lg*8);
        f16x8 A1 = *(const f16x8*)(gm_s + 4224 + li*264 + kk*32 + lg*8);
        f16x8 Bq = *(const f16x8*)(GMIN + (size_t)(      64*h + 16*w + li)*256 + kk*32 + lg*8);
        f16x8 Bk = *(const f16x8*)(GMIN + (size_t)(256 + 64*h + 16*w + li)*256 + kk*32 + lg*8);
        f16x8 Bv = *(const f16x8*)(GMIN + (size_t)(512 + 64*h + 16*w + li)*256 + kk*32 + lg*8);
        aq0 = mfma16(A0, Bq, aq0); aq1 = mfma16(A1, Bq, aq1);
        ak0 = mfma16(A0, Bk, ak0); ak1 = mfma16(A1, Bk, ak1);
        av0 = mfma16(A0, Bv, av0); av1 = mfma16(A1, Bv, av1);
      }
#pragma unroll
      for (int j = 0; j < 4; ++j){
        int rw = 4*lg + j, dim = 16*w + li;
        Q2[rw*72 + dim]         = (_Float16)aq0[j];
        Q2[1152 + rw*72 + dim]  = (_Float16)aq1[j];
        K2s[rw*72 + dim]        = (_Float16)ak0[j];
        K2s[1152 + rw*72 + dim] = (_Float16)ak1[j];
        Vt2[dim*40 + rw]        = (_Float16)av0[j];
        Vt2[2560 + dim*40 + rw] = (_Float16)av1[j];
      }
    }
    __syncthreads();
    if (w < 2){
      const int it = w, b = 2*p + it;
      f32x4 acc = 0.f;
#pragma unroll
      for (int kk = 0; kk < 2; ++kk){
        f16x8 A = *(const f16x8*)(Q2  + it*1152 + li*72 + kk*32 + lg*8);
        f16x8 B = *(const f16x8*)(K2s + it*1152 + li*72 + kk*32 + lg*8);
        acc = mfma16(A, B, acc);
      }
      float amk = em[(size_t)b*64 + li];
#pragma unroll
      for (int j = 0; j < 4; ++j){
        int q = 4*lg + j;
        float amq = em[(size_t)b*64 + q];
        float m = 1.f - (1.f - amq)*(1.f - amk);
        float v = acc[j]*0.125f;
        if (m > 0.f) v = -1e9f;
        lg2[it*384 + q*24 + li] = v;
      }
    }
    __syncthreads();
    {
      int q = tid >> 4, key = tid & 15;
#pragma unroll
      for (int it = 0; it < 2; ++it){
        const int b = 2*p + it;
        float v = lg2[it*384 + q*24 + key];
        float mx = v;
#pragma unroll
        for (int d = 1; d < 16; d <<= 1) mx = fmaxf(mx, __shfl_xor(mx, d, 16));
        float pe = expf(v - mx);
        float s = pe;
#pragma unroll
        for (int d = 1; d < 16; d <<= 1) s += __shfl_xor(s, d, 16);
        float amq = em[(size_t)b*64 + q], amk = em[(size_t)b*64 + key];
        float m = 1.f - (1.f - amq)*(1.f - amk);
        P2[it*640 + q*40 + key] = (_Float16)((pe/s)*(1.f - m));
      }
    }
    __syncthreads();
    {
#pragma unroll
      for (int it = 0; it < 2; ++it){
        f32x4 acc = 0.f;
        f16x8 A = *(const f16x8*)(P2 + it*640 + li*40 + lg*8);
        f16x8 B = *(const f16x8*)(Vt2 + it*2560 + (16*w + li)*40 + lg*8);
        acc = mfma16(A, B, acc);
#pragma unroll
        for (int j = 0; j < 4; ++j)
          outp[it*4224 + (4*lg + j)*264 + 64*h + 16*w + li] = (_Float16)acc[j];
      }
    }
    __syncthreads();
  }
  {
#pragma unroll
    for (int c = 0; c < 4; ++c){
      int col = 64*w + 16*c + li;
      f32x4 a0 = 0.f, a1 = 0.f;
      for (int kk = 0; kk < 8; ++kk){
        f16x8 B  = *(const f16x8*)(GMOUT + (size_t)col*256 + kk*32 + lg*8);
        f16x8 A0 = *(const f16x8*)(outp + li*264 + kk*32 + lg*8);
        f16x8 A1 = *(const f16x8*)(outp + 4224 + li*264 + kk*32 + lg*8);
        a0 = mfma16(A0, B, a0);
        a1 = mfma16(A1, B, a1);
      }
      float bias = gob[col];
#pragma unroll
      for (int j = 0; j < 4; ++j){
        int q = 4*lg + j;
        float m0 = 1.f - em[(size_t)(2*p)*64 + q];
        float m1 = 1.f - em[(size_t)(2*p + 1)*64 + q];
        cat_s[q*520 + 256 + col]        = (_Float16)((a0[j] + bias)*m0);
        cat_s[8320 + q*520 + 256 + col] = (_Float16)((a1[j] + bias)*m1);
      }
    }
  }
  __syncthreads();
  {
#pragma unroll
    for (int c = 0; c < 4; ++c){
      int col = 64*w + 16*c + li;
      f32x4 a0 = 0.f, a1 = 0.f;
      for (int kk = 0; kk < 16; ++kk){
        f16x8 B  = *(const f16x8*)(FC2T + (size_t)col*512 + kk*32 + lg*8);
        f16x8 A0 = *(const f16x8*)(cat_s + li*520 + kk*32 + lg*8);
        f16x8 A1 = *(const f16x8*)(cat_s + 8320 + li*520 + kk*32 + lg*8);
        a0 = mfma16(A0, B, a0);
        a1 = mfma16(A1, B, a1);
      }
      float bias = fc2b[col];
#pragma unroll
      for (int j = 0; j < 4; ++j){
        x3_s[(4*lg + j)*264 + col]        = (_Float16)fmaxf(a0[j] + bias, 0.f);
        x3_s[4224 + (4*lg + j)*264 + col] = (_Float16)fmaxf(a1[j] + bias, 0.f);
      }
    }
  }
  __syncthreads();
  {
    const int r0 = ((2*p) >> 6)*16, t0 = (2*p) & 63;
#pragma unroll
    for (int cc = 0; cc < 12; ++cc){
      int col = (w*12 + cc)*16 + li;
      f32x4 a0 = 0.f, a1 = 0.f;
      for (int kk = 0; kk < 8; ++kk){
        f16x8 B  = *(const f16x8*)(GIHT + (size_t)col*256 + kk*32 + lg*8);
        f16x8 A0 = *(const f16x8*)(x3_s + li*264 + kk*32 + lg*8);
        f16x8 A1 = *(const f16x8*)(x3_s + 4224 + li*264 + kk*32 + lg*8);
        a0 = mfma16(A0, B, a0);
        a1 = mfma16(A1, B, a1);
      }
      float bias = gib[col];
#pragma unroll
      for (int j = 0; j < 4; ++j){
        int q = 4*lg + j;
        gi[((size_t)((r0 + q)*64 + t0))*768 + col]     = a0[j] + bias;
        gi[((size_t)((r0 + q)*64 + t0 + 1))*768 + col] = a1[j] + bias;
      }
    }
  }
}

// ------------------------------------------------------------------ K3: GRU
__global__ __launch_bounds__(256) void k3_gru(
    const _Float16* __restrict__ WHH, const float* __restrict__ bhh,
    const float* __restrict__ gi, const float* __restrict__ h0,
    float* __restrict__ hs)
{
  const int rb = blockIdx.x;
  const int row0 = rb * 16;
  const int tid = threadIdx.x;
  const int w = tid >> 6, lg = (tid >> 4) & 3, li = tid & 15;

  extern __shared__ char smem3[];
  _Float16* hf16 = (_Float16*)smem3;
  float* hf32 = (float*)(smem3 + 8448);
  float* gh   = (float*)(smem3 + 8448 + 16640);
  float* bhs  = (float*)(smem3 + 8448 + 16640 + 49664);

  for (int idx = tid; idx < 768; idx += 256) bhs[idx] = bhh[idx];
  for (int idx = tid; idx < 4096; idx += 256){
    int r = idx >> 8, d = idx & 255;
    float v = h0[(size_t)(row0 + r)*256 + d];
    hf32[r*260 + d] = v;
    hf16[r*264 + d] = (_Float16)v;
  }
  __syncthreads();

  const int er = tid >> 4;
  const int d0 = (tid & 15) * 16;

  for (int t = 0; t < 64; ++t){
    const float* gp = gi + ((size_t)(row0 + er)*64 + t)*768 + d0;
    f32x4 gr[4], gz[4], gn[4];
#pragma unroll
    for (int v = 0; v < 4; ++v){
      gr[v] = *(const f32x4*)(gp + v*4);
      gz[v] = *(const f32x4*)(gp + 256 + v*4);
      gn[v] = *(const f32x4*)(gp + 512 + v*4);
    }
    f16x8 a[8];
#pragma unroll
    for (int kk = 0; kk < 8; ++kk)
      a[kk] = *(const f16x8*)(hf16 + li*264 + kk*32 + lg*8);
    f32x4 acc[12];
#pragma unroll
    for (int c = 0; c < 12; ++c) acc[c] = 0.f;
#pragma unroll
    for (int c = 0; c < 12; ++c){
      const _Float16* bp = WHH + (size_t)(w*192 + c*16 + li)*256 + lg*8;
#pragma unroll
      for (int kk = 0; kk < 8; ++kk)
        acc[c] = mfma16(a[kk], *(const f16x8*)(bp + kk*32), acc[c]);
    }
#pragma unroll
    for (int c = 0; c < 12; ++c){
      int col = w*192 + c*16 + li;
#pragma unroll
      for (int j = 0; j < 4; ++j)
        gh[(4*lg + j)*776 + col] = acc[c][j];
    }
    __syncthreads();
    {
      float* hp32 = hf32 + er*260 + d0;
      float* hsp  = hs + ((size_t)(rb*64 + t)*16 + er)*256 + d0;
      f16x8 hv8[2];
#pragma unroll
      for (int v = 0; v < 4; ++v){
        f32x4 xr = *(const f32x4*)(gh + er*776 +       d0 + v*4);
        f32x4 xz = *(const f32x4*)(gh + er*776 + 256 + d0 + v*4);
        f32x4 xn = *(const f32x4*)(gh + er*776 + 512 + d0 + v*4);
        f32x4 hold = *(const f32x4*)(hp32 + v*4);
        f32x4 hout;
#pragma unroll
        for (int e = 0; e < 4; ++e){
          int d = d0 + v*4 + e;
          float rr_ = 1.f/(1.f + __expf(-(gr[v][e] + xr[e] + bhs[d])));
          float zz  = 1.f/(1.f + __expf(-(gz[v][e] + xz[e] + bhs[256 + d])));
          float pre = gn[v][e] + rr_*(xn[e] + bhs[512 + d]);
          float nn  = 1.f - 2.f/(1.f + __expf(2.f*pre));
          float hv = (1.f - zz)*nn + zz*hold[e];
          hout[e] = hv;
          int sl = v*4 + e;
          hv8[sl >> 3][sl & 7] = (_Float16)hv;
        }
        *(f32x4*)(hp32 + v*4) = hout;
        *(f32x4*)(hsp + v*4)  = hout;
      }
      *(f16x8*)(hf16 + er*264 + d0)     = hv8[0];
      *(f16x8*)(hf16 + er*264 + d0 + 8) = hv8[1];
    }
    __syncthreads();
  }
}

// ------------------------------------------------------------------ K4: q out
__global__ __launch_bounds__(256) void k4_q(
    const _Float16* __restrict__ FC3T, const float* __restrict__ fc3b,
    const float* __restrict__ em, const float* __restrict__ hs, float* __restrict__ qo)
{
  const int tid = threadIdx.x;
  const int w = tid >> 6, lg = (tid >> 4) & 3, li = tid & 15;
  const int rb = blockIdx.x*64 + 16*w;
  f32x4 acc[2];
#pragma unroll
  for (int c = 0; c < 2; ++c) acc[c] = 0.f;
  for (int kk = 0; kk < 8; ++kk){
    const float* ap = hs + (size_t)(rb + li)*256 + kk*32 + lg*8;
    f32x4 v0 = *(const f32x4*)ap, v1 = *(const f32x4*)(ap + 4);
    f16x8 A;
#pragma unroll
    for (int e = 0; e < 4; ++e){ A[e] = (_Float16)v0[e]; A[e+4] = (_Float16)v1[e]; }
#pragma unroll
    for (int c = 0; c < 2; ++c){
      f16x8 B = *(const f16x8*)(FC3T + (size_t)(16*c + li)*256 + kk*32 + lg*8);
      acc[c] = mfma16(A, B, acc[c]);
    }
  }
#pragma unroll
  for (int c = 0; c < 2; ++c){
    int col = 16*c + li;
    float bias = fc3b[col];
#pragma unroll
    for (int j = 0; j < 4; ++j){
      int row = rb + 4*lg + j;
      float am = em[(size_t)(row >> 4)*64 + (row & 15)];
      qo[(size_t)row*32 + col] = (acc[c][j] + bias)*(1.f - am);
    }
  }
}

// --------------------------------------------------------------------- launch
extern "C" void kernel_launch(void* const* d_in, const int* in_sizes, int n_in,
                              void* d_out, int out_size, void* d_ws, size_t ws_size,
                              hipStream_t stream)
{
  constexpr size_t OFF_FC1T   = 0;
  constexpr size_t OFF_MSG1T  = 49152;
  constexpr size_t OFF_AINT   = 98304;
  constexpr size_t OFF_LINT   = 491520;
  constexpr size_t OFF_AOUTT  = 884736;
  constexpr size_t OFF_LOUTT  = 1015808;
  constexpr size_t OFF_GMINT  = 1146880;
  constexpr size_t OFF_GMOUTT = 1540096;
  constexpr size_t OFF_FC2T   = 1671168;
  constexpr size_t OFF_GIHT   = 1933312;
  constexpr size_t OFF_GHHT   = 2326528;
  constexpr size_t OFF_FC3T   = 2719744;
  constexpr size_t OFF_G1T    = 2736128;
  constexpr size_t OFF_GINT   = 2834432;
  constexpr size_t OFF_WVEFF  = 3620864;
  constexpr size_t OFF_BEFF   = 3637248;
  constexpr size_t OFF_GATE   = 3637504;
  constexpr size_t OFF_X2     = 3768576;
  constexpr size_t OFF_X2M    = 37323008;
  constexpr size_t OFF_GI     = 70877440;
  constexpr size_t NEED       = 171540736;
  if (ws_size < NEED) return;

  char* ws = (char*)d_ws;
  const float* ent = (const float*)d_in[0];
  const float* om  = (const float*)d_in[1];
  const float* em  = (const float*)d_in[2];

  WJobs jb{};
  int nj = 0;
  auto addj = [&](int src_idx, size_t off, int K, int N, int m){
    jb.src[nj] = (const float*)d_in[src_idx]; jb.off[nj] = (unsigned)off;
    jb.K[nj] = K; jb.N[nj] = N; jb.mode[nj] = m; ++nj;
  };
  addj(4,  OFF_FC1T,   96, 256, 0);
  addj(17, OFF_MSG1T,  96, 256, 0);
  addj(6,  OFF_AINT,  256, 768, 0);
  addj(19, OFF_LINT,  256, 768, 0);
  addj(7,  OFF_AOUTT, 256, 256, 0);
  addj(20, OFF_LOUTT, 256, 256, 0);
  addj(22, OFF_GMINT, 256, 768, 0);
  addj(23, OFF_GMOUTT,256, 256, 0);
  addj(9,  OFF_FC2T,  512, 256, 0);
  addj(11, OFF_GIHT,  256, 768, 0);
  addj(12, OFF_GHHT,  256, 768, 0);
  addj(15, OFF_FC3T,  256,  32, 0);
  addj(28, OFF_G1T,    96, 256, 1);
  addj(25, OFF_GINT,  256, 768, 1);
  k0_conv<<<dim3(96, nj), 256, 0, stream>>>(jb, ws);

  k0w_gate<<<1, 256, 0, stream>>>(
      (const float*)d_in[26], (const float*)d_in[30],
      (const float*)d_in[27], (const float*)d_in[25],
      (_Float16*)(ws + OFF_WVEFF), (float*)(ws + OFF_BEFF));

  constexpr int SMB = 156672, SMK2 = 109184, SM3 = 77824;
  (void)hipFuncSetAttribute(reinterpret_cast<const void*>(&k1_all),
                            hipFuncAttributeMaxDynamicSharedMemorySize, SMB);
  (void)hipFuncSetAttribute(reinterpret_cast<const void*>(&k2_global),
                            hipFuncAttributeMaxDynamicSharedMemorySize, SMK2);
  (void)hipFuncSetAttribute(reinterpret_cast<const void*>(&k3_gru),
                            hipFuncAttributeMaxDynamicSharedMemorySize, SM3);

  float* qout = (float*)d_out;
  float* hsout = qout + 1048576;
  float* gout = qout + 9437184;

  k1_all<<<4096, 512, SMB, stream>>>(ent, om, em,
      (const _Float16*)(ws + OFF_FC1T),  (const float*)d_in[5],
      (const _Float16*)(ws + OFF_AINT),
      (const _Float16*)(ws + OFF_AOUTT), (const float*)d_in[8],
      (float*)(ws + OFF_X2),
      (const _Float16*)(ws + OFF_MSG1T), (const float*)d_in[18],
      (const _Float16*)(ws + OFF_LINT),
      (const _Float16*)(ws + OFF_LOUTT), (const float*)d_in[21],
      (float*)(ws + OFF_X2M),
      (const _Float16*)(ws + OFF_G1T),   (const float*)d_in[29],
      (const _Float16*)(ws + OFF_GINT),
      (const _Float16*)(ws + OFF_WVEFF),
      (const float*)(ws + OFF_BEFF), (const float*)d_in[31],
      gout, (float*)(ws + OFF_GATE));

  k2_global<<<1024, 256, SMK2, stream>>>(em,
      (const float*)(ws + OFF_X2), (const float*)(ws + OFF_X2M),
      (const float*)(ws + OFF_GATE),
      (const _Float16*)(ws + OFF_GMINT), (const _Float16*)(ws + OFF_GMOUTT), (const float*)d_in[24],
      (const _Float16*)(ws + OFF_FC2T), (const float*)d_in[10],
      (const _Float16*)(ws + OFF_GIHT), (const float*)d_in[13],
      (float*)(ws + OFF_GI));

  k3_gru<<<32, 256, SM3, stream>>>(
      (const _Float16*)(ws + OFF_GHHT), (const float*)d_in[14],
      (const float*)(ws + OFF_GI), (const float*)d_in[3], hsout);

  k4_q<<<512, 256, 0, stream>>>(
      (const _Float16*)(ws + OFF_FC3T), (const float*)d_in[16],
      em, hsout, qout);
}

// Round 18
// 1154.282 us; speedup vs baseline: 1.3843x; 1.1369x over previous
//
#include <hip/hip_runtime.h>

// EntityAttentionRNNMsgAgent — fused MI355X implementation.
// r18 = r17 + (1) k2 tail GEMMs (out-proj/fc2/gi) stacked M=32 via 32x32
// (instruction count halves; r17-verified mapping) and (2) k3 at 512 threads
// (8 waves x 6 col-tiles; doubles latency-hiding on the w_hh L2 stream).
// k1_all / k0 / k0w / k4 byte-identical to r17 (1312.3us verified).

#define DEV __device__ __forceinline__

typedef _Float16 f16x8 __attribute__((ext_vector_type(8)));
typedef _Float16 f16x4 __attribute__((ext_vector_type(4)));
typedef float    f32x4 __attribute__((ext_vector_type(4)));
typedef float    f32x16 __attribute__((ext_vector_type(16)));

DEV f32x4 mfma16(f16x8 a, f16x8 b, f32x4 c){
  return __builtin_amdgcn_mfma_f32_16x16x32_f16(a, b, c, 0, 0, 0);
}
DEV f32x16 mfma32(f16x8 a, f16x8 b, f32x16 c){
  return __builtin_amdgcn_mfma_f32_32x32x16_f16(a, b, c, 0, 0, 0);
}

// A/B fragment pair for optional split-precision (MODE=1: value = hi + lo)
template<int MODE> struct AB {
  f16x8 hi, lo;
  DEV void mf(const AB& b, f32x4& c) const {
    if constexpr (MODE){
      c = mfma16(lo, b.hi, c);
      c = mfma16(hi, b.lo, c);
    }
    c = mfma16(hi, b.hi, c);
  }
};

template<int MODE> DEV AB<MODE> ldW(const _Float16* p, int losz){
  AB<MODE> r; r.hi = *(const f16x8*)p;
  if constexpr (MODE) r.lo = *(const f16x8*)(p + losz);
  return r;
}
template<int MODE> DEV AB<MODE> ldL(const _Float16* ph, const _Float16* pl){
  AB<MODE> r; r.hi = *(const f16x8*)ph;
  if constexpr (MODE) r.lo = *(const f16x8*)pl;
  return r;
}
template<int MODE> DEV AB<MODE> ldF(const float* p){
  AB<MODE> r;
  f32x4 v0 = *(const f32x4*)p, v1 = *(const f32x4*)(p + 4);
#pragma unroll
  for (int i = 0; i < 4; ++i){
    float a = v0[i], b = v1[i];
    _Float16 ah = (_Float16)a, bh = (_Float16)b;
    r.hi[i] = ah; r.hi[i+4] = bh;
    if constexpr (MODE){
      r.lo[i]   = (_Float16)(a - (float)ah);
      r.lo[i+4] = (_Float16)(b - (float)bh);
    }
  }
  return r;
}
template<int MODE> DEV void stL(_Float16* ph, _Float16* pl, int idx, float v){
  _Float16 h = (_Float16)v;
  ph[idx] = h;
  if constexpr (MODE) pl[idx] = (_Float16)(v - (float)h);
}

// ---------------------------------------------------------------- K0: weights
struct WJobs {
  const float* src[15];
  unsigned off[15];
  int K[15], N[15], mode[15];
};

__global__ __launch_bounds__(256) void k0_conv(WJobs jb, char* ws){
  const int job = blockIdx.y;
  const int K = jb.K[job], N = jb.N[job];
  const int total = K * N;
  _Float16* dh = (_Float16*)(ws + jb.off[job]);
  const float* src = jb.src[job];
  const int m = jb.mode[job];
  for (int idx = blockIdx.x*256 + threadIdx.x; idx < total; idx += gridDim.x*256){
    int n = idx / K, k = idx - n*K;
    float v = src[(size_t)k*N + n];
    _Float16 h = (_Float16)v;
    dh[idx] = h;
    if (m) dh[total + idx] = (_Float16)(v - (float)h);
  }
}

// ------------------------------------------------- K0w: gate-tail precompute
__global__ __launch_bounds__(256) void k0w_gate(
    const float* __restrict__ Wout, const float* __restrict__ Wg2,
    const float* __restrict__ bo,   const float* __restrict__ Win,
    _Float16* __restrict__ wveff, float* __restrict__ beff)
{
  __shared__ float weff_s[256*2];
  const int tid = threadIdx.x;
  {
    float a0 = 0.f, a1 = 0.f;
    const float* wr = Wout + (size_t)tid*256;
    for (int f = 0; f < 256; ++f){ float x = wr[f]; a0 += x*Wg2[2*f]; a1 += x*Wg2[2*f+1]; }
    weff_s[tid*2] = a0; weff_s[tid*2+1] = a1;
  }
  if (tid < 2){
    float s = 0.f;
    for (int f = 0; f < 256; ++f) s += bo[f]*Wg2[2*f + tid];
    beff[tid] = s;
  }
  __syncthreads();
  {
    const int j = tid;
    for (int n = 0; n < 16; ++n){
      float v = 0.f;
      if (n < 8){
        int h = n >> 1, c = n & 1;
        const float* wr = Win + (size_t)j*768 + 512 + h*64;
        const float* we = weff_s + (h*64)*2 + c;
        for (int d = 0; d < 64; ++d) v += wr[d]*we[2*d];
      }
      _Float16 hi = (_Float16)v;
      wveff[n*256 + j] = hi;
      wveff[16*256 + n*256 + j] = (_Float16)(v - (float)hi);
    }
  }
}

// -------------------------------------------- K1 fused: branch2 + gate roles
__global__ __launch_bounds__(512) void k1_all(
    const float* __restrict__ ent, const float* __restrict__ om, const float* __restrict__ em,
    const _Float16* __restrict__ W1a, const float* __restrict__ b1a,
    const _Float16* __restrict__ WINa,
    const _Float16* __restrict__ WOUTa, const float* __restrict__ boa,
    float* __restrict__ x2outa,
    const _Float16* __restrict__ W1b, const float* __restrict__ b1b,
    const _Float16* __restrict__ WINb,
    const _Float16* __restrict__ WOUTb, const float* __restrict__ bob,
    float* __restrict__ x2outb,
    const _Float16* __restrict__ W1g, const float* __restrict__ b1g,
    const _Float16* __restrict__ WINg,
    const _Float16* __restrict__ WVEFF,
    const float* __restrict__ beff, const float* __restrict__ gb2,
    float* __restrict__ og, float* __restrict__ gate)
{
  const int tid = threadIdx.x;
  const int w = tid >> 6, lg = (tid >> 4) & 3, li = tid & 15;
  extern __shared__ char smem[];

  if (blockIdx.x < 2048){
    // ============================ branch2 role ============================
    const int br = blockIdx.x >> 10;
    const int p  = blockIdx.x & 1023;
    const int bb2[2] = { 2*p, 2*p + 1 };
    const _Float16* W1   = br ? W1b   : W1a;
    const float*    b1   = br ? b1b   : b1a;
    const _Float16* WIN  = br ? WINb  : WINa;
    const _Float16* WOUT = br ? WOUTb : WOUTa;
    const float*    bo   = br ? bob   : boa;
    float*          x2out= br ? x2outb: x2outa;

    const int wi = w & 3, ih = w >> 2;
    const int l = tid & 63;
    const int r32 = l & 31, kh = (l >> 5)*8;

    _Float16* x1   = (_Float16*)smem;
    _Float16* Ks   = (_Float16*)(smem + 67584);
    _Float16* Vs   = (_Float16*)(smem + 86016);
    _Float16* Qful = (_Float16*)(smem + 104448);
    float*    lgs  = (float*)(smem + 121344);
    _Float16* Ps   = (_Float16*)(smem + 130560);
    _Float16* outp = (_Float16*)(smem + 135168);

    { // phase 1: x1 = relu(ent @ W1 + b1) via 32x32x16
      const int b = bb2[ih];
      _Float16* x1p = x1 + ih*16896;
      const int mt = wi & 1, ntb = (wi >> 1)*4;
      f32x16 acc0 = 0.f, acc1 = 0.f, acc2 = 0.f, acc3 = 0.f;
#pragma unroll
      for (int kk = 0; kk < 6; ++kk){
        AB<0> a = ldF<0>(ent + ((size_t)b*64 + mt*32 + r32)*96 + kk*16 + kh);
        f16x8 B0 = *(const f16x8*)(W1 + (size_t)((ntb + 0)*32 + r32)*96 + kk*16 + kh);
        f16x8 B1 = *(const f16x8*)(W1 + (size_t)((ntb + 1)*32 + r32)*96 + kk*16 + kh);
        f16x8 B2 = *(const f16x8*)(W1 + (size_t)((ntb + 2)*32 + r32)*96 + kk*16 + kh);
        f16x8 B3 = *(const f16x8*)(W1 + (size_t)((ntb + 3)*32 + r32)*96 + kk*16 + kh);
        acc0 = mfma32(a.hi, B0, acc0);
        acc1 = mfma32(a.hi, B1, acc1);
        acc2 = mfma32(a.hi, B2, acc2);
        acc3 = mfma32(a.hi, B3, acc3);
      }
#pragma unroll
      for (int s = 0; s < 4; ++s){
        const f32x16& ac = (s == 0) ? acc0 : (s == 1) ? acc1 : (s == 2) ? acc2 : acc3;
        int col = (ntb + s)*32 + r32;
        float bias = b1[col];
#pragma unroll
        for (int reg = 0; reg < 16; ++reg){
          int row = (reg & 3) + 8*(reg >> 2) + 4*(l >> 5);
          x1p[(mt*32 + row)*264 + col] = (_Float16)fmaxf(ac[reg] + bias, 0.f);
        }
      }
    }
    __syncthreads();

    { // Qfull = x1[rows 0..15, both items stacked M=32] @ Wq; wave -> n-tile w
      f32x16 acc = 0.f;
      const int itq = r32 >> 4, qr = r32 & 15;
      for (int kk = 0; kk < 16; ++kk){
        f16x8 A = *(const f16x8*)(x1 + itq*16896 + qr*264 + kk*16 + kh);
        f16x8 B = *(const f16x8*)(WIN + (size_t)(w*32 + r32)*256 + kk*16 + kh);
        acc = mfma32(A, B, acc);
      }
#pragma unroll
      for (int reg = 0; reg < 16; ++reg){
        int row = (reg & 3) + 8*(reg >> 2) + 4*(l >> 5);
        Qful[(row >> 4)*4224 + (row & 15)*264 + w*32 + r32] = (_Float16)acc[reg];
      }
    }
    __syncthreads();

    for (int h = 0; h < 4; ++h){
      if (w < 4){
        const int kt = w >> 1, dt = w & 1;
        f32x16 acc0 = 0.f, acc1 = 0.f;
        for (int kk = 0; kk < 16; ++kk){
          int ao = (kt*32 + r32)*264 + kk*16 + kh;
          f16x8 A0 = *(const f16x8*)(x1 + ao);
          f16x8 A1 = *(const f16x8*)(x1 + 16896 + ao);
          f16x8 B = *(const f16x8*)(WIN + (size_t)(256 + 64*h + dt*32 + r32)*256 + kk*16 + kh);
          acc0 = mfma32(A0, B, acc0);
          acc1 = mfma32(A1, B, acc1);
        }
#pragma unroll
        for (int reg = 0; reg < 16; ++reg){
          int row = (reg & 3) + 8*(reg >> 2) + 4*(l >> 5);
          Ks[(kt*32 + row)*72 + dt*32 + r32]        = (_Float16)acc0[reg];
          Ks[4608 + (kt*32 + row)*72 + dt*32 + r32] = (_Float16)acc1[reg];
        }
      } else {
        const int wv = w - 4;
        const int kt = wv >> 1, dt = wv & 1;
        f32x16 acc0 = 0.f, acc1 = 0.f;
        for (int kk = 0; kk < 16; ++kk){
          int ao = (kt*32 + r32)*264 + kk*16 + kh;
          f16x8 A0 = *(const f16x8*)(x1 + ao);
          f16x8 A1 = *(const f16x8*)(x1 + 16896 + ao);
          f16x8 B = *(const f16x8*)(WIN + (size_t)(512 + 64*h + dt*32 + r32)*256 + kk*16 + kh);
          acc0 = mfma32(A0, B, acc0);
          acc1 = mfma32(A1, B, acc1);
        }
#pragma unroll
        for (int rr = 0; rr < 4; ++rr){
          f16x4 p0, p1;
#pragma unroll
          for (int q4 = 0; q4 < 4; ++q4){
            p0[q4] = (_Float16)acc0[rr*4 + q4];
            p1[q4] = (_Float16)acc1[rr*4 + q4];
          }
          int key = kt*32 + rr*8 + 4*(l >> 5);
          *(f16x4*)(Vs + (dt*32 + r32)*72 + key)        = p0;
          *(f16x4*)(Vs + 4608 + (dt*32 + r32)*72 + key) = p1;
        }
      }
      __syncthreads();
      { // logits: A from Qful
        const int b = bb2[ih];
        f32x4 acc = 0.f;
#pragma unroll
        for (int kk = 0; kk < 2; ++kk){
          f16x8 A = *(const f16x8*)(Qful + ih*4224 + li*264 + 64*h + kk*32 + lg*8);
          f16x8 B = *(const f16x8*)(Ks + ih*4608 + (16*wi + li)*72 + kk*32 + lg*8);
          acc = mfma16(A, B, acc);
        }
#pragma unroll
        for (int j = 0; j < 4; ++j){
          int q = 4*lg + j, key = 16*wi + li;
          float v = acc[j] * 0.125f;
          float m = om[((size_t)b*64 + q)*64 + key];
          if (m > 0.f) v = -1e9f;
          lgs[ih*1152 + q*72 + key] = v;
        }
      }
      __syncthreads();
      { // softmax
        const int it = tid >> 8, q = (tid >> 4) & 15, i16 = tid & 15;
        const int b = bb2[it];
        float pv[4], mx = -3e38f;
#pragma unroll
        for (int u = 0; u < 4; ++u){ pv[u] = lgs[it*1152 + q*72 + i16 + 16*u]; mx = fmaxf(mx, pv[u]); }
#pragma unroll
        for (int d = 1; d < 16; d <<= 1) mx = fmaxf(mx, __shfl_xor(mx, d, 16));
        float s = 0.f;
#pragma unroll
        for (int u = 0; u < 4; ++u){ pv[u] = expf(pv[u] - mx); s += pv[u]; }
#pragma unroll
        for (int d = 1; d < 16; d <<= 1) s += __shfl_xor(s, d, 16);
#pragma unroll
        for (int u = 0; u < 4; ++u){
          int key = i16 + 16*u;
          float m = om[((size_t)b*64 + q)*64 + key];
          Ps[it*1152 + q*72 + key] = (_Float16)((pv[u]/s)*(1.f - m));
        }
      }
      __syncthreads();
      { // out_h = P @ V_h; outp stored f16
        f32x4 acc = 0.f;
#pragma unroll
        for (int kk = 0; kk < 2; ++kk){
          f16x8 A = *(const f16x8*)(Ps + ih*1152 + li*72 + kk*32 + lg*8);
          f16x8 B = *(const f16x8*)(Vs + ih*4608 + (16*wi + li)*72 + kk*32 + lg*8);
          acc = mfma16(A, B, acc);
        }
#pragma unroll
        for (int j = 0; j < 4; ++j)
          outp[ih*4224 + (4*lg + j)*264 + 64*h + 16*wi + li] = (_Float16)acc[j];
      }
      __syncthreads();
    }

    { // out-proj via 32x32, stacked M=32; wave -> n-tile w
      f32x16 acc = 0.f;
      const int ito = r32 >> 4, qr = r32 & 15;
      for (int kk = 0; kk < 16; ++kk){
        f16x8 A = *(const f16x8*)(outp + ito*4224 + qr*264 + kk*16 + kh);
        f16x8 B = *(const f16x8*)(WOUT + (size_t)(w*32 + r32)*256 + kk*16 + kh);
        acc = mfma32(A, B, acc);
      }
      int col = w*32 + r32;
      float bias = bo[col];
#pragma unroll
      for (int reg = 0; reg < 16; ++reg){
        int row = (reg & 3) + 8*(reg >> 2) + 4*(l >> 5);
        int it2 = row >> 4, q2 = row & 15;
        const int b = bb2[it2];
        float v = (acc[reg] + bias) * (1.f - em[(size_t)b*64 + q2]);
        x2out[((size_t)b*16 + q2)*256 + col] = v;
      }
    }
    return;
  }

  // ============================== gate role ==============================
  {
    constexpr int W1SZ = 96*256, WINSZ = 256*768, WVSZ = 16*256;
    const int b = blockIdx.x - 2048;
    const int l = tid & 63;
    const int r32 = l & 31, kh = (l >> 5)*8;

    char* sp = smem;
    _Float16* x1h = (_Float16*)sp; sp += 64*264*2;
    _Float16* x1l = (_Float16*)sp; sp += 64*264*2;
    _Float16* Kh  = (_Float16*)sp; sp += 64*72*2;
    _Float16* Kl  = (_Float16*)sp; sp += 64*72*2;
    _Float16* Qh  = (_Float16*)sp; sp += 16*264*2;
    _Float16* Ql  = (_Float16*)sp; sp += 16*264*2;
    float*    lgs = (float*)sp;    sp += 16*72*4;
    float*    Ps  = (float*)sp;    sp += 16*66*4;
    float*    v2s = (float*)sp;    sp += 64*18*4;
    float*  ogacc = (float*)sp;    sp += 32*4;
    float*  Kpart = (float*)sp;    sp += 8192*4;

    { // phase 1: x1 = relu(ent @ W1g + b1g), 32x32 split-2
      const int mt = w & 1, ntb = (w >> 1)*2;
      f32x16 acc0 = 0.f, acc1 = 0.f;
#pragma unroll
      for (int kk = 0; kk < 6; ++kk){
        AB<1> a = ldF<1>(ent + ((size_t)b*64 + mt*32 + r32)*96 + kk*16 + kh);
#pragma unroll
        for (int s = 0; s < 2; ++s){
          const _Float16* bp = W1g + (size_t)((ntb + s)*32 + r32)*96 + kk*16 + kh;
          f16x8 Bh = *(const f16x8*)bp;
          f16x8 Bl = *(const f16x8*)(bp + W1SZ);
          f32x16& ac = s ? acc1 : acc0;
          ac = mfma32(a.lo, Bh, ac);
          ac = mfma32(a.hi, Bl, ac);
          ac = mfma32(a.hi, Bh, ac);
        }
      }
#pragma unroll
      for (int s = 0; s < 2; ++s){
        const f32x16& ac = s ? acc1 : acc0;
        int col = (ntb + s)*32 + r32;
        float bias = b1g[col];
#pragma unroll
        for (int reg = 0; reg < 16; ++reg){
          int row = (reg & 3) + 8*(reg >> 2) + 4*(l >> 5);
          stL<1>(x1h, x1l, (mt*32 + row)*264 + col, fmaxf(ac[reg] + bias, 0.f));
        }
      }
    }
    if (tid < 32) ogacc[tid] = 0.f;
    __syncthreads();

    { // phase 2: Qfull (16x16 split-2), v2
#pragma unroll
      for (int s = 0; s < 2; ++s){
        int nt = w + s*8;
        f32x4 acc = 0.f;
        for (int kk = 0; kk < 8; ++kk){
          int ao = li*264 + kk*32 + lg*8;
          AB<1> a = ldL<1>(x1h + ao, x1l + ao);
          AB<1> bb = ldW<1>(WINg + (size_t)(nt*16 + li)*256 + kk*32 + lg*8, WINSZ);
          a.mf(bb, acc);
        }
#pragma unroll
        for (int j = 0; j < 4; ++j)
          stL<1>(Qh, Ql, (4*lg + j)*264 + nt*16 + li, acc[j]);
      }
      if (w < 4){
        f32x4 acc = 0.f;
        for (int kk = 0; kk < 8; ++kk){
          int ao = (w*16 + li)*264 + kk*32 + lg*8;
          AB<1> a = ldL<1>(x1h + ao, x1l + ao);
          AB<1> bb = ldW<1>(WVEFF + (size_t)li*256 + kk*32 + lg*8, WVSZ);
          a.mf(bb, acc);
        }
#pragma unroll
        for (int j = 0; j < 4; ++j)
          v2s[(w*16 + 4*lg + j)*18 + li] = acc[j];
      }
    }
    __syncthreads();

    for (int h = 0; h < 4; ++h){
      { // K_h partials: 32x32 split-2, tiles x k-halves across 8 waves
        const int t = w & 3, kt = t >> 1, dt = t & 1, khalf = w >> 2;
        f32x16 acc = 0.f;
#pragma unroll
        for (int k8 = 0; k8 < 8; ++k8){
          int ko = (khalf*8 + k8)*16 + kh;
          int ao = (kt*32 + r32)*264 + ko;
          f16x8 ah = *(const f16x8*)(x1h + ao);
          f16x8 al = *(const f16x8*)(x1l + ao);
          const _Float16* bp = WINg + (size_t)(256 + h*64 + dt*32 + r32)*256 + ko;
          f16x8 Bh = *(const f16x8*)bp;
          f16x8 Bl = *(const f16x8*)(bp + WINSZ);
          acc = mfma32(al, Bh, acc);
          acc = mfma32(ah, Bl, acc);
          acc = mfma32(ah, Bh, acc);
        }
#pragma unroll
        for (int reg = 0; reg < 16; ++reg){
          int row = (reg & 3) + 8*(reg >> 2) + 4*(l >> 5);
          Kpart[((khalf*4 + t)*32 + row)*32 + r32] = acc[reg];
        }
      }
      __syncthreads();
      { // reduce k-halves -> Kh/Kl
        for (int e = tid; e < 4096; e += 512){
          float s2 = Kpart[e] + Kpart[4096 + e];
          int t2 = e >> 10, idx = e & 1023, row = idx >> 5, col = idx & 31;
          stL<1>(Kh, Kl, ((t2 >> 1)*32 + row)*72 + (t2 & 1)*32 + col, s2);
        }
      }
      __syncthreads();
      if (w < 4){ // logits
        f32x4 acc = 0.f;
#pragma unroll
        for (int kk = 0; kk < 2; ++kk){
          int ao = li*264 + h*64 + kk*32 + lg*8;
          AB<1> a = ldL<1>(Qh + ao, Ql + ao);
          int bo_ = (16*w + li)*72 + kk*32 + lg*8;
          AB<1> bb = ldL<1>(Kh + bo_, Kl + bo_);
          a.mf(bb, acc);
        }
#pragma unroll
        for (int j = 0; j < 4; ++j){
          int q = 4*lg + j, key = 16*w + li;
          float v = acc[j] * 0.125f;
          float m = om[((size_t)b*64 + q)*64 + key];
          if (m > 0.f) v = -1e9f;
          lgs[q*72 + key] = v;
        }
      }
      __syncthreads();
      if (tid < 256){ // softmax
        int q = tid >> 4, i16 = tid & 15;
        float pv[4], mx = -3e38f;
#pragma unroll
        for (int u = 0; u < 4; ++u){ pv[u] = lgs[q*72 + i16 + 16*u]; mx = fmaxf(mx, pv[u]); }
#pragma unroll
        for (int d = 1; d < 16; d <<= 1) mx = fmaxf(mx, __shfl_xor(mx, d, 16));
        float s = 0.f;
#pragma unroll
        for (int u = 0; u < 4; ++u){ pv[u] = expf(pv[u] - mx); s += pv[u]; }
#pragma unroll
        for (int d = 1; d < 16; d <<= 1) s += __shfl_xor(s, d, 16);
#pragma unroll
        for (int u = 0; u < 4; ++u){
          int key = i16 + 16*u;
          float m = om[((size_t)b*64 + q)*64 + key];
          Ps[q*66 + key] = (pv[u]/s)*(1.f - m);
        }
      }
      __syncthreads();
      if (tid < 256){ // og += P_h . v2_h
        int q = tid >> 4, l16 = tid & 15;
        float a0 = 0.f, a1 = 0.f;
#pragma unroll
        for (int u = 0; u < 4; ++u){
          int k = l16 + 16*u;
          float p2 = Ps[q*66 + k];
          a0 += p2 * v2s[k*18 + h*2];
          a1 += p2 * v2s[k*18 + h*2 + 1];
        }
#pragma unroll
        for (int d = 1; d < 16; d <<= 1){ a0 += __shfl_xor(a0, d, 16); a1 += __shfl_xor(a1, d, 16); }
        if (l16 == 0){ ogacc[q*2] += a0; ogacc[q*2 + 1] += a1; }
      }
      __syncthreads();
    }
    if (tid < 16){
      int q = tid;
      float am = em[(size_t)b*64 + q];
      float g0 = (1.f - am)*(ogacc[2*q]     + beff[0]) + gb2[0];
      float g1 = (1.f - am)*(ogacc[2*q + 1] + beff[1]) + gb2[1];
      og[((size_t)b*16 + q)*2]     = g0;
      og[((size_t)b*16 + q)*2 + 1] = g1;
      gate[(size_t)b*16 + q] = (g1 > g0) ? 1.f : 0.f;
    }
  }
}

// ------------------- K2: gate, global attention, fc2, gi — 2 items/block
// r18: out-proj / fc2 / gi stacked M=32 via 32x32 (r17-verified mapping).
__global__ __launch_bounds__(256) void k2_global(
    const float* __restrict__ em,
    const float* __restrict__ x2, const float* __restrict__ x2m,
    const float* __restrict__ gate,
    const _Float16* __restrict__ GMIN, const _Float16* __restrict__ GMOUT, const float* __restrict__ gob,
    const _Float16* __restrict__ FC2T, const float* __restrict__ fc2b,
    const _Float16* __restrict__ GIHT, const float* __restrict__ gib,
    float* __restrict__ gi)
{
  const int p = blockIdx.x;
  const int tid = threadIdx.x;
  const int w = tid >> 6, lg = (tid >> 4) & 3, li = tid & 15;
  const int l = tid & 63;
  const int r32 = l & 31, kh = (l >> 5)*8;

  extern __shared__ char smem[];
  float*    gate_s = (float*)smem;
  _Float16* gm_s   = (_Float16*)(smem + 128);
  _Float16* Q2     = (_Float16*)(smem + 17024);
  _Float16* K2s    = (_Float16*)(smem + 21632);
  _Float16* Vt2    = (_Float16*)(smem + 26240);
  float*    lg2    = (float*)(smem + 36480);
  _Float16* P2     = (_Float16*)(smem + 39552);
  _Float16* outp   = (_Float16*)(smem + 42112);
  _Float16* cat_s  = (_Float16*)(smem + 59008);
  _Float16* x3_s   = (_Float16*)(smem + 92288);

  if (tid < 32){
    int it = tid >> 4, q = tid & 15;
    gate_s[it*16 + q] = gate[(size_t)(2*p + it)*16 + q];
  }
  __syncthreads();
#pragma unroll
  for (int it = 0; it < 2; ++it){
    const int b = 2*p + it;
    for (int idx = tid; idx < 4096; idx += 256){
      int q = idx >> 8, d = idx & 255;
      gm_s[it*4224 + q*264 + d]  = (_Float16)(x2m[((size_t)b*16 + q)*256 + d] * gate_s[it*16 + q]);
      cat_s[it*8320 + q*520 + d] = (_Float16)(x2[((size_t)b*16 + q)*256 + d]);
    }
  }
  for (int idx = tid; idx < 2*64*40; idx += 256) Vt2[idx] = (_Float16)0.f;
  for (int idx = tid; idx < 2*16*40; idx += 256) P2[idx] = (_Float16)0.f;
  __syncthreads();
  for (int h = 0; h < 4; ++h){
    {
      f32x4 aq0 = 0.f, aq1 = 0.f, ak0 = 0.f, ak1 = 0.f, av0 = 0.f, av1 = 0.f;
      for (int kk = 0; kk < 8; ++kk){
        f16x8 A0 = *(const f16x8*)(gm_s + li*264 + kk*32 + lg*8);
        f16x8 A1 = *(const f16x8*)(gm_s + 4224 + li*264 + kk*32 + lg*8);
        f16x8 Bq = *(const f16x8*)(GMIN + (size_t)(      64*h + 16*w + li)*256 + kk*32 + lg*8);
        f16x8 Bk = *(const f16x8*)(GMIN + (size_t)(256 + 64*h + 16*w + li)*256 + kk*32 + lg*8);
        f16x8 Bv = *(const f16x8*)(GMIN + (size_t)(512 + 64*h + 16*w + li)*256 + kk*32 + lg*8);
        aq0 = mfma16(A0, Bq, aq0); aq1 = mfma16(A1, Bq, aq1);
        ak0 = mfma16(A0, Bk, ak0); ak1 = mfma16(A1, Bk, ak1);
        av0 = mfma16(A0, Bv, av0); av1 = mfma16(A1, Bv, av1);
      }
#pragma unroll
      for (int j = 0; j < 4; ++j){
        int rw = 4*lg + j, dim = 16*w + li;
        Q2[rw*72 + dim]         = (_Float16)aq0[j];
        Q2[1152 + rw*72 + dim]  = (_Float16)aq1[j];
        K2s[rw*72 + dim]        = (_Float16)ak0[j];
        K2s[1152 + rw*72 + dim] = (_Float16)ak1[j];
        Vt2[dim*40 + rw]        = (_Float16)av0[j];
        Vt2[2560 + dim*40 + rw] = (_Float16)av1[j];
      }
    }
    __syncthreads();
    if (w < 2){
      const int it = w, b = 2*p + it;
      f32x4 acc = 0.f;
#pragma unroll
      for (int kk = 0; kk < 2; ++kk){
        f16x8 A = *(const f16x8*)(Q2  + it*1152 + li*72 + kk*32 + lg*8);
        f16x8 B = *(const f16x8*)(K2s + it*1152 + li*72 + kk*32 + lg*8);
        acc = mfma16(A, B, acc);
      }
      float amk = em[(size_t)b*64 + li];
#pragma unroll
      for (int j = 0; j < 4; ++j){
        int q = 4*lg + j;
        float amq = em[(size_t)b*64 + q];
        float m = 1.f - (1.f - amq)*(1.f - amk);
        float v = acc[j]*0.125f;
        if (m > 0.f) v = -1e9f;
        lg2[it*384 + q*24 + li] = v;
      }
    }
    __syncthreads();
    {
      int q = tid >> 4, key = tid & 15;
#pragma unroll
      for (int it = 0; it < 2; ++it){
        const int b = 2*p + it;
        float v = lg2[it*384 + q*24 + key];
        float mx = v;
#pragma unroll
        for (int d = 1; d < 16; d <<= 1) mx = fmaxf(mx, __shfl_xor(mx, d, 16));
        float pe = expf(v - mx);
        float s = pe;
#pragma unroll
        for (int d = 1; d < 16; d <<= 1) s += __shfl_xor(s, d, 16);
        float amq = em[(size_t)b*64 + q], amk = em[(size_t)b*64 + key];
        float m = 1.f - (1.f - amq)*(1.f - amk);
        P2[it*640 + q*40 + key] = (_Float16)((pe/s)*(1.f - m));
      }
    }
    __syncthreads();
    {
#pragma unroll
      for (int it = 0; it < 2; ++it){
        f32x4 acc = 0.f;
        f16x8 A = *(const f16x8*)(P2 + it*640 + li*40 + lg*8);
        f16x8 B = *(const f16x8*)(Vt2 + it*2560 + (16*w + li)*40 + lg*8);
        acc = mfma16(A, B, acc);
#pragma unroll
        for (int j = 0; j < 4; ++j)
          outp[it*4224 + (4*lg + j)*264 + 64*h + 16*w + li] = (_Float16)acc[j];
      }
    }
    __syncthreads();
  }
  { // gmsg out-proj stacked M=32; wave -> n-tiles {2w, 2w+1}
    const int ito = r32 >> 4, qr = r32 & 15;
#pragma unroll
    for (int s = 0; s < 2; ++s){
      int nt = 2*w + s;
      f32x16 acc = 0.f;
      for (int kk = 0; kk < 16; ++kk){
        f16x8 A = *(const f16x8*)(outp + ito*4224 + qr*264 + kk*16 + kh);
        f16x8 B = *(const f16x8*)(GMOUT + (size_t)(nt*32 + r32)*256 + kk*16 + kh);
        acc = mfma32(A, B, acc);
      }
      int col = nt*32 + r32;
      float bias = gob[col];
#pragma unroll
      for (int reg = 0; reg < 16; ++reg){
        int row = (reg & 3) + 8*(reg >> 2) + 4*(l >> 5);
        int it2 = row >> 4, q2 = row & 15;
        float m = 1.f - em[(size_t)(2*p + it2)*64 + q2];
        cat_s[it2*8320 + q2*520 + 256 + col] = (_Float16)((acc[reg] + bias)*m);
      }
    }
  }
  __syncthreads();
  { // x3 = relu(cat @ fc2 + b) stacked M=32; wave -> n-tiles {2w, 2w+1}, K=512
    const int ito = r32 >> 4, qr = r32 & 15;
#pragma unroll
    for (int s = 0; s < 2; ++s){
      int nt = 2*w + s;
      f32x16 acc = 0.f;
      for (int kk = 0; kk < 32; ++kk){
        f16x8 A = *(const f16x8*)(cat_s + ito*8320 + qr*520 + kk*16 + kh);
        f16x8 B = *(const f16x8*)(FC2T + (size_t)(nt*32 + r32)*512 + kk*16 + kh);
        acc = mfma32(A, B, acc);
      }
      int col = nt*32 + r32;
      float bias = fc2b[col];
#pragma unroll
      for (int reg = 0; reg < 16; ++reg){
        int row = (reg & 3) + 8*(reg >> 2) + 4*(l >> 5);
        int it2 = row >> 4, q2 = row & 15;
        x3_s[it2*4224 + q2*264 + col] = (_Float16)fmaxf(acc[reg] + bias, 0.f);
      }
    }
  }
  __syncthreads();
  { // gi stacked M=32; wave -> n-tiles {6w .. 6w+5}, N=768
    const int r0 = ((2*p) >> 6)*16, t0 = (2*p) & 63;
    const int ito = r32 >> 4, qr = r32 & 15;
#pragma unroll
    for (int s = 0; s < 6; ++s){
      int nt = 6*w + s;
      f32x16 acc = 0.f;
      for (int kk = 0; kk < 16; ++kk){
        f16x8 A = *(const f16x8*)(x3_s + ito*4224 + qr*264 + kk*16 + kh);
        f16x8 B = *(const f16x8*)(GIHT + (size_t)(nt*32 + r32)*256 + kk*16 + kh);
        acc = mfma32(A, B, acc);
      }
      int col = nt*32 + r32;
      float bias = gib[col];
#pragma unroll
      for (int reg = 0; reg < 16; ++reg){
        int row = (reg & 3) + 8*(reg >> 2) + 4*(l >> 5);
        int it2 = row >> 4, q2 = row & 15;
        gi[((size_t)((r0 + q2)*64 + t0 + it2))*768 + col] = acc[reg] + bias;
      }
    }
  }
}

// ------------------------------------------------------------------ K3: GRU
// r18: 512 threads = 8 waves x 6 col-tiles (was 4 waves x 12) — doubles the
// latency-hiding pool on the per-step w_hh L2 stream. Same math/barriers.
__global__ __launch_bounds__(512) void k3_gru(
    const _Float16* __restrict__ WHH, const float* __restrict__ bhh,
    const float* __restrict__ gi, const float* __restrict__ h0,
    float* __restrict__ hs)
{
  const int rb = blockIdx.x;
  const int row0 = rb * 16;
  const int tid = threadIdx.x;
  const int w = tid >> 6, lg = (tid >> 4) & 3, li = tid & 15;

  extern __shared__ char smem3[];
  _Float16* hf16 = (_Float16*)smem3;
  float* hf32 = (float*)(smem3 + 8448);
  float* gh   = (float*)(smem3 + 8448 + 16640);
  float* bhs  = (float*)(smem3 + 8448 + 16640 + 49664);

  for (int idx = tid; idx < 768; idx += 512) bhs[idx] = bhh[idx];
  for (int idx = tid; idx < 4096; idx += 512){
    int r = idx >> 8, d = idx & 255;
    float v = h0[(size_t)(row0 + r)*256 + d];
    hf32[r*260 + d] = v;
    hf16[r*264 + d] = (_Float16)v;
  }
  __syncthreads();

  const int er = tid >> 5;            // elementwise row 0..15
  const int dd = (tid & 31) * 8;      // elementwise dim base (8 dims)

  for (int t = 0; t < 64; ++t){
    const float* gp = gi + ((size_t)(row0 + er)*64 + t)*768 + dd;
    f32x4 gr[2], gz[2], gn[2];
#pragma unroll
    for (int v = 0; v < 2; ++v){
      gr[v] = *(const f32x4*)(gp + v*4);
      gz[v] = *(const f32x4*)(gp + 256 + v*4);
      gn[v] = *(const f32x4*)(gp + 512 + v*4);
    }
    f16x8 a[8];
#pragma unroll
    for (int kk = 0; kk < 8; ++kk)
      a[kk] = *(const f16x8*)(hf16 + li*264 + kk*32 + lg*8);
    f32x4 acc[6];
#pragma unroll
    for (int c = 0; c < 6; ++c) acc[c] = 0.f;
#pragma unroll
    for (int c = 0; c < 6; ++c){
      const _Float16* bp = WHH + (size_t)(w*96 + c*16 + li)*256 + lg*8;
#pragma unroll
      for (int kk = 0; kk < 8; ++kk)
        acc[c] = mfma16(a[kk], *(const f16x8*)(bp + kk*32), acc[c]);
    }
#pragma unroll
    for (int c = 0; c < 6; ++c){
      int col = w*96 + c*16 + li;
#pragma unroll
      for (int j = 0; j < 4; ++j)
        gh[(4*lg + j)*776 + col] = acc[c][j];
    }
    __syncthreads();
    {
      float* hp32 = hf32 + er*260 + dd;
      float* hsp  = hs + ((size_t)(rb*64 + t)*16 + er)*256 + dd;
      f16x8 hv8;
#pragma unroll
      for (int v = 0; v < 2; ++v){
        f32x4 xr = *(const f32x4*)(gh + er*776 +       dd + v*4);
        f32x4 xz = *(const f32x4*)(gh + er*776 + 256 + dd + v*4);
        f32x4 xn = *(const f32x4*)(gh + er*776 + 512 + dd + v*4);
        f32x4 hold = *(const f32x4*)(hp32 + v*4);
        f32x4 hout;
#pragma unroll
        for (int e = 0; e < 4; ++e){
          int d = dd + v*4 + e;
          float rr_ = 1.f/(1.f + __expf(-(gr[v][e] + xr[e] + bhs[d])));
          float zz  = 1.f/(1.f + __expf(-(gz[v][e] + xz[e] + bhs[256 + d])));
          float pre = gn[v][e] + rr_*(xn[e] + bhs[512 + d]);
          float nn  = 1.f - 2.f/(1.f + __expf(2.f*pre));
          float hv = (1.f - zz)*nn + zz*hold[e];
          hout[e] = hv;
          hv8[v*4 + e] = (_Float16)hv;
        }
        *(f32x4*)(hp32 + v*4) = hout;
        *(f32x4*)(hsp + v*4)  = hout;
      }
      *(f16x8*)(hf16 + er*264 + dd) = hv8;
    }
    __syncthreads();
  }
}

// ------------------------------------------------------------------ K4: q out
__global__ __launch_bounds__(256) void k4_q(
    const _Float16* __restrict__ FC3T, const float* __restrict__ fc3b,
    const float* __restrict__ em, const float* __restrict__ hs, float* __restrict__ qo)
{
  const int tid = threadIdx.x;
  const int w = tid >> 6, lg = (tid >> 4) & 3, li = tid & 15;
  const int rb = blockIdx.x*64 + 16*w;
  f32x4 acc[2];
#pragma unroll
  for (int c = 0; c < 2; ++c) acc[c] = 0.f;
  for (int kk = 0; kk < 8; ++kk){
    const float* ap = hs + (size_t)(rb + li)*256 + kk*32 + lg*8;
    f32x4 v0 = *(const f32x4*)ap, v1 = *(const f32x4*)(ap + 4);
    f16x8 A;
#pragma unroll
    for (int e = 0; e < 4; ++e){ A[e] = (_Float16)v0[e]; A[e+4] = (_Float16)v1[e]; }
#pragma unroll
    for (int c = 0; c < 2; ++c){
      f16x8 B = *(const f16x8*)(FC3T + (size_t)(16*c + li)*256 + kk*32 + lg*8);
      acc[c] = mfma16(A, B, acc[c]);
    }
  }
#pragma unroll
  for (int c = 0; c < 2; ++c){
    int col = 16*c + li;
    float bias = fc3b[col];
#pragma unroll
    for (int j = 0; j < 4; ++j){
      int row = rb + 4*lg + j;
      float am = em[(size_t)(row >> 4)*64 + (row & 15)];
      qo[(size_t)row*32 + col] = (acc[c][j] + bias)*(1.f - am);
    }
  }
}

// --------------------------------------------------------------------- launch
extern "C" void kernel_launch(void* const* d_in, const int* in_sizes, int n_in,
                              void* d_out, int out_size, void* d_ws, size_t ws_size,
                              hipStream_t stream)
{
  constexpr size_t OFF_FC1T   = 0;
  constexpr size_t OFF_MSG1T  = 49152;
  constexpr size_t OFF_AINT   = 98304;
  constexpr size_t OFF_LINT   = 491520;
  constexpr size_t OFF_AOUTT  = 884736;
  constexpr size_t OFF_LOUTT  = 1015808;
  constexpr size_t OFF_GMINT  = 1146880;
  constexpr size_t OFF_GMOUTT = 1540096;
  constexpr size_t OFF_FC2T   = 1671168;
  constexpr size_t OFF_GIHT   = 1933312;
  constexpr size_t OFF_GHHT   = 2326528;
  constexpr size_t OFF_FC3T   = 2719744;
  constexpr size_t OFF_G1T    = 2736128;
  constexpr size_t OFF_GINT   = 2834432;
  constexpr size_t OFF_WVEFF  = 3620864;
  constexpr size_t OFF_BEFF   = 3637248;
  constexpr size_t OFF_GATE   = 3637504;
  constexpr size_t OFF_X2     = 3768576;
  constexpr size_t OFF_X2M    = 37323008;
  constexpr size_t OFF_GI     = 70877440;
  constexpr size_t NEED       = 171540736;
  if (ws_size < NEED) return;

  char* ws = (char*)d_ws;
  const float* ent = (const float*)d_in[0];
  const float* om  = (const float*)d_in[1];
  const float* em  = (const float*)d_in[2];

  WJobs jb{};
  int nj = 0;
  auto addj = [&](int src_idx, size_t off, int K, int N, int m){
    jb.src[nj] = (const float*)d_in[src_idx]; jb.off[nj] = (unsigned)off;
    jb.K[nj] = K; jb.N[nj] = N; jb.mode[nj] = m; ++nj;
  };
  addj(4,  OFF_FC1T,   96, 256, 0);
  addj(17, OFF_MSG1T,  96, 256, 0);
  addj(6,  OFF_AINT,  256, 768, 0);
  addj(19, OFF_LINT,  256, 768, 0);
  addj(7,  OFF_AOUTT, 256, 256, 0);
  addj(20, OFF_LOUTT, 256, 256, 0);
  addj(22, OFF_GMINT, 256, 768, 0);
  addj(23, OFF_GMOUTT,256, 256, 0);
  addj(9,  OFF_FC2T,  512, 256, 0);
  addj(11, OFF_GIHT,  256, 768, 0);
  addj(12, OFF_GHHT,  256, 768, 0);
  addj(15, OFF_FC3T,  256,  32, 0);
  addj(28, OFF_G1T,    96, 256, 1);
  addj(25, OFF_GINT,  256, 768, 1);
  k0_conv<<<dim3(96, nj), 256, 0, stream>>>(jb, ws);

  k0w_gate<<<1, 256, 0, stream>>>(
      (const float*)d_in[26], (const float*)d_in[30],
      (const float*)d_in[27], (const float*)d_in[25],
      (_Float16*)(ws + OFF_WVEFF), (float*)(ws + OFF_BEFF));

  constexpr int SMB = 156672, SMK2 = 109184, SM3 = 77824;
  (void)hipFuncSetAttribute(reinterpret_cast<const void*>(&k1_all),
                            hipFuncAttributeMaxDynamicSharedMemorySize, SMB);
  (void)hipFuncSetAttribute(reinterpret_cast<const void*>(&k2_global),
                            hipFuncAttributeMaxDynamicSharedMemorySize, SMK2);
  (void)hipFuncSetAttribute(reinterpret_cast<const void*>(&k3_gru),
                            hipFuncAttributeMaxDynamicSharedMemorySize, SM3);

  float* qout = (float*)d_out;
  float* hsout = qout + 1048576;
  float* gout = qout + 9437184;

  k1_all<<<4096, 512, SMB, stream>>>(ent, om, em,
      (const _Float16*)(ws + OFF_FC1T),  (const float*)d_in[5],
      (const _Float16*)(ws + OFF_AINT),
      (const _Float16*)(ws + OFF_AOUTT), (const float*)d_in[8],
      (float*)(ws + OFF_X2),
      (const _Float16*)(ws + OFF_MSG1T), (const float*)d_in[18],
      (const _Float16*)(ws + OFF_LINT),
      (const _Float16*)(ws + OFF_LOUTT), (const float*)d_in[21],
      (float*)(ws + OFF_X2M),
      (const _Float16*)(ws + OFF_G1T),   (const float*)d_in[29],
      (const _Float16*)(ws + OFF_GINT),
      (const _Float16*)(ws + OFF_WVEFF),
      (const float*)(ws + OFF_BEFF), (const float*)d_in[31],
      gout, (float*)(ws + OFF_GATE));

  k2_global<<<1024, 256, SMK2, stream>>>(em,
      (const float*)(ws + OFF_X2), (const float*)(ws + OFF_X2M),
      (const float*)(ws + OFF_GATE),
      (const _Float16*)(ws + OFF_GMINT), (const _Float16*)(ws + OFF_GMOUTT), (const float*)d_in[24],
      (const _Float16*)(ws + OFF_FC2T), (const float*)d_in[10],
      (const _Float16*)(ws + OFF_GIHT), (const float*)d_in[13],
      (float*)(ws + OFF_GI));

  k3_gru<<<32, 512, SM3, stream>>>(
      (const _Float16*)(ws + OFF_GHHT), (const float*)d_in[14],
      (const float*)(ws + OFF_GI), (const float*)d_in[3], hsout);

  k4_q<<<512, 256, 0, stream>>>(
      (const _Float16*)(ws + OFF_FC3T), (const float*)d_in[16],
      em, hsout, qout);
}

// Round 19
// 1143.565 us; speedup vs baseline: 1.3973x; 1.0094x over previous
//
#include <hip/hip_runtime.h>

// EntityAttentionRNNMsgAgent — fused MI355X implementation.
// r19 = r18 + k2: QKV hoisted out of the head loop as one stacked-M=32
// 32x32 GEMM (96 mfma32/wave vs 192 mfma16/wave; head loop = logits/softmax/
// PV only, 3 barriers/head). LDS via lifetime overlay: cat_s overlays
// Qall/Kall (dead after head-3 logits); x2->cat staging moved to gmsg phase.
// k1_all / k3 / k4 / k0 / k0w byte-identical to r18 (1154.3us verified).

#define DEV __device__ __forceinline__

typedef _Float16 f16x8 __attribute__((ext_vector_type(8)));
typedef _Float16 f16x4 __attribute__((ext_vector_type(4)));
typedef float    f32x4 __attribute__((ext_vector_type(4)));
typedef float    f32x16 __attribute__((ext_vector_type(16)));

DEV f32x4 mfma16(f16x8 a, f16x8 b, f32x4 c){
  return __builtin_amdgcn_mfma_f32_16x16x32_f16(a, b, c, 0, 0, 0);
}
DEV f32x16 mfma32(f16x8 a, f16x8 b, f32x16 c){
  return __builtin_amdgcn_mfma_f32_32x32x16_f16(a, b, c, 0, 0, 0);
}

// A/B fragment pair for optional split-precision (MODE=1: value = hi + lo)
template<int MODE> struct AB {
  f16x8 hi, lo;
  DEV void mf(const AB& b, f32x4& c) const {
    if constexpr (MODE){
      c = mfma16(lo, b.hi, c);
      c = mfma16(hi, b.lo, c);
    }
    c = mfma16(hi, b.hi, c);
  }
};

template<int MODE> DEV AB<MODE> ldW(const _Float16* p, int losz){
  AB<MODE> r; r.hi = *(const f16x8*)p;
  if constexpr (MODE) r.lo = *(const f16x8*)(p + losz);
  return r;
}
template<int MODE> DEV AB<MODE> ldL(const _Float16* ph, const _Float16* pl){
  AB<MODE> r; r.hi = *(const f16x8*)ph;
  if constexpr (MODE) r.lo = *(const f16x8*)pl;
  return r;
}
template<int MODE> DEV AB<MODE> ldF(const float* p){
  AB<MODE> r;
  f32x4 v0 = *(const f32x4*)p, v1 = *(const f32x4*)(p + 4);
#pragma unroll
  for (int i = 0; i < 4; ++i){
    float a = v0[i], b = v1[i];
    _Float16 ah = (_Float16)a, bh = (_Float16)b;
    r.hi[i] = ah; r.hi[i+4] = bh;
    if constexpr (MODE){
      r.lo[i]   = (_Float16)(a - (float)ah);
      r.lo[i+4] = (_Float16)(b - (float)bh);
    }
  }
  return r;
}
template<int MODE> DEV void stL(_Float16* ph, _Float16* pl, int idx, float v){
  _Float16 h = (_Float16)v;
  ph[idx] = h;
  if constexpr (MODE) pl[idx] = (_Float16)(v - (float)h);
}

// ---------------------------------------------------------------- K0: weights
struct WJobs {
  const float* src[15];
  unsigned off[15];
  int K[15], N[15], mode[15];
};

__global__ __launch_bounds__(256) void k0_conv(WJobs jb, char* ws){
  const int job = blockIdx.y;
  const int K = jb.K[job], N = jb.N[job];
  const int total = K * N;
  _Float16* dh = (_Float16*)(ws + jb.off[job]);
  const float* src = jb.src[job];
  const int m = jb.mode[job];
  for (int idx = blockIdx.x*256 + threadIdx.x; idx < total; idx += gridDim.x*256){
    int n = idx / K, k = idx - n*K;
    float v = src[(size_t)k*N + n];
    _Float16 h = (_Float16)v;
    dh[idx] = h;
    if (m) dh[total + idx] = (_Float16)(v - (float)h);
  }
}

// ------------------------------------------------- K0w: gate-tail precompute
__global__ __launch_bounds__(256) void k0w_gate(
    const float* __restrict__ Wout, const float* __restrict__ Wg2,
    const float* __restrict__ bo,   const float* __restrict__ Win,
    _Float16* __restrict__ wveff, float* __restrict__ beff)
{
  __shared__ float weff_s[256*2];
  const int tid = threadIdx.x;
  {
    float a0 = 0.f, a1 = 0.f;
    const float* wr = Wout + (size_t)tid*256;
    for (int f = 0; f < 256; ++f){ float x = wr[f]; a0 += x*Wg2[2*f]; a1 += x*Wg2[2*f+1]; }
    weff_s[tid*2] = a0; weff_s[tid*2+1] = a1;
  }
  if (tid < 2){
    float s = 0.f;
    for (int f = 0; f < 256; ++f) s += bo[f]*Wg2[2*f + tid];
    beff[tid] = s;
  }
  __syncthreads();
  {
    const int j = tid;
    for (int n = 0; n < 16; ++n){
      float v = 0.f;
      if (n < 8){
        int h = n >> 1, c = n & 1;
        const float* wr = Win + (size_t)j*768 + 512 + h*64;
        const float* we = weff_s + (h*64)*2 + c;
        for (int d = 0; d < 64; ++d) v += wr[d]*we[2*d];
      }
      _Float16 hi = (_Float16)v;
      wveff[n*256 + j] = hi;
      wveff[16*256 + n*256 + j] = (_Float16)(v - (float)hi);
    }
  }
}

// -------------------------------------------- K1 fused: branch2 + gate roles
__global__ __launch_bounds__(512) void k1_all(
    const float* __restrict__ ent, const float* __restrict__ om, const float* __restrict__ em,
    const _Float16* __restrict__ W1a, const float* __restrict__ b1a,
    const _Float16* __restrict__ WINa,
    const _Float16* __restrict__ WOUTa, const float* __restrict__ boa,
    float* __restrict__ x2outa,
    const _Float16* __restrict__ W1b, const float* __restrict__ b1b,
    const _Float16* __restrict__ WINb,
    const _Float16* __restrict__ WOUTb, const float* __restrict__ bob,
    float* __restrict__ x2outb,
    const _Float16* __restrict__ W1g, const float* __restrict__ b1g,
    const _Float16* __restrict__ WINg,
    const _Float16* __restrict__ WVEFF,
    const float* __restrict__ beff, const float* __restrict__ gb2,
    float* __restrict__ og, float* __restrict__ gate)
{
  const int tid = threadIdx.x;
  const int w = tid >> 6, lg = (tid >> 4) & 3, li = tid & 15;
  extern __shared__ char smem[];

  if (blockIdx.x < 2048){
    // ============================ branch2 role ============================
    const int br = blockIdx.x >> 10;
    const int p  = blockIdx.x & 1023;
    const int bb2[2] = { 2*p, 2*p + 1 };
    const _Float16* W1   = br ? W1b   : W1a;
    const float*    b1   = br ? b1b   : b1a;
    const _Float16* WIN  = br ? WINb  : WINa;
    const _Float16* WOUT = br ? WOUTb : WOUTa;
    const float*    bo   = br ? bob   : boa;
    float*          x2out= br ? x2outb: x2outa;

    const int wi = w & 3, ih = w >> 2;
    const int l = tid & 63;
    const int r32 = l & 31, kh = (l >> 5)*8;

    _Float16* x1   = (_Float16*)smem;
    _Float16* Ks   = (_Float16*)(smem + 67584);
    _Float16* Vs   = (_Float16*)(smem + 86016);
    _Float16* Qful = (_Float16*)(smem + 104448);
    float*    lgs  = (float*)(smem + 121344);
    _Float16* Ps   = (_Float16*)(smem + 130560);
    _Float16* outp = (_Float16*)(smem + 135168);

    { // phase 1: x1 = relu(ent @ W1 + b1) via 32x32x16
      const int b = bb2[ih];
      _Float16* x1p = x1 + ih*16896;
      const int mt = wi & 1, ntb = (wi >> 1)*4;
      f32x16 acc0 = 0.f, acc1 = 0.f, acc2 = 0.f, acc3 = 0.f;
#pragma unroll
      for (int kk = 0; kk < 6; ++kk){
        AB<0> a = ldF<0>(ent + ((size_t)b*64 + mt*32 + r32)*96 + kk*16 + kh);
        f16x8 B0 = *(const f16x8*)(W1 + (size_t)((ntb + 0)*32 + r32)*96 + kk*16 + kh);
        f16x8 B1 = *(const f16x8*)(W1 + (size_t)((ntb + 1)*32 + r32)*96 + kk*16 + kh);
        f16x8 B2 = *(const f16x8*)(W1 + (size_t)((ntb + 2)*32 + r32)*96 + kk*16 + kh);
        f16x8 B3 = *(const f16x8*)(W1 + (size_t)((ntb + 3)*32 + r32)*96 + kk*16 + kh);
        acc0 = mfma32(a.hi, B0, acc0);
        acc1 = mfma32(a.hi, B1, acc1);
        acc2 = mfma32(a.hi, B2, acc2);
        acc3 = mfma32(a.hi, B3, acc3);
      }
#pragma unroll
      for (int s = 0; s < 4; ++s){
        const f32x16& ac = (s == 0) ? acc0 : (s == 1) ? acc1 : (s == 2) ? acc2 : acc3;
        int col = (ntb + s)*32 + r32;
        float bias = b1[col];
#pragma unroll
        for (int reg = 0; reg < 16; ++reg){
          int row = (reg & 3) + 8*(reg >> 2) + 4*(l >> 5);
          x1p[(mt*32 + row)*264 + col] = (_Float16)fmaxf(ac[reg] + bias, 0.f);
        }
      }
    }
    __syncthreads();

    { // Qfull = x1[rows 0..15, both items stacked M=32] @ Wq; wave -> n-tile w
      f32x16 acc = 0.f;
      const int itq = r32 >> 4, qr = r32 & 15;
      for (int kk = 0; kk < 16; ++kk){
        f16x8 A = *(const f16x8*)(x1 + itq*16896 + qr*264 + kk*16 + kh);
        f16x8 B = *(const f16x8*)(WIN + (size_t)(w*32 + r32)*256 + kk*16 + kh);
        acc = mfma32(A, B, acc);
      }
#pragma unroll
      for (int reg = 0; reg < 16; ++reg){
        int row = (reg & 3) + 8*(reg >> 2) + 4*(l >> 5);
        Qful[(row >> 4)*4224 + (row & 15)*264 + w*32 + r32] = (_Float16)acc[reg];
      }
    }
    __syncthreads();

    for (int h = 0; h < 4; ++h){
      if (w < 4){
        const int kt = w >> 1, dt = w & 1;
        f32x16 acc0 = 0.f, acc1 = 0.f;
        for (int kk = 0; kk < 16; ++kk){
          int ao = (kt*32 + r32)*264 + kk*16 + kh;
          f16x8 A0 = *(const f16x8*)(x1 + ao);
          f16x8 A1 = *(const f16x8*)(x1 + 16896 + ao);
          f16x8 B = *(const f16x8*)(WIN + (size_t)(256 + 64*h + dt*32 + r32)*256 + kk*16 + kh);
          acc0 = mfma32(A0, B, acc0);
          acc1 = mfma32(A1, B, acc1);
        }
#pragma unroll
        for (int reg = 0; reg < 16; ++reg){
          int row = (reg & 3) + 8*(reg >> 2) + 4*(l >> 5);
          Ks[(kt*32 + row)*72 + dt*32 + r32]        = (_Float16)acc0[reg];
          Ks[4608 + (kt*32 + row)*72 + dt*32 + r32] = (_Float16)acc1[reg];
        }
      } else {
        const int wv = w - 4;
        const int kt = wv >> 1, dt = wv & 1;
        f32x16 acc0 = 0.f, acc1 = 0.f;
        for (int kk = 0; kk < 16; ++kk){
          int ao = (kt*32 + r32)*264 + kk*16 + kh;
          f16x8 A0 = *(const f16x8*)(x1 + ao);
          f16x8 A1 = *(const f16x8*)(x1 + 16896 + ao);
          f16x8 B = *(const f16x8*)(WIN + (size_t)(512 + 64*h + dt*32 + r32)*256 + kk*16 + kh);
          acc0 = mfma32(A0, B, acc0);
          acc1 = mfma32(A1, B, acc1);
        }
#pragma unroll
        for (int rr = 0; rr < 4; ++rr){
          f16x4 p0, p1;
#pragma unroll
          for (int q4 = 0; q4 < 4; ++q4){
            p0[q4] = (_Float16)acc0[rr*4 + q4];
            p1[q4] = (_Float16)acc1[rr*4 + q4];
          }
          int key = kt*32 + rr*8 + 4*(l >> 5);
          *(f16x4*)(Vs + (dt*32 + r32)*72 + key)        = p0;
          *(f16x4*)(Vs + 4608 + (dt*32 + r32)*72 + key) = p1;
        }
      }
      __syncthreads();
      { // logits: A from Qful
        const int b = bb2[ih];
        f32x4 acc = 0.f;
#pragma unroll
        for (int kk = 0; kk < 2; ++kk){
          f16x8 A = *(const f16x8*)(Qful + ih*4224 + li*264 + 64*h + kk*32 + lg*8);
          f16x8 B = *(const f16x8*)(Ks + ih*4608 + (16*wi + li)*72 + kk*32 + lg*8);
          acc = mfma16(A, B, acc);
        }
#pragma unroll
        for (int j = 0; j < 4; ++j){
          int q = 4*lg + j, key = 16*wi + li;
          float v = acc[j] * 0.125f;
          float m = om[((size_t)b*64 + q)*64 + key];
          if (m > 0.f) v = -1e9f;
          lgs[ih*1152 + q*72 + key] = v;
        }
      }
      __syncthreads();
      { // softmax
        const int it = tid >> 8, q = (tid >> 4) & 15, i16 = tid & 15;
        const int b = bb2[it];
        float pv[4], mx = -3e38f;
#pragma unroll
        for (int u = 0; u < 4; ++u){ pv[u] = lgs[it*1152 + q*72 + i16 + 16*u]; mx = fmaxf(mx, pv[u]); }
#pragma unroll
        for (int d = 1; d < 16; d <<= 1) mx = fmaxf(mx, __shfl_xor(mx, d, 16));
        float s = 0.f;
#pragma unroll
        for (int u = 0; u < 4; ++u){ pv[u] = expf(pv[u] - mx); s += pv[u]; }
#pragma unroll
        for (int d = 1; d < 16; d <<= 1) s += __shfl_xor(s, d, 16);
#pragma unroll
        for (int u = 0; u < 4; ++u){
          int key = i16 + 16*u;
          float m = om[((size_t)b*64 + q)*64 + key];
          Ps[it*1152 + q*72 + key] = (_Float16)((pv[u]/s)*(1.f - m));
        }
      }
      __syncthreads();
      { // out_h = P @ V_h; outp stored f16
        f32x4 acc = 0.f;
#pragma unroll
        for (int kk = 0; kk < 2; ++kk){
          f16x8 A = *(const f16x8*)(Ps + ih*1152 + li*72 + kk*32 + lg*8);
          f16x8 B = *(const f16x8*)(Vs + ih*4608 + (16*wi + li)*72 + kk*32 + lg*8);
          acc = mfma16(A, B, acc);
        }
#pragma unroll
        for (int j = 0; j < 4; ++j)
          outp[ih*4224 + (4*lg + j)*264 + 64*h + 16*wi + li] = (_Float16)acc[j];
      }
      __syncthreads();
    }

    { // out-proj via 32x32, stacked M=32; wave -> n-tile w
      f32x16 acc = 0.f;
      const int ito = r32 >> 4, qr = r32 & 15;
      for (int kk = 0; kk < 16; ++kk){
        f16x8 A = *(const f16x8*)(outp + ito*4224 + qr*264 + kk*16 + kh);
        f16x8 B = *(const f16x8*)(WOUT + (size_t)(w*32 + r32)*256 + kk*16 + kh);
        acc = mfma32(A, B, acc);
      }
      int col = w*32 + r32;
      float bias = bo[col];
#pragma unroll
      for (int reg = 0; reg < 16; ++reg){
        int row = (reg & 3) + 8*(reg >> 2) + 4*(l >> 5);
        int it2 = row >> 4, q2 = row & 15;
        const int b = bb2[it2];
        float v = (acc[reg] + bias) * (1.f - em[(size_t)b*64 + q2]);
        x2out[((size_t)b*16 + q2)*256 + col] = v;
      }
    }
    return;
  }

  // ============================== gate role ==============================
  {
    constexpr int W1SZ = 96*256, WINSZ = 256*768, WVSZ = 16*256;
    const int b = blockIdx.x - 2048;
    const int l = tid & 63;
    const int r32 = l & 31, kh = (l >> 5)*8;

    char* sp = smem;
    _Float16* x1h = (_Float16*)sp; sp += 64*264*2;
    _Float16* x1l = (_Float16*)sp; sp += 64*264*2;
    _Float16* Kh  = (_Float16*)sp; sp += 64*72*2;
    _Float16* Kl  = (_Float16*)sp; sp += 64*72*2;
    _Float16* Qh  = (_Float16*)sp; sp += 16*264*2;
    _Float16* Ql  = (_Float16*)sp; sp += 16*264*2;
    float*    lgs = (float*)sp;    sp += 16*72*4;
    float*    Ps  = (float*)sp;    sp += 16*66*4;
    float*    v2s = (float*)sp;    sp += 64*18*4;
    float*  ogacc = (float*)sp;    sp += 32*4;
    float*  Kpart = (float*)sp;    sp += 8192*4;

    { // phase 1: x1 = relu(ent @ W1g + b1g), 32x32 split-2
      const int mt = w & 1, ntb = (w >> 1)*2;
      f32x16 acc0 = 0.f, acc1 = 0.f;
#pragma unroll
      for (int kk = 0; kk < 6; ++kk){
        AB<1> a = ldF<1>(ent + ((size_t)b*64 + mt*32 + r32)*96 + kk*16 + kh);
#pragma unroll
        for (int s = 0; s < 2; ++s){
          const _Float16* bp = W1g + (size_t)((ntb + s)*32 + r32)*96 + kk*16 + kh;
          f16x8 Bh = *(const f16x8*)bp;
          f16x8 Bl = *(const f16x8*)(bp + W1SZ);
          f32x16& ac = s ? acc1 : acc0;
          ac = mfma32(a.lo, Bh, ac);
          ac = mfma32(a.hi, Bl, ac);
          ac = mfma32(a.hi, Bh, ac);
        }
      }
#pragma unroll
      for (int s = 0; s < 2; ++s){
        const f32x16& ac = s ? acc1 : acc0;
        int col = (ntb + s)*32 + r32;
        float bias = b1g[col];
#pragma unroll
        for (int reg = 0; reg < 16; ++reg){
          int row = (reg & 3) + 8*(reg >> 2) + 4*(l >> 5);
          stL<1>(x1h, x1l, (mt*32 + row)*264 + col, fmaxf(ac[reg] + bias, 0.f));
        }
      }
    }
    if (tid < 32) ogacc[tid] = 0.f;
    __syncthreads();

    { // phase 2: Qfull (16x16 split-2), v2
#pragma unroll
      for (int s = 0; s < 2; ++s){
        int nt = w + s*8;
        f32x4 acc = 0.f;
        for (int kk = 0; kk < 8; ++kk){
          int ao = li*264 + kk*32 + lg*8;
          AB<1> a = ldL<1>(x1h + ao, x1l + ao);
          AB<1> bb = ldW<1>(WINg + (size_t)(nt*16 + li)*256 + kk*32 + lg*8, WINSZ);
          a.mf(bb, acc);
        }
#pragma unroll
        for (int j = 0; j < 4; ++j)
          stL<1>(Qh, Ql, (4*lg + j)*264 + nt*16 + li, acc[j]);
      }
      if (w < 4){
        f32x4 acc = 0.f;
        for (int kk = 0; kk < 8; ++kk){
          int ao = (w*16 + li)*264 + kk*32 + lg*8;
          AB<1> a = ldL<1>(x1h + ao, x1l + ao);
          AB<1> bb = ldW<1>(WVEFF + (size_t)li*256 + kk*32 + lg*8, WVSZ);
          a.mf(bb, acc);
        }
#pragma unroll
        for (int j = 0; j < 4; ++j)
          v2s[(w*16 + 4*lg + j)*18 + li] = acc[j];
      }
    }
    __syncthreads();

    for (int h = 0; h < 4; ++h){
      { // K_h partials: 32x32 split-2, tiles x k-halves across 8 waves
        const int t = w & 3, kt = t >> 1, dt = t & 1, khalf = w >> 2;
        f32x16 acc = 0.f;
#pragma unroll
        for (int k8 = 0; k8 < 8; ++k8){
          int ko = (khalf*8 + k8)*16 + kh;
          int ao = (kt*32 + r32)*264 + ko;
          f16x8 ah = *(const f16x8*)(x1h + ao);
          f16x8 al = *(const f16x8*)(x1l + ao);
          const _Float16* bp = WINg + (size_t)(256 + h*64 + dt*32 + r32)*256 + ko;
          f16x8 Bh = *(const f16x8*)bp;
          f16x8 Bl = *(const f16x8*)(bp + WINSZ);
          acc = mfma32(al, Bh, acc);
          acc = mfma32(ah, Bl, acc);
          acc = mfma32(ah, Bh, acc);
        }
#pragma unroll
        for (int reg = 0; reg < 16; ++reg){
          int row = (reg & 3) + 8*(reg >> 2) + 4*(l >> 5);
          Kpart[((khalf*4 + t)*32 + row)*32 + r32] = acc[reg];
        }
      }
      __syncthreads();
      { // reduce k-halves -> Kh/Kl
        for (int e = tid; e < 4096; e += 512){
          float s2 = Kpart[e] + Kpart[4096 + e];
          int t2 = e >> 10, idx = e & 1023, row = idx >> 5, col = idx & 31;
          stL<1>(Kh, Kl, ((t2 >> 1)*32 + row)*72 + (t2 & 1)*32 + col, s2);
        }
      }
      __syncthreads();
      if (w < 4){ // logits
        f32x4 acc = 0.f;
#pragma unroll
        for (int kk = 0; kk < 2; ++kk){
          int ao = li*264 + h*64 + kk*32 + lg*8;
          AB<1> a = ldL<1>(Qh + ao, Ql + ao);
          int bo_ = (16*w + li)*72 + kk*32 + lg*8;
          AB<1> bb = ldL<1>(Kh + bo_, Kl + bo_);
          a.mf(bb, acc);
        }
#pragma unroll
        for (int j = 0; j < 4; ++j){
          int q = 4*lg + j, key = 16*w + li;
          float v = acc[j] * 0.125f;
          float m = om[((size_t)b*64 + q)*64 + key];
          if (m > 0.f) v = -1e9f;
          lgs[q*72 + key] = v;
        }
      }
      __syncthreads();
      if (tid < 256){ // softmax
        int q = tid >> 4, i16 = tid & 15;
        float pv[4], mx = -3e38f;
#pragma unroll
        for (int u = 0; u < 4; ++u){ pv[u] = lgs[q*72 + i16 + 16*u]; mx = fmaxf(mx, pv[u]); }
#pragma unroll
        for (int d = 1; d < 16; d <<= 1) mx = fmaxf(mx, __shfl_xor(mx, d, 16));
        float s = 0.f;
#pragma unroll
        for (int u = 0; u < 4; ++u){ pv[u] = expf(pv[u] - mx); s += pv[u]; }
#pragma unroll
        for (int d = 1; d < 16; d <<= 1) s += __shfl_xor(s, d, 16);
#pragma unroll
        for (int u = 0; u < 4; ++u){
          int key = i16 + 16*u;
          float m = om[((size_t)b*64 + q)*64 + key];
          Ps[q*66 + key] = (pv[u]/s)*(1.f - m);
        }
      }
      __syncthreads();
      if (tid < 256){ // og += P_h . v2_h
        int q = tid >> 4, l16 = tid & 15;
        float a0 = 0.f, a1 = 0.f;
#pragma unroll
        for (int u = 0; u < 4; ++u){
          int k = l16 + 16*u;
          float p2 = Ps[q*66 + k];
          a0 += p2 * v2s[k*18 + h*2];
          a1 += p2 * v2s[k*18 + h*2 + 1];
        }
#pragma unroll
        for (int d = 1; d < 16; d <<= 1){ a0 += __shfl_xor(a0, d, 16); a1 += __shfl_xor(a1, d, 16); }
        if (l16 == 0){ ogacc[q*2] += a0; ogacc[q*2 + 1] += a1; }
      }
      __syncthreads();
    }
    if (tid < 16){
      int q = tid;
      float am = em[(size_t)b*64 + q];
      float g0 = (1.f - am)*(ogacc[2*q]     + beff[0]) + gb2[0];
      float g1 = (1.f - am)*(ogacc[2*q + 1] + beff[1]) + gb2[1];
      og[((size_t)b*16 + q)*2]     = g0;
      og[((size_t)b*16 + q)*2 + 1] = g1;
      gate[(size_t)b*16 + q] = (g1 > g0) ? 1.f : 0.f;
    }
  }
}

// ------------------- K2: gate, global attention, fc2, gi — 2 items/block
// r19: QKV hoisted as stacked-M=32 GEMM into all-head buffers Qall/Kall/Vtall;
// head loop = logits/softmax/PV only. cat_s overlays Qall/Kall (lifetimes
// disjoint); x2 staging moved to gmsg phase.
__global__ __launch_bounds__(256) void k2_global(
    const float* __restrict__ em,
    const float* __restrict__ x2, const float* __restrict__ x2m,
    const float* __restrict__ gate,
    const _Float16* __restrict__ GMIN, const _Float16* __restrict__ GMOUT, const float* __restrict__ gob,
    const _Float16* __restrict__ FC2T, const float* __restrict__ fc2b,
    const _Float16* __restrict__ GIHT, const float* __restrict__ gib,
    float* __restrict__ gi)
{
  const int p = blockIdx.x;
  const int tid = threadIdx.x;
  const int w = tid >> 6, lg = (tid >> 4) & 3, li = tid & 15;
  const int l = tid & 63;
  const int r32 = l & 31, kh = (l >> 5)*8;

  extern __shared__ char smem[];
  float*    gate_s = (float*)smem;                 // 128 B
  _Float16* gm_s   = (_Float16*)(smem + 128);      // [2][16][264] 16896 -> 17024
  float*    lg2    = (float*)(smem + 17024);       // [2][16][24]   3072 -> 20096
  _Float16* P2     = (_Float16*)(smem + 20096);    // [2][16][40]   2560 -> 22656
  _Float16* outp   = (_Float16*)(smem + 22656);    // [2][16][264] 16896 -> 39552
  _Float16* x3_s   = (_Float16*)(smem + 39552);    // [2][16][264] 16896 -> 56448
  _Float16* Vtall  = (_Float16*)(smem + 56448);    // [2][256][40] 40960 -> 97408
  _Float16* Qall   = (_Float16*)(smem + 97408);    // [2][16][264] 16896 -> 114304
  _Float16* Kall   = (_Float16*)(smem + 114304);   // [2][16][264] 16896 -> 131200
  _Float16* cat_s  = (_Float16*)(smem + 97408);    // overlay [2][16][520] 33280
  // SMK2 = 131200

  if (tid < 32){
    int it = tid >> 4, q = tid & 15;
    gate_s[it*16 + q] = gate[(size_t)(2*p + it)*16 + q];
  }
  __syncthreads();
  // staging: gm only; zero Vtall (for key pad 16..31) and P2 pad
#pragma unroll
  for (int it = 0; it < 2; ++it){
    const int b = 2*p + it;
    for (int idx = tid; idx < 4096; idx += 256){
      int q = idx >> 8, d = idx & 255;
      gm_s[it*4224 + q*264 + d] = (_Float16)(x2m[((size_t)b*16 + q)*256 + d] * gate_s[it*16 + q]);
    }
  }
  for (int idx = tid; idx < 10240; idx += 256) ((unsigned*)Vtall)[idx] = 0u;
  for (int idx = tid; idx < 2*16*40; idx += 256) P2[idx] = (_Float16)0.f;
  __syncthreads();

  { // QKVall = gm_stacked(32x256) @ GMIN(768x256); wave -> n-tiles {6w..6w+5}
    const int itq = r32 >> 4, qr = r32 & 15;
#pragma unroll
    for (int s = 0; s < 6; ++s){
      int nt = 6*w + s;
      f32x16 acc = 0.f;
      for (int kk = 0; kk < 16; ++kk){
        f16x8 A = *(const f16x8*)(gm_s + itq*4224 + qr*264 + kk*16 + kh);
        f16x8 B = *(const f16x8*)(GMIN + (size_t)(nt*32 + r32)*256 + kk*16 + kh);
        acc = mfma32(A, B, acc);
      }
      int sec = nt >> 3;                   // 0=q, 1=k, 2=v (wave-uniform)
      int hcol = (nt & 7)*32 + r32;        // head-dim column 0..255
#pragma unroll
      for (int reg = 0; reg < 16; ++reg){
        int row = (reg & 3) + 8*(reg >> 2) + 4*(l >> 5);
        int it2 = row >> 4, q2 = row & 15;
        _Float16 v = (_Float16)acc[reg];
        if (sec == 0)      Qall[it2*4224 + q2*264 + hcol] = v;
        else if (sec == 1) Kall[it2*4224 + q2*264 + hcol] = v;
        else               Vtall[it2*10240 + hcol*40 + q2] = v;
      }
    }
  }
  __syncthreads();

  for (int h = 0; h < 4; ++h){
    if (w < 2){ // 16x16 logits; wave w -> item w
      const int it = w, b = 2*p + it;
      f32x4 acc = 0.f;
#pragma unroll
      for (int kk = 0; kk < 2; ++kk){
        f16x8 A = *(const f16x8*)(Qall + it*4224 + li*264 + 64*h + kk*32 + lg*8);
        f16x8 B = *(const f16x8*)(Kall + it*4224 + li*264 + 64*h + kk*32 + lg*8);
        acc = mfma16(A, B, acc);
      }
      float amk = em[(size_t)b*64 + li];
#pragma unroll
      for (int j = 0; j < 4; ++j){
        int q = 4*lg + j;
        float amq = em[(size_t)b*64 + q];
        float m = 1.f - (1.f - amq)*(1.f - amk);
        float v = acc[j]*0.125f;
        if (m > 0.f) v = -1e9f;
        lg2[it*384 + q*24 + li] = v;
      }
    }
    __syncthreads();
    { // softmax, both items
      int q = tid >> 4, key = tid & 15;
#pragma unroll
      for (int it = 0; it < 2; ++it){
        const int b = 2*p + it;
        float v = lg2[it*384 + q*24 + key];
        float mx = v;
#pragma unroll
        for (int d = 1; d < 16; d <<= 1) mx = fmaxf(mx, __shfl_xor(mx, d, 16));
        float pe = expf(v - mx);
        float s = pe;
#pragma unroll
        for (int d = 1; d < 16; d <<= 1) s += __shfl_xor(s, d, 16);
        float amq = em[(size_t)b*64 + q], amk = em[(size_t)b*64 + key];
        float m = 1.f - (1.f - amq)*(1.f - amk);
        P2[it*640 + q*40 + key] = (_Float16)((pe/s)*(1.f - m));
      }
    }
    __syncthreads();
    { // PV, both items; B from Vtall
#pragma unroll
      for (int it = 0; it < 2; ++it){
        f32x4 acc = 0.f;
        f16x8 A = *(const f16x8*)(P2 + it*640 + li*40 + lg*8);
        f16x8 B = *(const f16x8*)(Vtall + it*10240 + (size_t)(64*h + 16*w + li)*40 + lg*8);
        acc = mfma16(A, B, acc);
#pragma unroll
        for (int j = 0; j < 4; ++j)
          outp[it*4224 + (4*lg + j)*264 + 64*h + 16*w + li] = (_Float16)acc[j];
      }
    }
    __syncthreads();
  }
  { // gmsg out-proj stacked M=32 (Qall/Kall dead -> cat overlay legal);
    // also stage x2 -> cat[:,0:256] here
    const int ito = r32 >> 4, qr = r32 & 15;
#pragma unroll
    for (int s = 0; s < 2; ++s){
      int nt = 2*w + s;
      f32x16 acc = 0.f;
      for (int kk = 0; kk < 16; ++kk){
        f16x8 A = *(const f16x8*)(outp + ito*4224 + qr*264 + kk*16 + kh);
        f16x8 B = *(const f16x8*)(GMOUT + (size_t)(nt*32 + r32)*256 + kk*16 + kh);
        acc = mfma32(A, B, acc);
      }
      int col = nt*32 + r32;
      float bias = gob[col];
#pragma unroll
      for (int reg = 0; reg < 16; ++reg){
        int row = (reg & 3) + 8*(reg >> 2) + 4*(l >> 5);
        int it2 = row >> 4, q2 = row & 15;
        float m = 1.f - em[(size_t)(2*p + it2)*64 + q2];
        cat_s[it2*8320 + q2*520 + 256 + col] = (_Float16)((acc[reg] + bias)*m);
      }
    }
#pragma unroll
    for (int it = 0; it < 2; ++it){
      const int b = 2*p + it;
      for (int idx = tid; idx < 4096; idx += 256){
        int q = idx >> 8, d = idx & 255;
        cat_s[it*8320 + q*520 + d] = (_Float16)(x2[((size_t)b*16 + q)*256 + d]);
      }
    }
  }
  __syncthreads();
  { // x3 = relu(cat @ fc2 + b) stacked M=32; wave -> n-tiles {2w, 2w+1}, K=512
    const int ito = r32 >> 4, qr = r32 & 15;
#pragma unroll
    for (int s = 0; s < 2; ++s){
      int nt = 2*w + s;
      f32x16 acc = 0.f;
      for (int kk = 0; kk < 32; ++kk){
        f16x8 A = *(const f16x8*)(cat_s + ito*8320 + qr*520 + kk*16 + kh);
        f16x8 B = *(const f16x8*)(FC2T + (size_t)(nt*32 + r32)*512 + kk*16 + kh);
        acc = mfma32(A, B, acc);
      }
      int col = nt*32 + r32;
      float bias = fc2b[col];
#pragma unroll
      for (int reg = 0; reg < 16; ++reg){
        int row = (reg & 3) + 8*(reg >> 2) + 4*(l >> 5);
        int it2 = row >> 4, q2 = row & 15;
        x3_s[it2*4224 + q2*264 + col] = (_Float16)fmaxf(acc[reg] + bias, 0.f);
      }
    }
  }
  __syncthreads();
  { // gi stacked M=32; wave -> n-tiles {6w .. 6w+5}, N=768
    const int r0 = ((2*p) >> 6)*16, t0 = (2*p) & 63;
    const int ito = r32 >> 4, qr = r32 & 15;
#pragma unroll
    for (int s = 0; s < 6; ++s){
      int nt = 6*w + s;
      f32x16 acc = 0.f;
      for (int kk = 0; kk < 16; ++kk){
        f16x8 A = *(const f16x8*)(x3_s + ito*4224 + qr*264 + kk*16 + kh);
        f16x8 B = *(const f16x8*)(GIHT + (size_t)(nt*32 + r32)*256 + kk*16 + kh);
        acc = mfma32(A, B, acc);
      }
      int col = nt*32 + r32;
      float bias = gib[col];
#pragma unroll
      for (int reg = 0; reg < 16; ++reg){
        int row = (reg & 3) + 8*(reg >> 2) + 4*(l >> 5);
        int it2 = row >> 4, q2 = row & 15;
        gi[((size_t)((r0 + q2)*64 + t0 + it2))*768 + col] = acc[reg] + bias;
      }
    }
  }
}

// ------------------------------------------------------------------ K3: GRU
// 512 threads = 8 waves x 6 col-tiles (r18-verified).
__global__ __launch_bounds__(512) void k3_gru(
    const _Float16* __restrict__ WHH, const float* __restrict__ bhh,
    const float* __restrict__ gi, const float* __restrict__ h0,
    float* __restrict__ hs)
{
  const int rb = blockIdx.x;
  const int row0 = rb * 16;
  const int tid = threadIdx.x;
  const int w = tid >> 6, lg = (tid >> 4) & 3, li = tid & 15;

  extern __shared__ char smem3[];
  _Float16* hf16 = (_Float16*)smem3;
  float* hf32 = (float*)(smem3 + 8448);
  float* gh   = (float*)(smem3 + 8448 + 16640);
  float* bhs  = (float*)(smem3 + 8448 + 16640 + 49664);

  for (int idx = tid; idx < 768; idx += 512) bhs[idx] = bhh[idx];
  for (int idx = tid; idx < 4096; idx += 512){
    int r = idx >> 8, d = idx & 255;
    float v = h0[(size_t)(row0 + r)*256 + d];
    hf32[r*260 + d] = v;
    hf16[r*264 + d] = (_Float16)v;
  }
  __syncthreads();

  const int er = tid >> 5;
  const int dd = (tid & 31) * 8;

  for (int t = 0; t < 64; ++t){
    const float* gp = gi + ((size_t)(row0 + er)*64 + t)*768 + dd;
    f32x4 gr[2], gz[2], gn[2];
#pragma unroll
    for (int v = 0; v < 2; ++v){
      gr[v] = *(const f32x4*)(gp + v*4);
      gz[v] = *(const f32x4*)(gp + 256 + v*4);
      gn[v] = *(const f32x4*)(gp + 512 + v*4);
    }
    f16x8 a[8];
#pragma unroll
    for (int kk = 0; kk < 8; ++kk)
      a[kk] = *(const f16x8*)(hf16 + li*264 + kk*32 + lg*8);
    f32x4 acc[6];
#pragma unroll
    for (int c = 0; c < 6; ++c) acc[c] = 0.f;
#pragma unroll
    for (int c = 0; c < 6; ++c){
      const _Float16* bp = WHH + (size_t)(w*96 + c*16 + li)*256 + lg*8;
#pragma unroll
      for (int kk = 0; kk < 8; ++kk)
        acc[c] = mfma16(a[kk], *(const f16x8*)(bp + kk*32), acc[c]);
    }
#pragma unroll
    for (int c = 0; c < 6; ++c){
      int col = w*96 + c*16 + li;
#pragma unroll
      for (int j = 0; j < 4; ++j)
        gh[(4*lg + j)*776 + col] = acc[c][j];
    }
    __syncthreads();
    {
      float* hp32 = hf32 + er*260 + dd;
      float* hsp  = hs + ((size_t)(rb*64 + t)*16 + er)*256 + dd;
      f16x8 hv8;
#pragma unroll
      for (int v = 0; v < 2; ++v){
        f32x4 xr = *(const f32x4*)(gh + er*776 +       dd + v*4);
        f32x4 xz = *(const f32x4*)(gh + er*776 + 256 + dd + v*4);
        f32x4 xn = *(const f32x4*)(gh + er*776 + 512 + dd + v*4);
        f32x4 hold = *(const f32x4*)(hp32 + v*4);
        f32x4 hout;
#pragma unroll
        for (int e = 0; e < 4; ++e){
          int d = dd + v*4 + e;
          float rr_ = 1.f/(1.f + __expf(-(gr[v][e] + xr[e] + bhs[d])));
          float zz  = 1.f/(1.f + __expf(-(gz[v][e] + xz[e] + bhs[256 + d])));
          float pre = gn[v][e] + rr_*(xn[e] + bhs[512 + d]);
          float nn  = 1.f - 2.f/(1.f + __expf(2.f*pre));
          float hv = (1.f - zz)*nn + zz*hold[e];
          hout[e] = hv;
          hv8[v*4 + e] = (_Float16)hv;
        }
        *(f32x4*)(hp32 + v*4) = hout;
        *(f32x4*)(hsp + v*4)  = hout;
      }
      *(f16x8*)(hf16 + er*264 + dd) = hv8;
    }
    __syncthreads();
  }
}

// ------------------------------------------------------------------ K4: q out
__global__ __launch_bounds__(256) void k4_q(
    const _Float16* __restrict__ FC3T, const float* __restrict__ fc3b,
    const float* __restrict__ em, const float* __restrict__ hs, float* __restrict__ qo)
{
  const int tid = threadIdx.x;
  const int w = tid >> 6, lg = (tid >> 4) & 3, li = tid & 15;
  const int rb = blockIdx.x*64 + 16*w;
  f32x4 acc[2];
#pragma unroll
  for (int c = 0; c < 2; ++c) acc[c] = 0.f;
  for (int kk = 0; kk < 8; ++kk){
    const float* ap = hs + (size_t)(rb + li)*256 + kk*32 + lg*8;
    f32x4 v0 = *(const f32x4*)ap, v1 = *(const f32x4*)(ap + 4);
    f16x8 A;
#pragma unroll
    for (int e = 0; e < 4; ++e){ A[e] = (_Float16)v0[e]; A[e+4] = (_Float16)v1[e]; }
#pragma unroll
    for (int c = 0; c < 2; ++c){
      f16x8 B = *(const f16x8*)(FC3T + (size_t)(16*c + li)*256 + kk*32 + lg*8);
      acc[c] = mfma16(A, B, acc[c]);
    }
  }
#pragma unroll
  for (int c = 0; c < 2; ++c){
    int col = 16*c + li;
    float bias = fc3b[col];
#pragma unroll
    for (int j = 0; j < 4; ++j){
      int row = rb + 4*lg + j;
      float am = em[(size_t)(row >> 4)*64 + (row & 15)];
      qo[(size_t)row*32 + col] = (acc[c][j] + bias)*(1.f - am);
    }
  }
}

// --------------------------------------------------------------------- launch
extern "C" void kernel_launch(void* const* d_in, const int* in_sizes, int n_in,
                              void* d_out, int out_size, void* d_ws, size_t ws_size,
                              hipStream_t stream)
{
  constexpr size_t OFF_FC1T   = 0;
  constexpr size_t OFF_MSG1T  = 49152;
  constexpr size_t OFF_AINT   = 98304;
  constexpr size_t OFF_LINT   = 491520;
  constexpr size_t OFF_AOUTT  = 884736;
  constexpr size_t OFF_LOUTT  = 1015808;
  constexpr size_t OFF_GMINT  = 1146880;
  constexpr size_t OFF_GMOUTT = 1540096;
  constexpr size_t OFF_FC2T   = 1671168;
  constexpr size_t OFF_GIHT   = 1933312;
  constexpr size_t OFF_GHHT   = 2326528;
  constexpr size_t OFF_FC3T   = 2719744;
  constexpr size_t OFF_G1T    = 2736128;
  constexpr size_t OFF_GINT   = 2834432;
  constexpr size_t OFF_WVEFF  = 3620864;
  constexpr size_t OFF_BEFF   = 3637248;
  constexpr size_t OFF_GATE   = 3637504;
  constexpr size_t OFF_X2     = 3768576;
  constexpr size_t OFF_X2M    = 37323008;
  constexpr size_t OFF_GI     = 70877440;
  constexpr size_t NEED       = 171540736;
  if (ws_size < NEED) return;

  char* ws = (char*)d_ws;
  const float* ent = (const float*)d_in[0];
  const float* om  = (const float*)d_in[1];
  const float* em  = (const float*)d_in[2];

  WJobs jb{};
  int nj = 0;
  auto addj = [&](int src_idx, size_t off, int K, int N, int m){
    jb.src[nj] = (const float*)d_in[src_idx]; jb.off[nj] = (unsigned)off;
    jb.K[nj] = K; jb.N[nj] = N; jb.mode[nj] = m; ++nj;
  };
  addj(4,  OFF_FC1T,   96, 256, 0);
  addj(17, OFF_MSG1T,  96, 256, 0);
  addj(6,  OFF_AINT,  256, 768, 0);
  addj(19, OFF_LINT,  256, 768, 0);
  addj(7,  OFF_AOUTT, 256, 256, 0);
  addj(20, OFF_LOUTT, 256, 256, 0);
  addj(22, OFF_GMINT, 256, 768, 0);
  addj(23, OFF_GMOUTT,256, 256, 0);
  addj(9,  OFF_FC2T,  512, 256, 0);
  addj(11, OFF_GIHT,  256, 768, 0);
  addj(12, OFF_GHHT,  256, 768, 0);
  addj(15, OFF_FC3T,  256,  32, 0);
  addj(28, OFF_G1T,    96, 256, 1);
  addj(25, OFF_GINT,  256, 768, 1);
  k0_conv<<<dim3(96, nj), 256, 0, stream>>>(jb, ws);

  k0w_gate<<<1, 256, 0, stream>>>(
      (const float*)d_in[26], (const float*)d_in[30],
      (const float*)d_in[27], (const float*)d_in[25],
      (_Float16*)(ws + OFF_WVEFF), (float*)(ws + OFF_BEFF));

  constexpr int SMB = 156672, SMK2 = 131200, SM3 = 77824;
  (void)hipFuncSetAttribute(reinterpret_cast<const void*>(&k1_all),
                            hipFuncAttributeMaxDynamicSharedMemorySize, SMB);
  (void)hipFuncSetAttribute(reinterpret_cast<const void*>(&k2_global),
                            hipFuncAttributeMaxDynamicSharedMemorySize, SMK2);
  (void)hipFuncSetAttribute(reinterpret_cast<const void*>(&k3_gru),
                            hipFuncAttributeMaxDynamicSharedMemorySize, SM3);

  float* qout = (float*)d_out;
  float* hsout = qout + 1048576;
  float* gout = qout + 9437184;

  k1_all<<<4096, 512, SMB, stream>>>(ent, om, em,
      (const _Float16*)(ws + OFF_FC1T),  (const float*)d_in[5],
      (const _Float16*)(ws + OFF_AINT),
      (const _Float16*)(ws + OFF_AOUTT), (const float*)d_in[8],
      (float*)(ws + OFF_X2),
      (const _Float16*)(ws + OFF_MSG1T), (const float*)d_in[18],
      (const _Float16*)(ws + OFF_LINT),
      (const _Float16*)(ws + OFF_LOUTT), (const float*)d_in[21],
      (float*)(ws + OFF_X2M),
      (const _Float16*)(ws + OFF_G1T),   (const float*)d_in[29],
      (const _Float16*)(ws + OFF_GINT),
      (const _Float16*)(ws + OFF_WVEFF),
      (const float*)(ws + OFF_BEFF), (const float*)d_in[31],
      gout, (float*)(ws + OFF_GATE));

  k2_global<<<1024, 256, SMK2, stream>>>(em,
      (const float*)(ws + OFF_X2), (const float*)(ws + OFF_X2M),
      (const float*)(ws + OFF_GATE),
      (const _Float16*)(ws + OFF_GMINT), (const _Float16*)(ws + OFF_GMOUTT), (const float*)d_in[24],
      (const _Float16*)(ws + OFF_FC2T), (const float*)d_in[10],
      (const _Float16*)(ws + OFF_GIHT), (const float*)d_in[13],
      (float*)(ws + OFF_GI));

  k3_gru<<<32, 512, SM3, stream>>>(
      (const _Float16*)(ws + OFF_GHHT), (const float*)d_in[14],
      (const float*)(ws + OFF_GI), (const float*)d_in[3], hsout);

  k4_q<<<512, 256, 0, stream>>>(
      (const _Float16*)(ws + OFF_FC3T), (const float*)d_in[16],
      em, hsout, qout);
}